// Round 7
// baseline (484.323 us; speedup 1.0000x reference)
//
#include <hip/hip_runtime.h>
#include <math.h>

typedef unsigned int u32;
typedef unsigned short u16;
typedef u32 u32x4 __attribute__((ext_vector_type(4)));
typedef float f32x4 __attribute__((ext_vector_type(4)));

__device__ __forceinline__ u16 f2bf(float f) {
  u32 u = __builtin_bit_cast(u32, f);
  return (u16)((u + 0x7FFFu + ((u >> 16) & 1u)) >> 16);
}
__device__ __forceinline__ float bf2f(u32 lo16) {
  return __builtin_bit_cast(float, lo16 << 16);
}
__device__ __forceinline__ void mfma16(f32x4& c, const u32x4& a, const u32x4& b) {
  asm volatile("v_mfma_f32_16x16x32_bf16 %0, %1, %2, %0" : "+v"(c) : "v"(a), "v"(b));
}
__device__ __forceinline__ float lrelu(float e) { return fmaxf(e, 0.2f * e); }

// ---------------------------------------------------------------------------
// BatchNorm
// ---------------------------------------------------------------------------
__global__ void bn_stats_kernel(const float* __restrict__ x, float* __restrict__ musum,
                                float* __restrict__ sqsum, int N, int F) {
  int t = threadIdx.x;  // F == 256
  float s = 0.f, s2 = 0.f;
  for (int r = blockIdx.x; r < N; r += gridDim.x) {
    float v = x[(size_t)r * F + t];
    s += v;
    s2 += v * v;
  }
  atomicAdd(&musum[t], s);
  atomicAdd(&sqsum[t], s2);
}

__global__ void bn_finalize_kernel(const float* __restrict__ musum, const float* __restrict__ sqsum,
                                   const float* __restrict__ gamma, const float* __restrict__ beta,
                                   float* __restrict__ scale, float* __restrict__ shift, int N) {
  int t = threadIdx.x;
  float m = musum[t] / (float)N;
  float v = sqsum[t] / (float)N - m * m;
  float sc = gamma[t] * rsqrtf(v + 1e-5f);
  scale[t] = sc;
  shift[t] = beta[t] - m * sc;
}

__global__ void bn_apply_bf16_kernel(const float* __restrict__ x, const float* __restrict__ scale,
                                     const float* __restrict__ shift, u16* __restrict__ xin,
                                     int total, int Fmask) {
  int i = blockIdx.x * blockDim.x + threadIdx.x;
  if (i < total) {
    int c = i & Fmask;
    xin[i] = f2bf(x[i] * scale[c] + shift[c]);
  }
}

// ---------------------------------------------------------------------------
// CSR build (dst-indexed)
// ---------------------------------------------------------------------------
__global__ void csr_count_kernel(const int* __restrict__ ei, int E, int N, int* __restrict__ cnt) {
  int e = blockIdx.x * blockDim.x + threadIdx.x;
  int ET = E + N;
  if (e < ET) {
    int d = (e < E) ? ei[E + e] : (e - E);
    atomicAdd(&cnt[d], 1);
  }
}

__global__ __launch_bounds__(1024) void csr_scan_kernel(const int* __restrict__ cnt,
                                                        int* __restrict__ row_ptr,
                                                        int* __restrict__ cursor, int N) {
  __shared__ int part[1024];
  int t = threadIdx.x;
  int chunk = (N + 1023) / 1024;
  int lo = t * chunk;
  int hi = min(lo + chunk, N);
  int s = 0;
  for (int i = lo; i < hi; i++) s += cnt[i];
  part[t] = s;
  __syncthreads();
  for (int off = 1; off < 1024; off <<= 1) {
    int v = (t >= off) ? part[t - off] : 0;
    __syncthreads();
    part[t] += v;
    __syncthreads();
  }
  int run = (t == 0) ? 0 : part[t - 1];
  for (int i = lo; i < hi; i++) {
    row_ptr[i] = run;
    cursor[i] = run;
    run += cnt[i];
  }
  if (t == 1023) row_ptr[N] = part[1023];
}

__global__ void csr_fill_kernel(const int* __restrict__ ei, int E, int N,
                                int* __restrict__ cursor, int* __restrict__ csr_src) {
  int e = blockIdx.x * blockDim.x + threadIdx.x;
  int ET = E + N;
  if (e < ET) {
    int s, d;
    if (e < E) { s = ei[e]; d = ei[E + e]; }
    else       { s = e - E; d = s; }
    int pos = atomicAdd(&cursor[d], 1);
    csr_src[pos] = s;
  }
}

// ---------------------------------------------------------------------------
// Weight pre-fragmentation into EXTENDED Wt arrays (bf16, [Nc_tot][K]):
//   Wt1ext [1152][256]: rows 0..1023 = W1^T, 1024..1055 = al-fold, rest 0
//   Wt2ext [  96][1280]: rows 0..63  = W2^T,   64..79   = al-fold, rest 0
//   Wt3ext [ 160][  64]: rows 0..127 = W3^T,  128..143  = al-fold, rest 0
// ---------------------------------------------------------------------------
__global__ void wt_build_all(const float* __restrict__ W1, const float* __restrict__ W2,
                             const float* __restrict__ W3, u16* __restrict__ Wt1,
                             u16* __restrict__ Wt2, u16* __restrict__ Wt3) {
  const int S1 = 1024 * 256, S2 = 64 * 1280, S3 = 128 * 64;
  const int P1 = 96 * 256, P2 = 32 * 1280, P3 = 32 * 64;  // pad+al rows zero-init
  int idx = blockIdx.x * blockDim.x + threadIdx.x;
  if (idx < S1) {
    int n = idx / 256, k = idx % 256;
    Wt1[idx] = f2bf(W1[(size_t)k * 1024 + n]);
  } else if (idx < S1 + S2) {
    int i = idx - S1;
    int n = i / 1280, k = i % 1280;
    Wt2[i] = f2bf(W2[(size_t)k * 64 + n]);
  } else if (idx < S1 + S2 + S3) {
    int i = idx - S1 - S2;
    int n = i / 64, k = i % 64;
    Wt3[i] = f2bf(W3[(size_t)k * 128 + n]);
  } else if (idx < S1 + S2 + S3 + P1) {
    Wt1[S1 + (idx - S1 - S2 - S3)] = 0;
  } else if (idx < S1 + S2 + S3 + P1 + P2) {
    Wt2[S2 + (idx - S1 - S2 - S3 - P1)] = 0;
  } else if (idx < S1 + S2 + S3 + P1 + P2 + P3) {
    Wt3[S3 + (idx - S1 - S2 - S3 - P1 - P2)] = 0;
  }
}

// Fold attention vectors: row NcH + 2h (+1) of Wtext = W[:,hC:(h+1)C] @ a_{src,dst}[h]
__global__ void alfold_build(const float* __restrict__ W1, const float* __restrict__ a1s,
                             const float* __restrict__ a1d, const float* __restrict__ W2,
                             const float* __restrict__ a2s, const float* __restrict__ a2d,
                             const float* __restrict__ W3, const float* __restrict__ a3s,
                             const float* __restrict__ a3d, u16* __restrict__ Wt1,
                             u16* __restrict__ Wt2, u16* __restrict__ Wt3) {
  const int T1 = 32 * 256, T2 = 16 * 1280, T3 = 16 * 64;
  int idx = blockIdx.x * blockDim.x + threadIdx.x;
  if (idx < T1) {  // H=16, C=64
    int jj = idx / 256, k = idx % 256, h = jj >> 1;
    const float* av = (jj & 1) ? a1d : a1s;
    float s = 0.f;
    for (int c = 0; c < 64; c++) s += W1[(size_t)k * 1024 + h * 64 + c] * av[h * 64 + c];
    Wt1[(size_t)(1024 + jj) * 256 + k] = f2bf(s);
  } else if (idx < T1 + T2) {  // H=8, C=8
    int i = idx - T1;
    int jj = i / 1280, k = i % 1280, h = jj >> 1;
    const float* av = (jj & 1) ? a2d : a2s;
    float s = 0.f;
    for (int c = 0; c < 8; c++) s += W2[(size_t)k * 64 + h * 8 + c] * av[h * 8 + c];
    Wt2[(size_t)(64 + jj) * 1280 + k] = f2bf(s);
  } else if (idx < T1 + T2 + T3) {  // H=8, C=16
    int i = idx - T1 - T2;
    int jj = i / 64, k = i % 64, h = jj >> 1;
    const float* av = (jj & 1) ? a3d : a3s;
    float s = 0.f;
    for (int c = 0; c < 16; c++) s += W3[(size_t)k * 128 + h * 16 + c] * av[h * 16 + c];
    Wt3[(size_t)(128 + jj) * 64 + k] = f2bf(s);
  }
}

// ---------------------------------------------------------------------------
// bf16 MFMA GEMM with fused al epilogue. A = two bf16 segments (K1 | K-K1),
// Wt [Nc_tot][K]. Cols < NcH -> bf16 Ch; cols NcH+j -> al_{s,d}[j>>1][m]
// (transposed [H][ALP] layout for per-head locality in aggregation).
// ---------------------------------------------------------------------------
template <int BM, int BN, int FM, int FN>
__global__ __launch_bounds__(256) void mfma_gemm_al(
    const u16* __restrict__ A1, const u16* __restrict__ A2, int K1, int K,
    const u16* __restrict__ Wt, u16* __restrict__ Ch, int NcH,
    float* __restrict__ als, float* __restrict__ ald, int ALN, int ALP, int M) {
  constexpr int BK = 32;
  constexpr int ACH = (BM * BK) / 8;  // 16B chunks in A tile
  constexpr int BCH = (BN * BK) / 8;
  static_assert(BM == 2 * FM * 16 && BN == 2 * FN * 16, "wave grid 2x2");
  __shared__ u16 As[BM * BK];
  __shared__ u16 Bs[BN * BK];
  int t = threadIdx.x;
  int m0 = blockIdx.x * BM, n0 = blockIdx.y * BN;
  int r = t & 15;
  int g = (t >> 4) & 3;
  int wid = t >> 6;
  int wm0 = (wid >> 1) * (FM * 16);
  int wn0 = (wid & 1) * (FN * 16);
  int K8 = K >> 3;
  int K2 = K - K1;

  f32x4 acc[FM][FN] = {};
  asm volatile("s_nop 7\n\ts_nop 7" :::);  // VALU acc-init -> MFMA SrcC hazard guard

  for (int k0 = 0; k0 < K; k0 += BK) {
    const u16* Aseg;
    int sA, kl;
    if (k0 < K1) { Aseg = A1; sA = K1; kl = k0; }
    else         { Aseg = A2; sA = K2; kl = k0 - K1; }
    __syncthreads();
#pragma unroll
    for (int i = 0; i < (ACH + 255) / 256; i++) {
      int c = i * 256 + t;
      if (ACH % 256 == 0 || c < ACH) {
        int m = c >> 2, kb = c & 3;
        *(u32x4*)(As + c * 8) =
            *(const u32x4*)(Aseg + (size_t)(m0 + m) * sA + kl + kb * 8);
      }
    }
#pragma unroll
    for (int i = 0; i < (BCH + 255) / 256; i++) {
      int c = i * 256 + t;
      if (BCH % 256 == 0 || c < BCH) {
        int nn = c >> 2, kb = c & 3;
        *(u32x4*)(Bs + c * 8) =
            *(const u32x4*)(Wt + ((size_t)(n0 + nn) * K8 + (k0 >> 3) + kb) * 8);
      }
    }
    __syncthreads();
    u32x4 af[FM], bfr[FN];
#pragma unroll
    for (int fi = 0; fi < FM; fi++)
      af[fi] = *(const u32x4*)(As + ((wm0 + fi * 16 + r) * 4 + g) * 8);
#pragma unroll
    for (int fj = 0; fj < FN; fj++)
      bfr[fj] = *(const u32x4*)(Bs + ((wn0 + fj * 16 + r) * 4 + g) * 8);
#pragma unroll
    for (int fi = 0; fi < FM; fi++)
#pragma unroll
      for (int fj = 0; fj < FN; fj++) mfma16(acc[fi][fj], af[fi], bfr[fj]);
  }
  asm volatile("s_nop 7\n\ts_nop 7" :::);  // MFMA -> VALU read hazard guard

#pragma unroll
  for (int fi = 0; fi < FM; fi++) {
#pragma unroll
    for (int fj = 0; fj < FN; fj++) {
#pragma unroll
      for (int v = 0; v < 4; v++) {
        int m = m0 + wm0 + fi * 16 + g * 4 + v;
        int nn = n0 + wn0 + fj * 16 + r;
        if (m < M) {
          float val = acc[fi][fj][v];
          if (nn < NcH) {
            Ch[(size_t)m * NcH + nn] = f2bf(val);
          } else {
            int j = nn - NcH;
            if (j < ALN) ((j & 1) ? ald : als)[(size_t)(j >> 1) * ALP + m] = val;
          }
        }
      }
    }
  }
}

// ---------------------------------------------------------------------------
// Layer-1 aggregation, HEAD-SLICED + XCD-affine: wave = (node, head).
// head = (blockIdx&7) + 8*phase, so each XCD's L2 holds one 2.56MB column
// slice of xwh plus the 80KB per-head al slice. Lane = column within head.
// ---------------------------------------------------------------------------
__global__ __launch_bounds__(256) void gat_agg1_hslice(
    const u16* __restrict__ xwh, const float* __restrict__ alsrc,
    const float* __restrict__ aldst, const int* __restrict__ row_ptr,
    const int* __restrict__ csr_src, const float* __restrict__ bias,
    const float* __restrict__ slope_p, u16* __restrict__ out, int N, int ALP, int NB) {
  constexpr int U = 6;
  int b = blockIdx.x;
  int xcd = b & 7;
  int seq = b >> 3;
  int phase = seq / NB;
  int nodeblk = seq - phase * NB;
  int h = xcd + (phase << 3);
  int n = nodeblk * 4 + (threadIdx.x >> 6);
  if (n >= N) return;
  int lane = threadIdx.x & 63;
  const float* alh = alsrc + (size_t)h * ALP;
  float ad = aldst[(size_t)h * ALP + n];
  int start = row_ptr[n];
  int end = row_ptr[n + 1];
  int deg = end - start;
  int endm1 = end - 1;

  // phase A: online softmax stats, edges strided across all 64 lanes
  float m = -1e30f, s = 0.f;
  for (int j = lane; j < deg; j += 64) {
    float e = lrelu(alh[csr_src[start + j]] + ad);
    float mn = fmaxf(m, e);
    s = s * __expf(m - mn) + __expf(e - mn);
    m = mn;
  }
#pragma unroll
  for (int st = 1; st <= 32; st <<= 1) {
    float m2 = __shfl_xor(m, st);
    float s2 = __shfl_xor(s, st);
    float mn = fmaxf(m, m2);
    s = s * __expf(m - mn) + s2 * __expf(m2 - mn);
    m = mn;
  }
  float rr = 1.f / (s + 1e-16f);

  // phase B: unroll-6 pipelined gather; lane covers one column of the head
  const u16* base = xwh + (size_t)h * 64 + lane;
  float acc = 0.f;
  int c[U];
#pragma unroll
  for (int i = 0; i < U; i++) c[i] = csr_src[min(start + i, endm1)];
  int j = 0;
  for (; j + U <= deg; j += U) {
    u16 v[U];
    float a[U];
#pragma unroll
    for (int i = 0; i < U; i++) v[i] = base[(size_t)c[i] * 1024];
#pragma unroll
    for (int i = 0; i < U; i++) a[i] = alh[c[i]];
#pragma unroll
    for (int i = 0; i < U; i++) c[i] = csr_src[min(start + j + U + i, endm1)];
#pragma unroll
    for (int i = 0; i < U; i++) {
      float w = __expf(lrelu(a[i] + ad) - m) * rr;
      acc = fmaf(w, bf2f(v[i]), acc);
    }
  }
  for (int i = 0; j < deg; j++, i++) {
    float w = __expf(lrelu(alh[c[i]] + ad) - m) * rr;
    acc = fmaf(w, bf2f(base[(size_t)c[i] * 1024]), acc);
  }

  // epilogue: bias + PReLU -> bf16
  float p = slope_p[0];
  int cc = h * 64 + lane;
  float v = acc + bias[cc];
  out[(size_t)n * 1024 + cc] = f2bf((v >= 0.f) ? v : p * v);
}

// ---------------------------------------------------------------------------
// Layer-2 aggregation, one wave per node, unroll-8 pipelined. bf16 rows 128B.
// al layout [H][ALP].
// ---------------------------------------------------------------------------
__global__ __launch_bounds__(256) void gat_agg2_wave(
    const u16* __restrict__ xwh, const float* __restrict__ alsrc,
    const float* __restrict__ aldst, const int* __restrict__ row_ptr,
    const int* __restrict__ csr_src, const float* __restrict__ bias,
    const float* __restrict__ slope_p, u16* __restrict__ out, int N, int ALP) {
  constexpr int U = 8;
  int n = blockIdx.x * 4 + (threadIdx.x >> 6);
  if (n >= N) return;
  int lane = threadIdx.x & 63;
  int head = lane >> 3, g = lane & 7;
  const float* alh = alsrc + (size_t)head * ALP;
  float ad = aldst[(size_t)head * ALP + n];
  int start = row_ptr[n];
  int end = row_ptr[n + 1];
  int deg = end - start;
  int endm1 = end - 1;

  float m = -1e30f, s = 0.f;
  for (int j = g; j < deg; j += 8) {
    float e = lrelu(alh[csr_src[start + j]] + ad);
    float mn = fmaxf(m, e);
    s = s * __expf(m - mn) + __expf(e - mn);
    m = mn;
  }
#pragma unroll
  for (int st = 1; st <= 4; st <<= 1) {
    float m2 = __shfl_xor(m, st);
    float s2 = __shfl_xor(s, st);
    float mn = fmaxf(m, m2);
    s = s * __expf(m - mn) + s2 * __expf(m2 - mn);
    m = mn;
  }
  float rr = 1.f / (s + 1e-16f);

  float acc = 0.f;
  int c[U];
#pragma unroll
  for (int i = 0; i < U; i++) c[i] = csr_src[min(start + i, endm1)];
  int j = 0;
  for (; j + U <= deg; j += U) {
    u16 v[U];
    float a[U];
#pragma unroll
    for (int i = 0; i < U; i++) v[i] = xwh[(size_t)c[i] * 64 + lane];
#pragma unroll
    for (int i = 0; i < U; i++) a[i] = alh[c[i]];
#pragma unroll
    for (int i = 0; i < U; i++) c[i] = csr_src[min(start + j + U + i, endm1)];
#pragma unroll
    for (int i = 0; i < U; i++) {
      float w = __expf(lrelu(a[i] + ad) - m) * rr;
      acc = fmaf(w, bf2f(v[i]), acc);
    }
  }
  for (int i = 0; j < deg; j++, i++) {
    float v = bf2f(xwh[(size_t)c[i] * 64 + lane]);
    float w = __expf(lrelu(alh[c[i]] + ad) - m) * rr;
    acc = fmaf(w, v, acc);
  }

  float p = slope_p[0];
  float v = acc + bias[lane];
  out[(size_t)n * 64 + lane] = f2bf((v >= 0.f) ? v : p * v);
}

// ---------------------------------------------------------------------------
// Layer-3 aggregation, one wave per node, unroll-8 pipelined. bf16 rows 256B.
// Mean over heads + log_softmax. al layout [H][ALP].
// ---------------------------------------------------------------------------
__global__ __launch_bounds__(256) void gat_agg3_wave(
    const u16* __restrict__ xwh, const float* __restrict__ alsrc,
    const float* __restrict__ aldst, const int* __restrict__ row_ptr,
    const int* __restrict__ csr_src, const float* __restrict__ bias,
    float* __restrict__ out, int N, int ALP) {
  constexpr int U = 8;
  int n = blockIdx.x * 4 + (threadIdx.x >> 6);
  if (n >= N) return;
  int lane = threadIdx.x & 63;
  int head = lane >> 3, g = lane & 7;
  const float* alh = alsrc + (size_t)head * ALP;
  float ad = aldst[(size_t)head * ALP + n];
  int start = row_ptr[n];
  int end = row_ptr[n + 1];
  int deg = end - start;
  int endm1 = end - 1;

  float m = -1e30f, s = 0.f;
  for (int j = g; j < deg; j += 8) {
    float e = lrelu(alh[csr_src[start + j]] + ad);
    float mn = fmaxf(m, e);
    s = s * __expf(m - mn) + __expf(e - mn);
    m = mn;
  }
#pragma unroll
  for (int st = 1; st <= 4; st <<= 1) {
    float m2 = __shfl_xor(m, st);
    float s2 = __shfl_xor(s, st);
    float mn = fmaxf(m, m2);
    s = s * __expf(m - mn) + s2 * __expf(m2 - mn);
    m = mn;
  }
  float rr = 1.f / (s + 1e-16f);

  float a0 = 0.f, a1 = 0.f;
  int c[U];
#pragma unroll
  for (int i = 0; i < U; i++) c[i] = csr_src[min(start + i, endm1)];
  int j = 0;
  for (; j + U <= deg; j += U) {
    u32 v[U];
    float a[U];
#pragma unroll
    for (int i = 0; i < U; i++) v[i] = *(const u32*)(xwh + (size_t)c[i] * 128 + lane * 2);
#pragma unroll
    for (int i = 0; i < U; i++) a[i] = alh[c[i]];
#pragma unroll
    for (int i = 0; i < U; i++) c[i] = csr_src[min(start + j + U + i, endm1)];
#pragma unroll
    for (int i = 0; i < U; i++) {
      float w = __expf(lrelu(a[i] + ad) - m) * rr;
      a0 = fmaf(w, bf2f(v[i] & 0xffffu), a0);
      a1 = fmaf(w, bf2f(v[i] >> 16), a1);
    }
  }
  for (int i = 0; j < deg; j++, i++) {
    u32 v = *(const u32*)(xwh + (size_t)c[i] * 128 + lane * 2);
    float w = __expf(lrelu(alh[c[i]] + ad) - m) * rr;
    a0 = fmaf(w, bf2f(v & 0xffffu), a0);
    a1 = fmaf(w, bf2f(v >> 16), a1);
  }

#pragma unroll
  for (int st = 8; st <= 32; st <<= 1) {
    a0 += __shfl_xor(a0, st);
    a1 += __shfl_xor(a1, st);
  }
  int c0 = (2 * lane) & 15, c1 = (2 * lane + 1) & 15;
  float v0 = a0 * 0.125f + bias[c0];
  float v1 = a1 * 0.125f + bias[c1];
  float mx = fmaxf(v0, v1);
#pragma unroll
  for (int st = 1; st <= 4; st <<= 1) mx = fmaxf(mx, __shfl_xor(mx, st));
  float se = __expf(v0 - mx) + __expf(v1 - mx);
#pragma unroll
  for (int st = 1; st <= 4; st <<= 1) se += __shfl_xor(se, st);
  float lse = mx + logf(se);
  if (lane < 8) {
    float2 o = make_float2(v0 - lse, v1 - lse);
    *((float2*)(out + (size_t)n * 16) + lane) = o;
  }
}

// ---------------------------------------------------------------------------
extern "C" void kernel_launch(void* const* d_in, const int* in_sizes, int n_in,
                              void* d_out, int out_size, void* d_ws, size_t ws_size,
                              hipStream_t stream) {
  const float* x        = (const float*)d_in[0];
  const int*   ei       = (const int*)d_in[1];
  const float* bn_gamma = (const float*)d_in[2];
  const float* bn_beta  = (const float*)d_in[3];
  const float* W1       = (const float*)d_in[4];
  const float* a1s      = (const float*)d_in[5];
  const float* a1d      = (const float*)d_in[6];
  const float* b1       = (const float*)d_in[7];
  const float* p1       = (const float*)d_in[8];
  const float* W2       = (const float*)d_in[9];
  const float* a2s      = (const float*)d_in[10];
  const float* a2d      = (const float*)d_in[11];
  const float* b2       = (const float*)d_in[12];
  const float* p2       = (const float*)d_in[13];
  const float* W3       = (const float*)d_in[14];
  const float* a3s      = (const float*)d_in[15];
  const float* a3d      = (const float*)d_in[16];
  const float* b3       = (const float*)d_in[17];
  float* out = (float*)d_out;

  const int F  = in_sizes[2];       // 256
  const int N  = in_sizes[0] / F;   // 20000
  const int E  = in_sizes[1] / 2;   // 320000
  const int ET = E + N;
  const int MP = ((N + 127) / 128) * 128;  // MFMA row padding (also al stride)

  size_t off = 0;
  auto alloc = [&](size_t bytes) -> char* {
    char* r = (char*)d_ws + off;
    off += (bytes + 255) & ~(size_t)255;
    return r;
  };
  float* musum   = (float*)alloc(F * 4);
  float* sqsum   = (float*)alloc(F * 4);
  float* scale   = (float*)alloc(F * 4);
  float* shift   = (float*)alloc(F * 4);
  int*   row_ptr = (int*)alloc((size_t)(N + 1) * 4);
  int*   cursor  = (int*)alloc((size_t)N * 4);
  int*   csr_src = (int*)alloc((size_t)ET * 4);
  float* al_s    = (float*)alloc((size_t)16 * MP * 4);
  float* al_d    = (float*)alloc((size_t)16 * MP * 4);
  u16*   Wt1     = (u16*)alloc((size_t)1152 * 256 * 2);
  u16*   Wt2     = (u16*)alloc((size_t)96 * 1280 * 2);
  u16*   Wt3     = (u16*)alloc((size_t)160 * 64 * 2);
  u16*   x_in_h  = (u16*)alloc((size_t)MP * 256 * 2);
  u16*   xw1h    = (u16*)alloc((size_t)MP * 1024 * 2);
  u16*   h1      = (u16*)alloc((size_t)MP * 1024 * 2);
  u16*   xw2h    = (u16*)alloc((size_t)MP * 64 * 2);
  u16*   h2h     = (u16*)alloc((size_t)MP * 64 * 2);
  u16*   xw3h    = (u16*)alloc((size_t)MP * 128 * 2);

  // ---- BatchNorm ----
  hipMemsetAsync(musum, 0, (size_t)2 * F * 4, stream);
  bn_stats_kernel<<<256, 256, 0, stream>>>(x, musum, sqsum, N, F);
  bn_finalize_kernel<<<1, F, 0, stream>>>(musum, sqsum, bn_gamma, bn_beta, scale, shift, N);
  int totalXF = N * F;
  bn_apply_bf16_kernel<<<(totalXF + 255) / 256, 256, 0, stream>>>(x, scale, shift, x_in_h,
                                                                  totalXF, F - 1);

  // ---- CSR by dst ----
  hipMemsetAsync(cursor, 0, (size_t)N * 4, stream);
  csr_count_kernel<<<(ET + 255) / 256, 256, 0, stream>>>(ei, E, N, cursor);
  csr_scan_kernel<<<1, 1024, 0, stream>>>(cursor, row_ptr, cursor, N);
  csr_fill_kernel<<<(ET + 255) / 256, 256, 0, stream>>>(ei, E, N, cursor, csr_src);

  // ---- weight prep ----
  {
    int total = 1024 * 256 + 64 * 1280 + 128 * 64 + 96 * 256 + 32 * 1280 + 32 * 64;
    wt_build_all<<<(total + 255) / 256, 256, 0, stream>>>(W1, W2, W3, Wt1, Wt2, Wt3);
    int tot2 = 32 * 256 + 16 * 1280 + 16 * 64;
    alfold_build<<<(tot2 + 255) / 256, 256, 0, stream>>>(W1, a1s, a1d, W2, a2s, a2d, W3, a3s, a3d,
                                                         Wt1, Wt2, Wt3);
  }

  int nblk = (N + 3) / 4;

  // ---- Layer 1: [N,256]@[256,1024(+32al)] MFMA, H=16, C=64 ----
  {
    dim3 grid(MP / 128, 9);  // 9th tile covers al cols 1024..1151
    mfma_gemm_al<128, 128, 4, 4><<<grid, 256, 0, stream>>>(
        x_in_h, x_in_h, 256, 256, Wt1, xw1h, 1024, al_s, al_d, 32, MP, N);
    // head-sliced, XCD-affine aggregation: grid = 8 xcd * NB nodeblocks * 2 phases
    gat_agg1_hslice<<<8 * nblk * 2, 256, 0, stream>>>(xw1h, al_s, al_d, row_ptr, csr_src, b1, p1,
                                                      h1, N, MP, nblk);
  }

  // ---- Layer 2: concat([x_in,h1]) [N,1280]@[1280,64+16al] MFMA, H=8, C=8 ----
  {
    dim3 grid((N + 63) / 64, 1);
    mfma_gemm_al<64, 96, 2, 3><<<grid, 256, 0, stream>>>(
        x_in_h, h1, 256, 1280, Wt2, xw2h, 64, al_s, al_d, 16, MP, N);
    gat_agg2_wave<<<nblk, 256, 0, stream>>>(xw2h, al_s, al_d, row_ptr, csr_src, b2, p2, h2h, N, MP);
  }

  // ---- Layer 3: [N,64]@[64,128+16al] MFMA, H=8, C=16, mean + log_softmax ----
  {
    dim3 grid((N + 63) / 64, 1);
    mfma_gemm_al<64, 160, 2, 5><<<grid, 256, 0, stream>>>(
        h2h, h2h, 64, 64, Wt3, xw3h, 128, al_s, al_d, 16, MP, N);
    gat_agg3_wave<<<nblk, 256, 0, stream>>>(xw3h, al_s, al_d, row_ptr, csr_src, b3, out, N, MP);
  }
}

// Round 8
// 462.541 us; speedup vs baseline: 1.0471x; 1.0471x over previous
//
#include <hip/hip_runtime.h>
#include <math.h>

typedef unsigned int u32;
typedef unsigned short u16;
typedef u32 u32x4 __attribute__((ext_vector_type(4)));
typedef float f32x4 __attribute__((ext_vector_type(4)));

__device__ __forceinline__ u16 f2bf(float f) {
  u32 u = __builtin_bit_cast(u32, f);
  return (u16)((u + 0x7FFFu + ((u >> 16) & 1u)) >> 16);
}
__device__ __forceinline__ float bf2f(u32 lo16) {
  return __builtin_bit_cast(float, lo16 << 16);
}
__device__ __forceinline__ void mfma16(f32x4& c, const u32x4& a, const u32x4& b) {
  asm volatile("v_mfma_f32_16x16x32_bf16 %0, %1, %2, %0" : "+v"(c) : "v"(a), "v"(b));
}
__device__ __forceinline__ float lrelu(float e) { return fmaxf(e, 0.2f * e); }

// ---------------------------------------------------------------------------
// BatchNorm
// ---------------------------------------------------------------------------
__global__ void bn_stats_kernel(const float* __restrict__ x, float* __restrict__ musum,
                                float* __restrict__ sqsum, int N, int F) {
  int t = threadIdx.x;  // F == 256
  float s = 0.f, s2 = 0.f;
  for (int r = blockIdx.x; r < N; r += gridDim.x) {
    float v = x[(size_t)r * F + t];
    s += v;
    s2 += v * v;
  }
  atomicAdd(&musum[t], s);
  atomicAdd(&sqsum[t], s2);
}

__global__ void bn_finalize_kernel(const float* __restrict__ musum, const float* __restrict__ sqsum,
                                   const float* __restrict__ gamma, const float* __restrict__ beta,
                                   float* __restrict__ scale, float* __restrict__ shift, int N) {
  int t = threadIdx.x;
  float m = musum[t] / (float)N;
  float v = sqsum[t] / (float)N - m * m;
  float sc = gamma[t] * rsqrtf(v + 1e-5f);
  scale[t] = sc;
  shift[t] = beta[t] - m * sc;
}

__global__ void bn_apply_bf16_kernel(const float* __restrict__ x, const float* __restrict__ scale,
                                     const float* __restrict__ shift, u16* __restrict__ xin,
                                     int total, int Fmask) {
  int i = blockIdx.x * blockDim.x + threadIdx.x;
  if (i < total) {
    int c = i & Fmask;
    xin[i] = f2bf(x[i] * scale[c] + shift[c]);
  }
}

// ---------------------------------------------------------------------------
// CSR build (dst-indexed)
// ---------------------------------------------------------------------------
__global__ void csr_count_kernel(const int* __restrict__ ei, int E, int N, int* __restrict__ cnt) {
  int e = blockIdx.x * blockDim.x + threadIdx.x;
  int ET = E + N;
  if (e < ET) {
    int d = (e < E) ? ei[E + e] : (e - E);
    atomicAdd(&cnt[d], 1);
  }
}

__global__ __launch_bounds__(1024) void csr_scan_kernel(const int* __restrict__ cnt,
                                                        int* __restrict__ row_ptr,
                                                        int* __restrict__ cursor, int N) {
  __shared__ int part[1024];
  int t = threadIdx.x;
  int chunk = (N + 1023) / 1024;
  int lo = t * chunk;
  int hi = min(lo + chunk, N);
  int s = 0;
  for (int i = lo; i < hi; i++) s += cnt[i];
  part[t] = s;
  __syncthreads();
  for (int off = 1; off < 1024; off <<= 1) {
    int v = (t >= off) ? part[t - off] : 0;
    __syncthreads();
    part[t] += v;
    __syncthreads();
  }
  int run = (t == 0) ? 0 : part[t - 1];
  for (int i = lo; i < hi; i++) {
    row_ptr[i] = run;
    cursor[i] = run;
    run += cnt[i];
  }
  if (t == 1023) row_ptr[N] = part[1023];
}

__global__ void csr_fill_kernel(const int* __restrict__ ei, int E, int N,
                                int* __restrict__ cursor, int* __restrict__ csr_src) {
  int e = blockIdx.x * blockDim.x + threadIdx.x;
  int ET = E + N;
  if (e < ET) {
    int s, d;
    if (e < E) { s = ei[e]; d = ei[E + e]; }
    else       { s = e - E; d = s; }
    int pos = atomicAdd(&cursor[d], 1);
    csr_src[pos] = s;
  }
}

// ---------------------------------------------------------------------------
// Degree-sorted node permutation (counting sort, 256 buckets, clamp 255).
// Output perm[] groups nodes of equal/similar degree -> zero wave divergence.
// ---------------------------------------------------------------------------
__global__ void deg_hist_kernel(const int* __restrict__ row_ptr, int* __restrict__ hist, int N) {
  int n = blockIdx.x * blockDim.x + threadIdx.x;
  if (n < N) atomicAdd(&hist[min(row_ptr[n + 1] - row_ptr[n], 255)], 1);
}

__global__ void hist_scan_kernel(int* __restrict__ hist) {
  __shared__ int sh[256];
  int t = threadIdx.x;
  sh[t] = hist[t];
  __syncthreads();
  for (int off = 1; off < 256; off <<= 1) {
    int v = (t >= off) ? sh[t - off] : 0;
    __syncthreads();
    sh[t] += v;
    __syncthreads();
  }
  hist[t] = (t == 0) ? 0 : sh[t - 1];  // exclusive base; reused as cursor
}

__global__ void perm_fill_kernel(const int* __restrict__ row_ptr, int* __restrict__ hist,
                                 int* __restrict__ perm, int N) {
  int n = blockIdx.x * blockDim.x + threadIdx.x;
  if (n < N) {
    int d = min(row_ptr[n + 1] - row_ptr[n], 255);
    int pos = atomicAdd(&hist[d], 1);
    perm[pos] = n;
  }
}

// ---------------------------------------------------------------------------
// Weight pre-fragmentation into EXTENDED Wt arrays (bf16, [Nc_tot][K])
// ---------------------------------------------------------------------------
__global__ void wt_build_all(const float* __restrict__ W1, const float* __restrict__ W2,
                             const float* __restrict__ W3, u16* __restrict__ Wt1,
                             u16* __restrict__ Wt2, u16* __restrict__ Wt3) {
  const int S1 = 1024 * 256, S2 = 64 * 1280, S3 = 128 * 64;
  const int P1 = 96 * 256, P2 = 32 * 1280, P3 = 32 * 64;  // pad+al rows zero-init
  int idx = blockIdx.x * blockDim.x + threadIdx.x;
  if (idx < S1) {
    int n = idx / 256, k = idx % 256;
    Wt1[idx] = f2bf(W1[(size_t)k * 1024 + n]);
  } else if (idx < S1 + S2) {
    int i = idx - S1;
    int n = i / 1280, k = i % 1280;
    Wt2[i] = f2bf(W2[(size_t)k * 64 + n]);
  } else if (idx < S1 + S2 + S3) {
    int i = idx - S1 - S2;
    int n = i / 64, k = i % 64;
    Wt3[i] = f2bf(W3[(size_t)k * 128 + n]);
  } else if (idx < S1 + S2 + S3 + P1) {
    Wt1[S1 + (idx - S1 - S2 - S3)] = 0;
  } else if (idx < S1 + S2 + S3 + P1 + P2) {
    Wt2[S2 + (idx - S1 - S2 - S3 - P1)] = 0;
  } else if (idx < S1 + S2 + S3 + P1 + P2 + P3) {
    Wt3[S3 + (idx - S1 - S2 - S3 - P1 - P2)] = 0;
  }
}

// Fold attention vectors: row NcH + 2h (+1) of Wtext = W[:,hC:(h+1)C] @ a_{src,dst}[h]
__global__ void alfold_build(const float* __restrict__ W1, const float* __restrict__ a1s,
                             const float* __restrict__ a1d, const float* __restrict__ W2,
                             const float* __restrict__ a2s, const float* __restrict__ a2d,
                             const float* __restrict__ W3, const float* __restrict__ a3s,
                             const float* __restrict__ a3d, u16* __restrict__ Wt1,
                             u16* __restrict__ Wt2, u16* __restrict__ Wt3) {
  const int T1 = 32 * 256, T2 = 16 * 1280, T3 = 16 * 64;
  int idx = blockIdx.x * blockDim.x + threadIdx.x;
  if (idx < T1) {  // H=16, C=64
    int jj = idx / 256, k = idx % 256, h = jj >> 1;
    const float* av = (jj & 1) ? a1d : a1s;
    float s = 0.f;
    for (int c = 0; c < 64; c++) s += W1[(size_t)k * 1024 + h * 64 + c] * av[h * 64 + c];
    Wt1[(size_t)(1024 + jj) * 256 + k] = f2bf(s);
  } else if (idx < T1 + T2) {  // H=8, C=8
    int i = idx - T1;
    int jj = i / 1280, k = i % 1280, h = jj >> 1;
    const float* av = (jj & 1) ? a2d : a2s;
    float s = 0.f;
    for (int c = 0; c < 8; c++) s += W2[(size_t)k * 64 + h * 8 + c] * av[h * 8 + c];
    Wt2[(size_t)(64 + jj) * 1280 + k] = f2bf(s);
  } else if (idx < T1 + T2 + T3) {  // H=8, C=16
    int i = idx - T1 - T2;
    int jj = i / 64, k = i % 64, h = jj >> 1;
    const float* av = (jj & 1) ? a3d : a3s;
    float s = 0.f;
    for (int c = 0; c < 16; c++) s += W3[(size_t)k * 128 + h * 16 + c] * av[h * 16 + c];
    Wt3[(size_t)(128 + jj) * 64 + k] = f2bf(s);
  }
}

// ---------------------------------------------------------------------------
// bf16 MFMA GEMM with fused al epilogue. Cols < NcH -> bf16 Ch; cols NcH+j ->
// al_{s,d}[j>>1][m] (transposed [H][ALP] layout).
// ---------------------------------------------------------------------------
template <int BM, int BN, int FM, int FN>
__global__ __launch_bounds__(256) void mfma_gemm_al(
    const u16* __restrict__ A1, const u16* __restrict__ A2, int K1, int K,
    const u16* __restrict__ Wt, u16* __restrict__ Ch, int NcH,
    float* __restrict__ als, float* __restrict__ ald, int ALN, int ALP, int M) {
  constexpr int BK = 32;
  constexpr int ACH = (BM * BK) / 8;
  constexpr int BCH = (BN * BK) / 8;
  static_assert(BM == 2 * FM * 16 && BN == 2 * FN * 16, "wave grid 2x2");
  __shared__ u16 As[BM * BK];
  __shared__ u16 Bs[BN * BK];
  int t = threadIdx.x;
  int m0 = blockIdx.x * BM, n0 = blockIdx.y * BN;
  int r = t & 15;
  int g = (t >> 4) & 3;
  int wid = t >> 6;
  int wm0 = (wid >> 1) * (FM * 16);
  int wn0 = (wid & 1) * (FN * 16);
  int K8 = K >> 3;
  int K2 = K - K1;

  f32x4 acc[FM][FN] = {};
  asm volatile("s_nop 7\n\ts_nop 7" :::);  // VALU acc-init -> MFMA SrcC hazard guard

  for (int k0 = 0; k0 < K; k0 += BK) {
    const u16* Aseg;
    int sA, kl;
    if (k0 < K1) { Aseg = A1; sA = K1; kl = k0; }
    else         { Aseg = A2; sA = K2; kl = k0 - K1; }
    __syncthreads();
#pragma unroll
    for (int i = 0; i < (ACH + 255) / 256; i++) {
      int c = i * 256 + t;
      if (ACH % 256 == 0 || c < ACH) {
        int m = c >> 2, kb = c & 3;
        *(u32x4*)(As + c * 8) =
            *(const u32x4*)(Aseg + (size_t)(m0 + m) * sA + kl + kb * 8);
      }
    }
#pragma unroll
    for (int i = 0; i < (BCH + 255) / 256; i++) {
      int c = i * 256 + t;
      if (BCH % 256 == 0 || c < BCH) {
        int nn = c >> 2, kb = c & 3;
        *(u32x4*)(Bs + c * 8) =
            *(const u32x4*)(Wt + ((size_t)(n0 + nn) * K8 + (k0 >> 3) + kb) * 8);
      }
    }
    __syncthreads();
    u32x4 af[FM], bfr[FN];
#pragma unroll
    for (int fi = 0; fi < FM; fi++)
      af[fi] = *(const u32x4*)(As + ((wm0 + fi * 16 + r) * 4 + g) * 8);
#pragma unroll
    for (int fj = 0; fj < FN; fj++)
      bfr[fj] = *(const u32x4*)(Bs + ((wn0 + fj * 16 + r) * 4 + g) * 8);
#pragma unroll
    for (int fi = 0; fi < FM; fi++)
#pragma unroll
      for (int fj = 0; fj < FN; fj++) mfma16(acc[fi][fj], af[fi], bfr[fj]);
  }
  asm volatile("s_nop 7\n\ts_nop 7" :::);  // MFMA -> VALU read hazard guard

#pragma unroll
  for (int fi = 0; fi < FM; fi++) {
#pragma unroll
    for (int fj = 0; fj < FN; fj++) {
#pragma unroll
      for (int v = 0; v < 4; v++) {
        int m = m0 + wm0 + fi * 16 + g * 4 + v;
        int nn = n0 + wn0 + fj * 16 + r;
        if (m < M) {
          float val = acc[fi][fj][v];
          if (nn < NcH) {
            Ch[(size_t)m * NcH + nn] = f2bf(val);
          } else {
            int j = nn - NcH;
            if (j < ALN) ((j & 1) ? ald : als)[(size_t)(j >> 1) * ALP + m] = val;
          }
        }
      }
    }
  }
}

// ---------------------------------------------------------------------------
// Layer-1 aggregation: GROUP-SLICED + XCD-affine.
// Wave = 8 tasks (8 degree-matched nodes via perm, SAME head h).
// head h = (blockIdx&7) + 8*phase -> each XCD's L2 holds one 2.56MB col slice.
// 8-lane group covers the head's 64 cols as dwordx4 (16B/lane).
// ---------------------------------------------------------------------------
__global__ __launch_bounds__(256) void gat_agg1_gs(
    const u16* __restrict__ xwh, const float* __restrict__ alsrc,
    const float* __restrict__ aldst, const int* __restrict__ row_ptr,
    const int* __restrict__ csr_src, const int* __restrict__ perm,
    const float* __restrict__ bias, const float* __restrict__ slope_p,
    u16* __restrict__ out, int N, int ALP, int NBH) {
  constexpr int U = 4;
  int b = blockIdx.x;
  int xcd = b & 7, seq = b >> 3;
  int phase = seq / NBH, nb = seq - phase * NBH;
  int h = xcd + (phase << 3);
  int lane = threadIdx.x & 63;
  int g = lane >> 3, l8 = lane & 7;
  int ti = nb * 32 + (threadIdx.x >> 6) * 8 + g;
  int n = perm[min(ti, N - 1)];
  const float* alh = alsrc + (size_t)h * ALP;
  float ad = aldst[(size_t)h * ALP + n];
  int start = row_ptr[n];
  int end = row_ptr[n + 1];
  int deg = (ti < N) ? end - start : 0;
  int endm1 = end - 1;

  // phase A: softmax stats, 8 lanes stride the group's edge list
  float m = -1e30f, s = 0.f;
  for (int j = l8; j < deg; j += 8) {
    float e = lrelu(alh[csr_src[start + j]] + ad);
    float mn = fmaxf(m, e);
    s = s * __expf(m - mn) + __expf(e - mn);
    m = mn;
  }
#pragma unroll
  for (int st = 1; st <= 4; st <<= 1) {
    float m2 = __shfl_xor(m, st);
    float s2 = __shfl_xor(s, st);
    float mn = fmaxf(m, m2);
    s = s * __expf(m - mn) + s2 * __expf(m2 - mn);
    m = mn;
  }
  float rr = 1.f / (s + 1e-16f);

  // phase B: unroll-4 pipelined gather, 16B/lane
  float acc[8] = {};
  const u16* base = xwh + (size_t)h * 64 + (size_t)l8 * 8;

  auto fma8 = [&](const u32x4& v, float w) {
#pragma unroll
    for (int i = 0; i < 4; i++) {
      u32 u = v[i];
      acc[2 * i] = fmaf(w, bf2f(u & 0xffffu), acc[2 * i]);
      acc[2 * i + 1] = fmaf(w, bf2f(u >> 16), acc[2 * i + 1]);
    }
  };

  int c[U];
#pragma unroll
  for (int i = 0; i < U; i++) c[i] = csr_src[min(start + i, endm1)];
  int j = 0;
  for (; j + U <= deg; j += U) {
    u32x4 v[U];
    float a[U];
#pragma unroll
    for (int i = 0; i < U; i++) v[i] = *(const u32x4*)(base + (size_t)c[i] * 1024);
#pragma unroll
    for (int i = 0; i < U; i++) a[i] = alh[c[i]];
#pragma unroll
    for (int i = 0; i < U; i++) c[i] = csr_src[min(start + j + U + i, endm1)];
#pragma unroll
    for (int i = 0; i < U; i++) {
      float w = __expf(lrelu(a[i] + ad) - m) * rr;
      fma8(v[i], w);
    }
  }
  for (int i = 0; j < deg; j++, i++) {
    u32x4 v = *(const u32x4*)(base + (size_t)c[i] * 1024);
    float w = __expf(lrelu(alh[c[i]] + ad) - m) * rr;
    fma8(v, w);
  }

  if (ti < N) {
    float p = slope_p[0];
    u32 ow[4];
#pragma unroll
    for (int i = 0; i < 4; i++) {
      int cc = h * 64 + l8 * 8 + 2 * i;
      float v0 = acc[2 * i] + bias[cc];
      float v1 = acc[2 * i + 1] + bias[cc + 1];
      v0 = (v0 >= 0.f) ? v0 : p * v0;
      v1 = (v1 >= 0.f) ? v1 : p * v1;
      ow[i] = (u32)f2bf(v0) | ((u32)f2bf(v1) << 16);
    }
    *(u32x4*)(out + (size_t)n * 1024 + h * 64 + l8 * 8) = *(u32x4*)ow;
  }
}

// ---------------------------------------------------------------------------
// Layer-2 aggregation, one wave per node, unroll-8 pipelined. bf16 rows 128B.
// al layout [H][ALP].
// ---------------------------------------------------------------------------
__global__ __launch_bounds__(256) void gat_agg2_wave(
    const u16* __restrict__ xwh, const float* __restrict__ alsrc,
    const float* __restrict__ aldst, const int* __restrict__ row_ptr,
    const int* __restrict__ csr_src, const float* __restrict__ bias,
    const float* __restrict__ slope_p, u16* __restrict__ out, int N, int ALP) {
  constexpr int U = 8;
  int n = blockIdx.x * 4 + (threadIdx.x >> 6);
  if (n >= N) return;
  int lane = threadIdx.x & 63;
  int head = lane >> 3, g = lane & 7;
  const float* alh = alsrc + (size_t)head * ALP;
  float ad = aldst[(size_t)head * ALP + n];
  int start = row_ptr[n];
  int end = row_ptr[n + 1];
  int deg = end - start;
  int endm1 = end - 1;

  float m = -1e30f, s = 0.f;
  for (int j = g; j < deg; j += 8) {
    float e = lrelu(alh[csr_src[start + j]] + ad);
    float mn = fmaxf(m, e);
    s = s * __expf(m - mn) + __expf(e - mn);
    m = mn;
  }
#pragma unroll
  for (int st = 1; st <= 4; st <<= 1) {
    float m2 = __shfl_xor(m, st);
    float s2 = __shfl_xor(s, st);
    float mn = fmaxf(m, m2);
    s = s * __expf(m - mn) + s2 * __expf(m2 - mn);
    m = mn;
  }
  float rr = 1.f / (s + 1e-16f);

  float acc = 0.f;
  int c[U];
#pragma unroll
  for (int i = 0; i < U; i++) c[i] = csr_src[min(start + i, endm1)];
  int j = 0;
  for (; j + U <= deg; j += U) {
    u16 v[U];
    float a[U];
#pragma unroll
    for (int i = 0; i < U; i++) v[i] = xwh[(size_t)c[i] * 64 + lane];
#pragma unroll
    for (int i = 0; i < U; i++) a[i] = alh[c[i]];
#pragma unroll
    for (int i = 0; i < U; i++) c[i] = csr_src[min(start + j + U + i, endm1)];
#pragma unroll
    for (int i = 0; i < U; i++) {
      float w = __expf(lrelu(a[i] + ad) - m) * rr;
      acc = fmaf(w, bf2f(v[i]), acc);
    }
  }
  for (int i = 0; j < deg; j++, i++) {
    float v = bf2f(xwh[(size_t)c[i] * 64 + lane]);
    float w = __expf(lrelu(alh[c[i]] + ad) - m) * rr;
    acc = fmaf(w, v, acc);
  }

  float p = slope_p[0];
  float v = acc + bias[lane];
  out[(size_t)n * 64 + lane] = f2bf((v >= 0.f) ? v : p * v);
}

// ---------------------------------------------------------------------------
// Layer-3 aggregation, one wave per node, unroll-8 pipelined. bf16 rows 256B.
// Mean over heads + log_softmax. al layout [H][ALP].
// ---------------------------------------------------------------------------
__global__ __launch_bounds__(256) void gat_agg3_wave(
    const u16* __restrict__ xwh, const float* __restrict__ alsrc,
    const float* __restrict__ aldst, const int* __restrict__ row_ptr,
    const int* __restrict__ csr_src, const float* __restrict__ bias,
    float* __restrict__ out, int N, int ALP) {
  constexpr int U = 8;
  int n = blockIdx.x * 4 + (threadIdx.x >> 6);
  if (n >= N) return;
  int lane = threadIdx.x & 63;
  int head = lane >> 3, g = lane & 7;
  const float* alh = alsrc + (size_t)head * ALP;
  float ad = aldst[(size_t)head * ALP + n];
  int start = row_ptr[n];
  int end = row_ptr[n + 1];
  int deg = end - start;
  int endm1 = end - 1;

  float m = -1e30f, s = 0.f;
  for (int j = g; j < deg; j += 8) {
    float e = lrelu(alh[csr_src[start + j]] + ad);
    float mn = fmaxf(m, e);
    s = s * __expf(m - mn) + __expf(e - mn);
    m = mn;
  }
#pragma unroll
  for (int st = 1; st <= 4; st <<= 1) {
    float m2 = __shfl_xor(m, st);
    float s2 = __shfl_xor(s, st);
    float mn = fmaxf(m, m2);
    s = s * __expf(m - mn) + s2 * __expf(m2 - mn);
    m = mn;
  }
  float rr = 1.f / (s + 1e-16f);

  float a0 = 0.f, a1 = 0.f;
  int c[U];
#pragma unroll
  for (int i = 0; i < U; i++) c[i] = csr_src[min(start + i, endm1)];
  int j = 0;
  for (; j + U <= deg; j += U) {
    u32 v[U];
    float a[U];
#pragma unroll
    for (int i = 0; i < U; i++) v[i] = *(const u32*)(xwh + (size_t)c[i] * 128 + lane * 2);
#pragma unroll
    for (int i = 0; i < U; i++) a[i] = alh[c[i]];
#pragma unroll
    for (int i = 0; i < U; i++) c[i] = csr_src[min(start + j + U + i, endm1)];
#pragma unroll
    for (int i = 0; i < U; i++) {
      float w = __expf(lrelu(a[i] + ad) - m) * rr;
      a0 = fmaf(w, bf2f(v[i] & 0xffffu), a0);
      a1 = fmaf(w, bf2f(v[i] >> 16), a1);
    }
  }
  for (int i = 0; j < deg; j++, i++) {
    u32 v = *(const u32*)(xwh + (size_t)c[i] * 128 + lane * 2);
    float w = __expf(lrelu(alh[c[i]] + ad) - m) * rr;
    a0 = fmaf(w, bf2f(v & 0xffffu), a0);
    a1 = fmaf(w, bf2f(v >> 16), a1);
  }

#pragma unroll
  for (int st = 8; st <= 32; st <<= 1) {
    a0 += __shfl_xor(a0, st);
    a1 += __shfl_xor(a1, st);
  }
  int c0 = (2 * lane) & 15, c1 = (2 * lane + 1) & 15;
  float v0 = a0 * 0.125f + bias[c0];
  float v1 = a1 * 0.125f + bias[c1];
  float mx = fmaxf(v0, v1);
#pragma unroll
  for (int st = 1; st <= 4; st <<= 1) mx = fmaxf(mx, __shfl_xor(mx, st));
  float se = __expf(v0 - mx) + __expf(v1 - mx);
#pragma unroll
  for (int st = 1; st <= 4; st <<= 1) se += __shfl_xor(se, st);
  float lse = mx + logf(se);
  if (lane < 8) {
    float2 o = make_float2(v0 - lse, v1 - lse);
    *((float2*)(out + (size_t)n * 16) + lane) = o;
  }
}

// ---------------------------------------------------------------------------
extern "C" void kernel_launch(void* const* d_in, const int* in_sizes, int n_in,
                              void* d_out, int out_size, void* d_ws, size_t ws_size,
                              hipStream_t stream) {
  const float* x        = (const float*)d_in[0];
  const int*   ei       = (const int*)d_in[1];
  const float* bn_gamma = (const float*)d_in[2];
  const float* bn_beta  = (const float*)d_in[3];
  const float* W1       = (const float*)d_in[4];
  const float* a1s      = (const float*)d_in[5];
  const float* a1d      = (const float*)d_in[6];
  const float* b1       = (const float*)d_in[7];
  const float* p1       = (const float*)d_in[8];
  const float* W2       = (const float*)d_in[9];
  const float* a2s      = (const float*)d_in[10];
  const float* a2d      = (const float*)d_in[11];
  const float* b2       = (const float*)d_in[12];
  const float* p2       = (const float*)d_in[13];
  const float* W3       = (const float*)d_in[14];
  const float* a3s      = (const float*)d_in[15];
  const float* a3d      = (const float*)d_in[16];
  const float* b3       = (const float*)d_in[17];
  float* out = (float*)d_out;

  const int F  = in_sizes[2];       // 256
  const int N  = in_sizes[0] / F;   // 20000
  const int E  = in_sizes[1] / 2;   // 320000
  const int ET = E + N;
  const int MP = ((N + 127) / 128) * 128;  // MFMA row padding (also al stride)

  size_t off = 0;
  auto alloc = [&](size_t bytes) -> char* {
    char* r = (char*)d_ws + off;
    off += (bytes + 255) & ~(size_t)255;
    return r;
  };
  float* musum   = (float*)alloc(F * 4);
  float* sqsum   = (float*)alloc(F * 4);
  float* scale   = (float*)alloc(F * 4);
  float* shift   = (float*)alloc(F * 4);
  int*   row_ptr = (int*)alloc((size_t)(N + 1) * 4);
  int*   cursor  = (int*)alloc((size_t)N * 4);
  int*   csr_src = (int*)alloc((size_t)ET * 4);
  int*   hist    = (int*)alloc((size_t)256 * 4);
  int*   perm    = (int*)alloc((size_t)N * 4);
  float* al_s    = (float*)alloc((size_t)16 * MP * 4);
  float* al_d    = (float*)alloc((size_t)16 * MP * 4);
  u16*   Wt1     = (u16*)alloc((size_t)1152 * 256 * 2);
  u16*   Wt2     = (u16*)alloc((size_t)96 * 1280 * 2);
  u16*   Wt3     = (u16*)alloc((size_t)160 * 64 * 2);
  u16*   x_in_h  = (u16*)alloc((size_t)MP * 256 * 2);
  u16*   xw1h    = (u16*)alloc((size_t)MP * 1024 * 2);
  u16*   h1      = (u16*)alloc((size_t)MP * 1024 * 2);
  u16*   xw2h    = (u16*)alloc((size_t)MP * 64 * 2);
  u16*   h2h     = (u16*)alloc((size_t)MP * 64 * 2);
  u16*   xw3h    = (u16*)alloc((size_t)MP * 128 * 2);

  // ---- BatchNorm ----
  hipMemsetAsync(musum, 0, (size_t)2 * F * 4, stream);
  bn_stats_kernel<<<256, 256, 0, stream>>>(x, musum, sqsum, N, F);
  bn_finalize_kernel<<<1, F, 0, stream>>>(musum, sqsum, bn_gamma, bn_beta, scale, shift, N);
  int totalXF = N * F;
  bn_apply_bf16_kernel<<<(totalXF + 255) / 256, 256, 0, stream>>>(x, scale, shift, x_in_h,
                                                                  totalXF, F - 1);

  // ---- CSR by dst ----
  hipMemsetAsync(cursor, 0, (size_t)N * 4, stream);
  csr_count_kernel<<<(ET + 255) / 256, 256, 0, stream>>>(ei, E, N, cursor);
  csr_scan_kernel<<<1, 1024, 0, stream>>>(cursor, row_ptr, cursor, N);
  csr_fill_kernel<<<(ET + 255) / 256, 256, 0, stream>>>(ei, E, N, cursor, csr_src);

  // ---- degree-sorted node permutation ----
  hipMemsetAsync(hist, 0, 256 * 4, stream);
  deg_hist_kernel<<<(N + 255) / 256, 256, 0, stream>>>(row_ptr, hist, N);
  hist_scan_kernel<<<1, 256, 0, stream>>>(hist);
  perm_fill_kernel<<<(N + 255) / 256, 256, 0, stream>>>(row_ptr, hist, perm, N);

  // ---- weight prep ----
  {
    int total = 1024 * 256 + 64 * 1280 + 128 * 64 + 96 * 256 + 32 * 1280 + 32 * 64;
    wt_build_all<<<(total + 255) / 256, 256, 0, stream>>>(W1, W2, W3, Wt1, Wt2, Wt3);
    int tot2 = 32 * 256 + 16 * 1280 + 16 * 64;
    alfold_build<<<(tot2 + 255) / 256, 256, 0, stream>>>(W1, a1s, a1d, W2, a2s, a2d, W3, a3s, a3d,
                                                         Wt1, Wt2, Wt3);
  }

  int nblk = (N + 3) / 4;

  // ---- Layer 1: [N,256]@[256,1024(+32al)] MFMA, H=16, C=64 ----
  {
    dim3 grid(MP / 128, 9);  // 9th tile covers al cols 1024..1151
    mfma_gemm_al<128, 128, 4, 4><<<grid, 256, 0, stream>>>(
        x_in_h, x_in_h, 256, 256, Wt1, xw1h, 1024, al_s, al_d, 32, MP, N);
    int NBH = (N + 31) / 32;  // node-32-blocks per head
    gat_agg1_gs<<<8 * NBH * 2, 256, 0, stream>>>(xw1h, al_s, al_d, row_ptr, csr_src, perm, b1, p1,
                                                 h1, N, MP, NBH);
  }

  // ---- Layer 2: concat([x_in,h1]) [N,1280]@[1280,64+16al] MFMA, H=8, C=8 ----
  {
    dim3 grid((N + 63) / 64, 1);
    mfma_gemm_al<64, 96, 2, 3><<<grid, 256, 0, stream>>>(
        x_in_h, h1, 256, 1280, Wt2, xw2h, 64, al_s, al_d, 16, MP, N);
    gat_agg2_wave<<<nblk, 256, 0, stream>>>(xw2h, al_s, al_d, row_ptr, csr_src, b2, p2, h2h, N, MP);
  }

  // ---- Layer 3: [N,64]@[64,128+16al] MFMA, H=8, C=16, mean + log_softmax ----
  {
    dim3 grid((N + 63) / 64, 1);
    mfma_gemm_al<64, 160, 2, 5><<<grid, 256, 0, stream>>>(
        h2h, h2h, 64, 64, Wt3, xw3h, 128, al_s, al_d, 16, MP, N);
    gat_agg3_wave<<<nblk, 256, 0, stream>>>(xw3h, al_s, al_d, row_ptr, csr_src, b3, out, N, MP);
  }
}

// Round 9
// 327.094 us; speedup vs baseline: 1.4807x; 1.4141x over previous
//
#include <hip/hip_runtime.h>
#include <math.h>

typedef unsigned int u32;
typedef unsigned short u16;
typedef u32 u32x4 __attribute__((ext_vector_type(4)));
typedef float f32x4 __attribute__((ext_vector_type(4)));

__device__ __forceinline__ u16 f2bf(float f) {
  u32 u = __builtin_bit_cast(u32, f);
  return (u16)((u + 0x7FFFu + ((u >> 16) & 1u)) >> 16);
}
__device__ __forceinline__ float bf2f(u32 lo16) {
  return __builtin_bit_cast(float, lo16 << 16);
}
__device__ __forceinline__ void mfma16(f32x4& c, const u32x4& a, const u32x4& b) {
  asm volatile("v_mfma_f32_16x16x32_bf16 %0, %1, %2, %0" : "+v"(c) : "v"(a), "v"(b));
}
__device__ __forceinline__ float lrelu(float e) { return fmaxf(e, 0.2f * e); }

// ---------------------------------------------------------------------------
// BatchNorm
// ---------------------------------------------------------------------------
__global__ void bn_stats_kernel(const float* __restrict__ x, float* __restrict__ musum,
                                float* __restrict__ sqsum, int N, int F) {
  int t = threadIdx.x;  // F == 256
  float s = 0.f, s2 = 0.f;
  for (int r = blockIdx.x; r < N; r += gridDim.x) {
    float v = x[(size_t)r * F + t];
    s += v;
    s2 += v * v;
  }
  atomicAdd(&musum[t], s);
  atomicAdd(&sqsum[t], s2);
}

__global__ void bn_finalize_kernel(const float* __restrict__ musum, const float* __restrict__ sqsum,
                                   const float* __restrict__ gamma, const float* __restrict__ beta,
                                   float* __restrict__ scale, float* __restrict__ shift, int N) {
  int t = threadIdx.x;
  float m = musum[t] / (float)N;
  float v = sqsum[t] / (float)N - m * m;
  float sc = gamma[t] * rsqrtf(v + 1e-5f);
  scale[t] = sc;
  shift[t] = beta[t] - m * sc;
}

__global__ void bn_apply_bf16_kernel(const float* __restrict__ x, const float* __restrict__ scale,
                                     const float* __restrict__ shift, u16* __restrict__ xin,
                                     int total, int Fmask) {
  int i = blockIdx.x * blockDim.x + threadIdx.x;
  if (i < total) {
    int c = i & Fmask;
    xin[i] = f2bf(x[i] * scale[c] + shift[c]);
  }
}

// ---------------------------------------------------------------------------
// CSR build (dst-indexed)
// ---------------------------------------------------------------------------
__global__ void csr_count_kernel(const int* __restrict__ ei, int E, int N, int* __restrict__ cnt) {
  int e = blockIdx.x * blockDim.x + threadIdx.x;
  int ET = E + N;
  if (e < ET) {
    int d = (e < E) ? ei[E + e] : (e - E);
    atomicAdd(&cnt[d], 1);
  }
}

__global__ __launch_bounds__(1024) void csr_scan_kernel(const int* __restrict__ cnt,
                                                        int* __restrict__ row_ptr,
                                                        int* __restrict__ cursor, int N) {
  __shared__ int part[1024];
  int t = threadIdx.x;
  int chunk = (N + 1023) / 1024;
  int lo = t * chunk;
  int hi = min(lo + chunk, N);
  int s = 0;
  for (int i = lo; i < hi; i++) s += cnt[i];
  part[t] = s;
  __syncthreads();
  for (int off = 1; off < 1024; off <<= 1) {
    int v = (t >= off) ? part[t - off] : 0;
    __syncthreads();
    part[t] += v;
    __syncthreads();
  }
  int run = (t == 0) ? 0 : part[t - 1];
  for (int i = lo; i < hi; i++) {
    row_ptr[i] = run;
    cursor[i] = run;
    run += cnt[i];
  }
  if (t == 1023) row_ptr[N] = part[1023];
}

__global__ void csr_fill_kernel(const int* __restrict__ ei, int E, int N,
                                int* __restrict__ cursor, int* __restrict__ csr_src) {
  int e = blockIdx.x * blockDim.x + threadIdx.x;
  int ET = E + N;
  if (e < ET) {
    int s, d;
    if (e < E) { s = ei[e]; d = ei[E + e]; }
    else       { s = e - E; d = s; }
    int pos = atomicAdd(&cursor[d], 1);
    csr_src[pos] = s;
  }
}

// ---------------------------------------------------------------------------
// Degree-sorted node permutation: SINGLE-BLOCK LDS counting sort (256 bins).
// Replaces the global-atomic hist/scan/fill trio (same-address global atomics
// on the modal degree bin serialized ~60us/kernel; LDS atomics are ~2cy).
// ---------------------------------------------------------------------------
__global__ __launch_bounds__(1024) void perm_build_kernel(const int* __restrict__ row_ptr,
                                                          int* __restrict__ perm, int N) {
  __shared__ int bins[256];
  __shared__ int base[256];
  int t = threadIdx.x;
  if (t < 256) bins[t] = 0;
  __syncthreads();
  for (int i = t; i < N; i += 1024) {
    int d = min(row_ptr[i + 1] - row_ptr[i], 255);
    atomicAdd(&bins[d], 1);
  }
  __syncthreads();
  for (int off = 1; off < 256; off <<= 1) {
    int u = (t < 256 && t >= off) ? bins[t - off] : 0;
    __syncthreads();
    if (t < 256) bins[t] += u;
    __syncthreads();
  }
  if (t < 256) base[t] = (t == 0) ? 0 : bins[t - 1];
  __syncthreads();
  if (t < 256) bins[t] = base[t];  // cursor
  __syncthreads();
  for (int i = t; i < N; i += 1024) {
    int d = min(row_ptr[i + 1] - row_ptr[i], 255);
    int pos = atomicAdd(&bins[d], 1);
    perm[pos] = i;
  }
}

// ---------------------------------------------------------------------------
// Weight pre-fragmentation into EXTENDED Wt arrays (bf16, [Nc_tot][K])
// ---------------------------------------------------------------------------
__global__ void wt_build_all(const float* __restrict__ W1, const float* __restrict__ W2,
                             const float* __restrict__ W3, u16* __restrict__ Wt1,
                             u16* __restrict__ Wt2, u16* __restrict__ Wt3) {
  const int S1 = 1024 * 256, S2 = 64 * 1280, S3 = 128 * 64;
  const int P1 = 96 * 256, P2 = 32 * 1280, P3 = 32 * 64;  // pad+al rows zero-init
  int idx = blockIdx.x * blockDim.x + threadIdx.x;
  if (idx < S1) {
    int n = idx / 256, k = idx % 256;
    Wt1[idx] = f2bf(W1[(size_t)k * 1024 + n]);
  } else if (idx < S1 + S2) {
    int i = idx - S1;
    int n = i / 1280, k = i % 1280;
    Wt2[i] = f2bf(W2[(size_t)k * 64 + n]);
  } else if (idx < S1 + S2 + S3) {
    int i = idx - S1 - S2;
    int n = i / 64, k = i % 64;
    Wt3[i] = f2bf(W3[(size_t)k * 128 + n]);
  } else if (idx < S1 + S2 + S3 + P1) {
    Wt1[S1 + (idx - S1 - S2 - S3)] = 0;
  } else if (idx < S1 + S2 + S3 + P1 + P2) {
    Wt2[S2 + (idx - S1 - S2 - S3 - P1)] = 0;
  } else if (idx < S1 + S2 + S3 + P1 + P2 + P3) {
    Wt3[S3 + (idx - S1 - S2 - S3 - P1 - P2)] = 0;
  }
}

// Fold attention vectors: row NcH + 2h (+1) of Wtext = W[:,hC:(h+1)C] @ a_{src,dst}[h]
__global__ void alfold_build(const float* __restrict__ W1, const float* __restrict__ a1s,
                             const float* __restrict__ a1d, const float* __restrict__ W2,
                             const float* __restrict__ a2s, const float* __restrict__ a2d,
                             const float* __restrict__ W3, const float* __restrict__ a3s,
                             const float* __restrict__ a3d, u16* __restrict__ Wt1,
                             u16* __restrict__ Wt2, u16* __restrict__ Wt3) {
  const int T1 = 32 * 256, T2 = 16 * 1280, T3 = 16 * 64;
  int idx = blockIdx.x * blockDim.x + threadIdx.x;
  if (idx < T1) {  // H=16, C=64
    int jj = idx / 256, k = idx % 256, h = jj >> 1;
    const float* av = (jj & 1) ? a1d : a1s;
    float s = 0.f;
    for (int c = 0; c < 64; c++) s += W1[(size_t)k * 1024 + h * 64 + c] * av[h * 64 + c];
    Wt1[(size_t)(1024 + jj) * 256 + k] = f2bf(s);
  } else if (idx < T1 + T2) {  // H=8, C=8
    int i = idx - T1;
    int jj = i / 1280, k = i % 1280, h = jj >> 1;
    const float* av = (jj & 1) ? a2d : a2s;
    float s = 0.f;
    for (int c = 0; c < 8; c++) s += W2[(size_t)k * 64 + h * 8 + c] * av[h * 8 + c];
    Wt2[(size_t)(64 + jj) * 1280 + k] = f2bf(s);
  } else if (idx < T1 + T2 + T3) {  // H=8, C=16
    int i = idx - T1 - T2;
    int jj = i / 64, k = i % 64, h = jj >> 1;
    const float* av = (jj & 1) ? a3d : a3s;
    float s = 0.f;
    for (int c = 0; c < 16; c++) s += W3[(size_t)k * 128 + h * 16 + c] * av[h * 16 + c];
    Wt3[(size_t)(128 + jj) * 64 + k] = f2bf(s);
  }
}

// ---------------------------------------------------------------------------
// bf16 MFMA GEMM with fused al epilogue. Cols < NcH -> bf16 Ch; cols NcH+j ->
// al_{s,d}[j>>1][m] (transposed [H][ALP] layout).
// ---------------------------------------------------------------------------
template <int BM, int BN, int FM, int FN>
__global__ __launch_bounds__(256) void mfma_gemm_al(
    const u16* __restrict__ A1, const u16* __restrict__ A2, int K1, int K,
    const u16* __restrict__ Wt, u16* __restrict__ Ch, int NcH,
    float* __restrict__ als, float* __restrict__ ald, int ALN, int ALP, int M) {
  constexpr int BK = 32;
  constexpr int ACH = (BM * BK) / 8;
  constexpr int BCH = (BN * BK) / 8;
  static_assert(BM == 2 * FM * 16 && BN == 2 * FN * 16, "wave grid 2x2");
  __shared__ u16 As[BM * BK];
  __shared__ u16 Bs[BN * BK];
  int t = threadIdx.x;
  int m0 = blockIdx.x * BM, n0 = blockIdx.y * BN;
  int r = t & 15;
  int g = (t >> 4) & 3;
  int wid = t >> 6;
  int wm0 = (wid >> 1) * (FM * 16);
  int wn0 = (wid & 1) * (FN * 16);
  int K8 = K >> 3;
  int K2 = K - K1;

  f32x4 acc[FM][FN] = {};
  asm volatile("s_nop 7\n\ts_nop 7" :::);  // VALU acc-init -> MFMA SrcC hazard guard

  for (int k0 = 0; k0 < K; k0 += BK) {
    const u16* Aseg;
    int sA, kl;
    if (k0 < K1) { Aseg = A1; sA = K1; kl = k0; }
    else         { Aseg = A2; sA = K2; kl = k0 - K1; }
    __syncthreads();
#pragma unroll
    for (int i = 0; i < (ACH + 255) / 256; i++) {
      int c = i * 256 + t;
      if (ACH % 256 == 0 || c < ACH) {
        int m = c >> 2, kb = c & 3;
        *(u32x4*)(As + c * 8) =
            *(const u32x4*)(Aseg + (size_t)(m0 + m) * sA + kl + kb * 8);
      }
    }
#pragma unroll
    for (int i = 0; i < (BCH + 255) / 256; i++) {
      int c = i * 256 + t;
      if (BCH % 256 == 0 || c < BCH) {
        int nn = c >> 2, kb = c & 3;
        *(u32x4*)(Bs + c * 8) =
            *(const u32x4*)(Wt + ((size_t)(n0 + nn) * K8 + (k0 >> 3) + kb) * 8);
      }
    }
    __syncthreads();
    u32x4 af[FM], bfr[FN];
#pragma unroll
    for (int fi = 0; fi < FM; fi++)
      af[fi] = *(const u32x4*)(As + ((wm0 + fi * 16 + r) * 4 + g) * 8);
#pragma unroll
    for (int fj = 0; fj < FN; fj++)
      bfr[fj] = *(const u32x4*)(Bs + ((wn0 + fj * 16 + r) * 4 + g) * 8);
#pragma unroll
    for (int fi = 0; fi < FM; fi++)
#pragma unroll
      for (int fj = 0; fj < FN; fj++) mfma16(acc[fi][fj], af[fi], bfr[fj]);
  }
  asm volatile("s_nop 7\n\ts_nop 7" :::);  // MFMA -> VALU read hazard guard

#pragma unroll
  for (int fi = 0; fi < FM; fi++) {
#pragma unroll
    for (int fj = 0; fj < FN; fj++) {
#pragma unroll
      for (int v = 0; v < 4; v++) {
        int m = m0 + wm0 + fi * 16 + g * 4 + v;
        int nn = n0 + wn0 + fj * 16 + r;
        if (m < M) {
          float val = acc[fi][fj][v];
          if (nn < NcH) {
            Ch[(size_t)m * NcH + nn] = f2bf(val);
          } else {
            int j = nn - NcH;
            if (j < ALN) ((j & 1) ? ald : als)[(size_t)(j >> 1) * ALP + m] = val;
          }
        }
      }
    }
  }
}

// ---------------------------------------------------------------------------
// Layer-1 aggregation: GROUP-SLICED + XCD-affine + ONE-PASS online softmax.
// Wave = 8 tasks (degree-matched nodes via perm, SAME head h).
// Rescale amortized once per U-batch.
// ---------------------------------------------------------------------------
__global__ __launch_bounds__(256) void gat_agg1_gs(
    const u16* __restrict__ xwh, const float* __restrict__ alsrc,
    const float* __restrict__ aldst, const int* __restrict__ row_ptr,
    const int* __restrict__ csr_src, const int* __restrict__ perm,
    const float* __restrict__ bias, const float* __restrict__ slope_p,
    u16* __restrict__ out, int N, int ALP, int NBH) {
  constexpr int U = 4;
  int b = blockIdx.x;
  int xcd = b & 7, seq = b >> 3;
  int phase = seq / NBH, nb = seq - phase * NBH;
  int h = xcd + (phase << 3);
  int lane = threadIdx.x & 63;
  int g = lane >> 3, l8 = lane & 7;
  int ti = nb * 32 + (threadIdx.x >> 6) * 8 + g;
  int n = perm[min(ti, N - 1)];
  const float* alh = alsrc + (size_t)h * ALP;
  float ad = aldst[(size_t)h * ALP + n];
  int start = row_ptr[n];
  int end = row_ptr[n + 1];
  int deg = (ti < N) ? end - start : 0;
  int endm1 = end - 1;

  float m = -1e30f, s = 0.f;
  float acc[8] = {};
  const u16* base = xwh + (size_t)h * 64 + (size_t)l8 * 8;

  auto fma8 = [&](const u32x4& v, float w) {
#pragma unroll
    for (int i = 0; i < 4; i++) {
      u32 u = v[i];
      acc[2 * i] = fmaf(w, bf2f(u & 0xffffu), acc[2 * i]);
      acc[2 * i + 1] = fmaf(w, bf2f(u >> 16), acc[2 * i + 1]);
    }
  };

  int c[U];
#pragma unroll
  for (int i = 0; i < U; i++) c[i] = csr_src[min(start + i, endm1)];
  int j = 0;
  for (; j + U <= deg; j += U) {
    u32x4 v[U];
    float e[U];
#pragma unroll
    for (int i = 0; i < U; i++) v[i] = *(const u32x4*)(base + (size_t)c[i] * 1024);
#pragma unroll
    for (int i = 0; i < U; i++) e[i] = lrelu(alh[c[i]] + ad);
#pragma unroll
    for (int i = 0; i < U; i++) c[i] = csr_src[min(start + j + U + i, endm1)];
    float mn = fmaxf(fmaxf(e[0], e[1]), fmaxf(e[2], e[3]));
    if (mn > m) {
      float sc = __expf(m - mn);
      s *= sc;
#pragma unroll
      for (int k = 0; k < 8; k++) acc[k] *= sc;
      m = mn;
    }
#pragma unroll
    for (int i = 0; i < U; i++) {
      float w = __expf(e[i] - m);
      s += w;
      fma8(v[i], w);
    }
  }
  for (int i = 0; j < deg; j++, i++) {
    u32x4 v = *(const u32x4*)(base + (size_t)c[i] * 1024);
    float e = lrelu(alh[c[i]] + ad);
    if (e > m) {
      float sc = __expf(m - e);
      s *= sc;
#pragma unroll
      for (int k = 0; k < 8; k++) acc[k] *= sc;
      m = e;
    }
    float w = __expf(e - m);
    s += w;
    fma8(v, w);
  }
  float rr = 1.f / (s + 1e-16f);

  if (ti < N) {
    float p = slope_p[0];
    u32 ow[4];
#pragma unroll
    for (int i = 0; i < 4; i++) {
      int cc = h * 64 + l8 * 8 + 2 * i;
      float v0 = acc[2 * i] * rr + bias[cc];
      float v1 = acc[2 * i + 1] * rr + bias[cc + 1];
      v0 = (v0 >= 0.f) ? v0 : p * v0;
      v1 = (v1 >= 0.f) ? v1 : p * v1;
      ow[i] = (u32)f2bf(v0) | ((u32)f2bf(v1) << 16);
    }
    *(u32x4*)(out + (size_t)n * 1024 + h * 64 + l8 * 8) = *(u32x4*)ow;
  }
}

// ---------------------------------------------------------------------------
// Layer-2 aggregation, one wave per node, ONE-PASS online softmax, U=8.
// bf16 rows 128B; al layout [H][ALP]; lane = col, head = lane>>3.
// ---------------------------------------------------------------------------
__global__ __launch_bounds__(256) void gat_agg2_wave(
    const u16* __restrict__ xwh, const float* __restrict__ alsrc,
    const float* __restrict__ aldst, const int* __restrict__ row_ptr,
    const int* __restrict__ csr_src, const float* __restrict__ bias,
    const float* __restrict__ slope_p, u16* __restrict__ out, int N, int ALP) {
  constexpr int U = 8;
  int n = blockIdx.x * 4 + (threadIdx.x >> 6);
  if (n >= N) return;
  int lane = threadIdx.x & 63;
  int head = lane >> 3;
  const float* alh = alsrc + (size_t)head * ALP;
  float ad = aldst[(size_t)head * ALP + n];
  int start = row_ptr[n];
  int end = row_ptr[n + 1];
  int deg = end - start;
  int endm1 = end - 1;

  float m = -1e30f, s = 0.f, acc = 0.f;
  int c[U];
#pragma unroll
  for (int i = 0; i < U; i++) c[i] = csr_src[min(start + i, endm1)];
  int j = 0;
  for (; j + U <= deg; j += U) {
    u16 v[U];
    float e[U];
#pragma unroll
    for (int i = 0; i < U; i++) v[i] = xwh[(size_t)c[i] * 64 + lane];
#pragma unroll
    for (int i = 0; i < U; i++) e[i] = lrelu(alh[c[i]] + ad);
#pragma unroll
    for (int i = 0; i < U; i++) c[i] = csr_src[min(start + j + U + i, endm1)];
    float mn = e[0];
#pragma unroll
    for (int i = 1; i < U; i++) mn = fmaxf(mn, e[i]);
    if (mn > m) {
      float sc = __expf(m - mn);
      s *= sc;
      acc *= sc;
      m = mn;
    }
#pragma unroll
    for (int i = 0; i < U; i++) {
      float w = __expf(e[i] - m);
      s += w;
      acc = fmaf(w, bf2f(v[i]), acc);
    }
  }
  for (int i = 0; j < deg; j++, i++) {
    float vv = bf2f(xwh[(size_t)c[i] * 64 + lane]);
    float e = lrelu(alh[c[i]] + ad);
    if (e > m) {
      float sc = __expf(m - e);
      s *= sc;
      acc *= sc;
      m = e;
    }
    float w = __expf(e - m);
    s += w;
    acc = fmaf(w, vv, acc);
  }
  float rr = 1.f / (s + 1e-16f);

  float p = slope_p[0];
  float v = acc * rr + bias[lane];
  out[(size_t)n * 64 + lane] = f2bf((v >= 0.f) ? v : p * v);
}

// ---------------------------------------------------------------------------
// Layer-3 aggregation, one wave per node, ONE-PASS online softmax, U=8.
// bf16 rows 256B; mean over heads + log_softmax; al layout [H][ALP].
// ---------------------------------------------------------------------------
__global__ __launch_bounds__(256) void gat_agg3_wave(
    const u16* __restrict__ xwh, const float* __restrict__ alsrc,
    const float* __restrict__ aldst, const int* __restrict__ row_ptr,
    const int* __restrict__ csr_src, const float* __restrict__ bias,
    float* __restrict__ out, int N, int ALP) {
  constexpr int U = 8;
  int n = blockIdx.x * 4 + (threadIdx.x >> 6);
  if (n >= N) return;
  int lane = threadIdx.x & 63;
  int head = lane >> 3;
  const float* alh = alsrc + (size_t)head * ALP;
  float ad = aldst[(size_t)head * ALP + n];
  int start = row_ptr[n];
  int end = row_ptr[n + 1];
  int deg = end - start;
  int endm1 = end - 1;

  float m = -1e30f, s = 0.f, a0 = 0.f, a1 = 0.f;
  int c[U];
#pragma unroll
  for (int i = 0; i < U; i++) c[i] = csr_src[min(start + i, endm1)];
  int j = 0;
  for (; j + U <= deg; j += U) {
    u32 v[U];
    float e[U];
#pragma unroll
    for (int i = 0; i < U; i++) v[i] = *(const u32*)(xwh + (size_t)c[i] * 128 + lane * 2);
#pragma unroll
    for (int i = 0; i < U; i++) e[i] = lrelu(alh[c[i]] + ad);
#pragma unroll
    for (int i = 0; i < U; i++) c[i] = csr_src[min(start + j + U + i, endm1)];
    float mn = e[0];
#pragma unroll
    for (int i = 1; i < U; i++) mn = fmaxf(mn, e[i]);
    if (mn > m) {
      float sc = __expf(m - mn);
      s *= sc;
      a0 *= sc;
      a1 *= sc;
      m = mn;
    }
#pragma unroll
    for (int i = 0; i < U; i++) {
      float w = __expf(e[i] - m);
      s += w;
      a0 = fmaf(w, bf2f(v[i] & 0xffffu), a0);
      a1 = fmaf(w, bf2f(v[i] >> 16), a1);
    }
  }
  for (int i = 0; j < deg; j++, i++) {
    u32 v = *(const u32*)(xwh + (size_t)c[i] * 128 + lane * 2);
    float e = lrelu(alh[c[i]] + ad);
    if (e > m) {
      float sc = __expf(m - e);
      s *= sc;
      a0 *= sc;
      a1 *= sc;
      m = e;
    }
    float w = __expf(e - m);
    s += w;
    a0 = fmaf(w, bf2f(v & 0xffffu), a0);
    a1 = fmaf(w, bf2f(v >> 16), a1);
  }
  float rr = 1.f / (s + 1e-16f);
  a0 *= rr;
  a1 *= rr;

  // sum across heads (bits 3..5 of lane select the head)
#pragma unroll
  for (int st = 8; st <= 32; st <<= 1) {
    a0 += __shfl_xor(a0, st);
    a1 += __shfl_xor(a1, st);
  }
  int c0 = (2 * lane) & 15, c1 = (2 * lane + 1) & 15;
  float v0 = a0 * 0.125f + bias[c0];
  float v1 = a1 * 0.125f + bias[c1];
  float mx = fmaxf(v0, v1);
#pragma unroll
  for (int st = 1; st <= 4; st <<= 1) mx = fmaxf(mx, __shfl_xor(mx, st));
  float se = __expf(v0 - mx) + __expf(v1 - mx);
#pragma unroll
  for (int st = 1; st <= 4; st <<= 1) se += __shfl_xor(se, st);
  float lse = mx + logf(se);
  if (lane < 8) {
    float2 o = make_float2(v0 - lse, v1 - lse);
    *((float2*)(out + (size_t)n * 16) + lane) = o;
  }
}

// ---------------------------------------------------------------------------
extern "C" void kernel_launch(void* const* d_in, const int* in_sizes, int n_in,
                              void* d_out, int out_size, void* d_ws, size_t ws_size,
                              hipStream_t stream) {
  const float* x        = (const float*)d_in[0];
  const int*   ei       = (const int*)d_in[1];
  const float* bn_gamma = (const float*)d_in[2];
  const float* bn_beta  = (const float*)d_in[3];
  const float* W1       = (const float*)d_in[4];
  const float* a1s      = (const float*)d_in[5];
  const float* a1d      = (const float*)d_in[6];
  const float* b1       = (const float*)d_in[7];
  const float* p1       = (const float*)d_in[8];
  const float* W2       = (const float*)d_in[9];
  const float* a2s      = (const float*)d_in[10];
  const float* a2d      = (const float*)d_in[11];
  const float* b2       = (const float*)d_in[12];
  const float* p2       = (const float*)d_in[13];
  const float* W3       = (const float*)d_in[14];
  const float* a3s      = (const float*)d_in[15];
  const float* a3d      = (const float*)d_in[16];
  const float* b3       = (const float*)d_in[17];
  float* out = (float*)d_out;

  const int F  = in_sizes[2];       // 256
  const int N  = in_sizes[0] / F;   // 20000
  const int E  = in_sizes[1] / 2;   // 320000
  const int ET = E + N;
  const int MP = ((N + 127) / 128) * 128;  // MFMA row padding (also al stride)

  size_t off = 0;
  auto alloc = [&](size_t bytes) -> char* {
    char* r = (char*)d_ws + off;
    off += (bytes + 255) & ~(size_t)255;
    return r;
  };
  float* musum   = (float*)alloc(F * 4);
  float* sqsum   = (float*)alloc(F * 4);
  float* scale   = (float*)alloc(F * 4);
  float* shift   = (float*)alloc(F * 4);
  int*   row_ptr = (int*)alloc((size_t)(N + 1) * 4);
  int*   cursor  = (int*)alloc((size_t)N * 4);
  int*   csr_src = (int*)alloc((size_t)ET * 4);
  int*   perm    = (int*)alloc((size_t)N * 4);
  float* al_s    = (float*)alloc((size_t)16 * MP * 4);
  float* al_d    = (float*)alloc((size_t)16 * MP * 4);
  u16*   Wt1     = (u16*)alloc((size_t)1152 * 256 * 2);
  u16*   Wt2     = (u16*)alloc((size_t)96 * 1280 * 2);
  u16*   Wt3     = (u16*)alloc((size_t)160 * 64 * 2);
  u16*   x_in_h  = (u16*)alloc((size_t)MP * 256 * 2);
  u16*   xw1h    = (u16*)alloc((size_t)MP * 1024 * 2);
  u16*   h1      = (u16*)alloc((size_t)MP * 1024 * 2);
  u16*   xw2h    = (u16*)alloc((size_t)MP * 64 * 2);
  u16*   h2h     = (u16*)alloc((size_t)MP * 64 * 2);
  u16*   xw3h    = (u16*)alloc((size_t)MP * 128 * 2);

  // ---- BatchNorm ----
  hipMemsetAsync(musum, 0, (size_t)2 * F * 4, stream);
  bn_stats_kernel<<<256, 256, 0, stream>>>(x, musum, sqsum, N, F);
  bn_finalize_kernel<<<1, F, 0, stream>>>(musum, sqsum, bn_gamma, bn_beta, scale, shift, N);
  int totalXF = N * F;
  bn_apply_bf16_kernel<<<(totalXF + 255) / 256, 256, 0, stream>>>(x, scale, shift, x_in_h,
                                                                  totalXF, F - 1);

  // ---- CSR by dst ----
  hipMemsetAsync(cursor, 0, (size_t)N * 4, stream);
  csr_count_kernel<<<(ET + 255) / 256, 256, 0, stream>>>(ei, E, N, cursor);
  csr_scan_kernel<<<1, 1024, 0, stream>>>(cursor, row_ptr, cursor, N);
  csr_fill_kernel<<<(ET + 255) / 256, 256, 0, stream>>>(ei, E, N, cursor, csr_src);

  // ---- degree-sorted node permutation (single-block LDS counting sort) ----
  perm_build_kernel<<<1, 1024, 0, stream>>>(row_ptr, perm, N);

  // ---- weight prep ----
  {
    int total = 1024 * 256 + 64 * 1280 + 128 * 64 + 96 * 256 + 32 * 1280 + 32 * 64;
    wt_build_all<<<(total + 255) / 256, 256, 0, stream>>>(W1, W2, W3, Wt1, Wt2, Wt3);
    int tot2 = 32 * 256 + 16 * 1280 + 16 * 64;
    alfold_build<<<(tot2 + 255) / 256, 256, 0, stream>>>(W1, a1s, a1d, W2, a2s, a2d, W3, a3s, a3d,
                                                         Wt1, Wt2, Wt3);
  }

  int nblk = (N + 3) / 4;

  // ---- Layer 1: [N,256]@[256,1024(+32al)] MFMA, H=16, C=64 ----
  {
    dim3 grid(MP / 128, 9);  // 9th tile covers al cols 1024..1151
    mfma_gemm_al<128, 128, 4, 4><<<grid, 256, 0, stream>>>(
        x_in_h, x_in_h, 256, 256, Wt1, xw1h, 1024, al_s, al_d, 32, MP, N);
    int NBH = (N + 31) / 32;  // node-32-blocks per head
    gat_agg1_gs<<<8 * NBH * 2, 256, 0, stream>>>(xw1h, al_s, al_d, row_ptr, csr_src, perm, b1, p1,
                                                 h1, N, MP, NBH);
  }

  // ---- Layer 2: concat([x_in,h1]) [N,1280]@[1280,64+16al] MFMA, H=8, C=8 ----
  {
    dim3 grid((N + 63) / 64, 1);
    mfma_gemm_al<64, 96, 2, 3><<<grid, 256, 0, stream>>>(
        x_in_h, h1, 256, 1280, Wt2, xw2h, 64, al_s, al_d, 16, MP, N);
    gat_agg2_wave<<<nblk, 256, 0, stream>>>(xw2h, al_s, al_d, row_ptr, csr_src, b2, p2, h2h, N, MP);
  }

  // ---- Layer 3: [N,64]@[64,128+16al] MFMA, H=8, C=16, mean + log_softmax ----
  {
    dim3 grid((N + 63) / 64, 1);
    mfma_gemm_al<64, 160, 2, 5><<<grid, 256, 0, stream>>>(
        h2h, h2h, 64, 64, Wt3, xw3h, 128, al_s, al_d, 16, MP, N);
    gat_agg3_wave<<<nblk, 256, 0, stream>>>(xw3h, al_s, al_d, row_ptr, csr_src, b3, out, N, MP);
  }
}

// Round 10
// 316.328 us; speedup vs baseline: 1.5311x; 1.0340x over previous
//
#include <hip/hip_runtime.h>
#include <math.h>

typedef unsigned int u32;
typedef unsigned short u16;
typedef u32 u32x4 __attribute__((ext_vector_type(4)));
typedef float f32x4 __attribute__((ext_vector_type(4)));

__device__ __forceinline__ u16 f2bf(float f) {
  u32 u = __builtin_bit_cast(u32, f);
  return (u16)((u + 0x7FFFu + ((u >> 16) & 1u)) >> 16);
}
__device__ __forceinline__ float bf2f(u32 lo16) {
  return __builtin_bit_cast(float, lo16 << 16);
}
__device__ __forceinline__ void mfma16(f32x4& c, const u32x4& a, const u32x4& b) {
  asm volatile("v_mfma_f32_16x16x32_bf16 %0, %1, %2, %0" : "+v"(c) : "v"(a), "v"(b));
}
__device__ __forceinline__ float lrelu(float e) { return fmaxf(e, 0.2f * e); }

// ---------------------------------------------------------------------------
// BatchNorm
// ---------------------------------------------------------------------------
__global__ void bn_stats_kernel(const float* __restrict__ x, float* __restrict__ musum,
                                float* __restrict__ sqsum, int N, int F) {
  int t = threadIdx.x;  // F == 256
  float s = 0.f, s2 = 0.f;
  for (int r = blockIdx.x; r < N; r += gridDim.x) {
    float v = x[(size_t)r * F + t];
    s += v;
    s2 += v * v;
  }
  atomicAdd(&musum[t], s);
  atomicAdd(&sqsum[t], s2);
}

__global__ void bn_finalize_kernel(const float* __restrict__ musum, const float* __restrict__ sqsum,
                                   const float* __restrict__ gamma, const float* __restrict__ beta,
                                   float* __restrict__ scale, float* __restrict__ shift, int N) {
  int t = threadIdx.x;
  float m = musum[t] / (float)N;
  float v = sqsum[t] / (float)N - m * m;
  float sc = gamma[t] * rsqrtf(v + 1e-5f);
  scale[t] = sc;
  shift[t] = beta[t] - m * sc;
}

__global__ void bn_apply_bf16_kernel(const float* __restrict__ x, const float* __restrict__ scale,
                                     const float* __restrict__ shift, u16* __restrict__ xin,
                                     int total, int Fmask) {
  int i = blockIdx.x * blockDim.x + threadIdx.x;
  if (i < total) {
    int c = i & Fmask;
    xin[i] = f2bf(x[i] * scale[c] + shift[c]);
  }
}

// ---------------------------------------------------------------------------
// CSR build (dst-indexed)
// ---------------------------------------------------------------------------
__global__ void csr_count_kernel(const int* __restrict__ ei, int E, int N, int* __restrict__ cnt) {
  int e = blockIdx.x * blockDim.x + threadIdx.x;
  int ET = E + N;
  if (e < ET) {
    int d = (e < E) ? ei[E + e] : (e - E);
    atomicAdd(&cnt[d], 1);
  }
}

__global__ __launch_bounds__(1024) void csr_scan_kernel(const int* __restrict__ cnt,
                                                        int* __restrict__ row_ptr,
                                                        int* __restrict__ cursor, int N) {
  __shared__ int part[1024];
  int t = threadIdx.x;
  int chunk = (N + 1023) / 1024;
  int lo = t * chunk;
  int hi = min(lo + chunk, N);
  int s = 0;
  for (int i = lo; i < hi; i++) s += cnt[i];
  part[t] = s;
  __syncthreads();
  for (int off = 1; off < 1024; off <<= 1) {
    int v = (t >= off) ? part[t - off] : 0;
    __syncthreads();
    part[t] += v;
    __syncthreads();
  }
  int run = (t == 0) ? 0 : part[t - 1];
  for (int i = lo; i < hi; i++) {
    row_ptr[i] = run;
    cursor[i] = run;
    run += cnt[i];
  }
  if (t == 1023) row_ptr[N] = part[1023];
}

__global__ void csr_fill_kernel(const int* __restrict__ ei, int E, int N,
                                int* __restrict__ cursor, int* __restrict__ csr_src) {
  int e = blockIdx.x * blockDim.x + threadIdx.x;
  int ET = E + N;
  if (e < ET) {
    int s, d;
    if (e < E) { s = ei[e]; d = ei[E + e]; }
    else       { s = e - E; d = s; }
    int pos = atomicAdd(&cursor[d], 1);
    csr_src[pos] = s;
  }
}

// ---------------------------------------------------------------------------
// Degree-sorted node permutation: single-block LDS counting sort (256 bins).
// ---------------------------------------------------------------------------
__global__ __launch_bounds__(1024) void perm_build_kernel(const int* __restrict__ row_ptr,
                                                          int* __restrict__ perm, int N) {
  __shared__ int bins[256];
  __shared__ int base[256];
  int t = threadIdx.x;
  if (t < 256) bins[t] = 0;
  __syncthreads();
  for (int i = t; i < N; i += 1024) {
    int d = min(row_ptr[i + 1] - row_ptr[i], 255);
    atomicAdd(&bins[d], 1);
  }
  __syncthreads();
  for (int off = 1; off < 256; off <<= 1) {
    int u = (t < 256 && t >= off) ? bins[t - off] : 0;
    __syncthreads();
    if (t < 256) bins[t] += u;
    __syncthreads();
  }
  if (t < 256) base[t] = (t == 0) ? 0 : bins[t - 1];
  __syncthreads();
  if (t < 256) bins[t] = base[t];  // cursor
  __syncthreads();
  for (int i = t; i < N; i += 1024) {
    int d = min(row_ptr[i + 1] - row_ptr[i], 255);
    int pos = atomicAdd(&bins[d], 1);
    perm[pos] = i;
  }
}

// ---------------------------------------------------------------------------
// Weight pre-fragmentation into EXTENDED Wt arrays (bf16, [Nc_tot][K])
// ---------------------------------------------------------------------------
__global__ void wt_build_all(const float* __restrict__ W1, const float* __restrict__ W2,
                             const float* __restrict__ W3, u16* __restrict__ Wt1,
                             u16* __restrict__ Wt2, u16* __restrict__ Wt3) {
  const int S1 = 1024 * 256, S2 = 64 * 1280, S3 = 128 * 64;
  const int P1 = 96 * 256, P2 = 32 * 1280, P3 = 32 * 64;  // pad+al rows zero-init
  int idx = blockIdx.x * blockDim.x + threadIdx.x;
  if (idx < S1) {
    int n = idx / 256, k = idx % 256;
    Wt1[idx] = f2bf(W1[(size_t)k * 1024 + n]);
  } else if (idx < S1 + S2) {
    int i = idx - S1;
    int n = i / 1280, k = i % 1280;
    Wt2[i] = f2bf(W2[(size_t)k * 64 + n]);
  } else if (idx < S1 + S2 + S3) {
    int i = idx - S1 - S2;
    int n = i / 64, k = i % 64;
    Wt3[i] = f2bf(W3[(size_t)k * 128 + n]);
  } else if (idx < S1 + S2 + S3 + P1) {
    Wt1[S1 + (idx - S1 - S2 - S3)] = 0;
  } else if (idx < S1 + S2 + S3 + P1 + P2) {
    Wt2[S2 + (idx - S1 - S2 - S3 - P1)] = 0;
  } else if (idx < S1 + S2 + S3 + P1 + P2 + P3) {
    Wt3[S3 + (idx - S1 - S2 - S3 - P1 - P2)] = 0;
  }
}

// Fold attention vectors: row NcH + 2h (+1) of Wtext = W[:,hC:(h+1)C] @ a_{src,dst}[h]
__global__ void alfold_build(const float* __restrict__ W1, const float* __restrict__ a1s,
                             const float* __restrict__ a1d, const float* __restrict__ W2,
                             const float* __restrict__ a2s, const float* __restrict__ a2d,
                             const float* __restrict__ W3, const float* __restrict__ a3s,
                             const float* __restrict__ a3d, u16* __restrict__ Wt1,
                             u16* __restrict__ Wt2, u16* __restrict__ Wt3) {
  const int T1 = 32 * 256, T2 = 16 * 1280, T3 = 16 * 64;
  int idx = blockIdx.x * blockDim.x + threadIdx.x;
  if (idx < T1) {  // H=16, C=64
    int jj = idx / 256, k = idx % 256, h = jj >> 1;
    const float* av = (jj & 1) ? a1d : a1s;
    float s = 0.f;
    for (int c = 0; c < 64; c++) s += W1[(size_t)k * 1024 + h * 64 + c] * av[h * 64 + c];
    Wt1[(size_t)(1024 + jj) * 256 + k] = f2bf(s);
  } else if (idx < T1 + T2) {  // H=8, C=8
    int i = idx - T1;
    int jj = i / 1280, k = i % 1280, h = jj >> 1;
    const float* av = (jj & 1) ? a2d : a2s;
    float s = 0.f;
    for (int c = 0; c < 8; c++) s += W2[(size_t)k * 64 + h * 8 + c] * av[h * 8 + c];
    Wt2[(size_t)(64 + jj) * 1280 + k] = f2bf(s);
  } else if (idx < T1 + T2 + T3) {  // H=8, C=16
    int i = idx - T1 - T2;
    int jj = i / 64, k = i % 64, h = jj >> 1;
    const float* av = (jj & 1) ? a3d : a3s;
    float s = 0.f;
    for (int c = 0; c < 16; c++) s += W3[(size_t)k * 128 + h * 16 + c] * av[h * 16 + c];
    Wt3[(size_t)(128 + jj) * 64 + k] = f2bf(s);
  }
}

// ---------------------------------------------------------------------------
// bf16 MFMA GEMM, double-buffered LDS via global_load_lds (width 16), one
// barrier per K-step. Fused al epilogue: cols < NcH -> bf16 Ch; cols NcH+j ->
// al_{s,d}[j>>1][m] (transposed [H][ALP]).
// ---------------------------------------------------------------------------
template <int BM, int BN, int FM, int FN>
__global__ __launch_bounds__(256) void mfma_gemm_al(
    const u16* __restrict__ A1, const u16* __restrict__ A2, int K1, int K,
    const u16* __restrict__ Wt, u16* __restrict__ Ch, int NcH,
    float* __restrict__ als, float* __restrict__ ald, int ALN, int ALP, int M) {
  constexpr int BK = 32;
  constexpr int ACH = (BM * BK) / 8;  // 16B chunks in A tile
  constexpr int BCH = (BN * BK) / 8;
  static_assert(BM == 2 * FM * 16 && BN == 2 * FN * 16, "wave grid 2x2");
  __shared__ u16 As[2][BM * BK];
  __shared__ u16 Bs[2][BN * BK];
  int t = threadIdx.x;
  int m0 = blockIdx.x * BM, n0 = blockIdx.y * BN;
  int r = t & 15;
  int g = (t >> 4) & 3;
  int wid = t >> 6;
  int wm0 = (wid >> 1) * (FM * 16);
  int wn0 = (wid & 1) * (FN * 16);
  int K8 = K >> 3;
  int K2 = K - K1;

  // async global->LDS staging for K-step k0 into buffer `buf`.
  // LDS dest is linear: chunk c at byte c*16 == wave-uniform base + lane*16.
  auto stage = [&](int buf, int k0) {
    const u16* Aseg;
    int sA, kl;
    if (k0 < K1) { Aseg = A1; sA = K1; kl = k0; }
    else         { Aseg = A2; sA = K2; kl = k0 - K1; }
#pragma unroll
    for (int i = 0; i < (ACH + 255) / 256; i++) {
      int c = i * 256 + t;
      if (ACH % 256 == 0 || c < ACH) {
        int m = c >> 2, kb = c & 3;
        __builtin_amdgcn_global_load_lds(
            (const __attribute__((address_space(1))) void*)(Aseg + (size_t)(m0 + m) * sA + kl + kb * 8),
            (__attribute__((address_space(3))) void*)(&As[buf][c * 8]), 16, 0, 0);
      }
    }
#pragma unroll
    for (int i = 0; i < (BCH + 255) / 256; i++) {
      int c = i * 256 + t;
      if (BCH % 256 == 0 || c < BCH) {
        int nn = c >> 2, kb = c & 3;
        __builtin_amdgcn_global_load_lds(
            (const __attribute__((address_space(1))) void*)(Wt + ((size_t)(n0 + nn) * K8 + (k0 >> 3) + kb) * 8),
            (__attribute__((address_space(3))) void*)(&Bs[buf][c * 8]), 16, 0, 0);
      }
    }
  };

  f32x4 acc[FM][FN] = {};
  asm volatile("s_nop 7\n\ts_nop 7" :::);  // VALU acc-init -> MFMA SrcC hazard guard

  stage(0, 0);
  __syncthreads();  // vmcnt(0) drain + barrier: tile 0 resident
  int nt = K / BK;
  for (int ts = 0; ts < nt; ts++) {
    if (ts + 1 < nt) stage((ts + 1) & 1, (ts + 1) * BK);  // overlap with compute
    int cur = ts & 1;
    u32x4 af[FM], bfr[FN];
#pragma unroll
    for (int fi = 0; fi < FM; fi++)
      af[fi] = *(const u32x4*)(&As[cur][((wm0 + fi * 16 + r) * 4 + g) * 8]);
#pragma unroll
    for (int fj = 0; fj < FN; fj++)
      bfr[fj] = *(const u32x4*)(&Bs[cur][((wn0 + fj * 16 + r) * 4 + g) * 8]);
#pragma unroll
    for (int fi = 0; fi < FM; fi++)
#pragma unroll
      for (int fj = 0; fj < FN; fj++) mfma16(acc[fi][fj], af[fi], bfr[fj]);
    __syncthreads();  // drains vmcnt (next tile ready) + all ds_reads of cur done
  }
  asm volatile("s_nop 7\n\ts_nop 7" :::);  // MFMA -> VALU read hazard guard

#pragma unroll
  for (int fi = 0; fi < FM; fi++) {
#pragma unroll
    for (int fj = 0; fj < FN; fj++) {
#pragma unroll
      for (int v = 0; v < 4; v++) {
        int m = m0 + wm0 + fi * 16 + g * 4 + v;
        int nn = n0 + wn0 + fj * 16 + r;
        if (m < M) {
          float val = acc[fi][fj][v];
          if (nn < NcH) {
            Ch[(size_t)m * NcH + nn] = f2bf(val);
          } else {
            int j = nn - NcH;
            if (j < ALN) ((j & 1) ? ald : als)[(size_t)(j >> 1) * ALP + m] = val;
          }
        }
      }
    }
  }
}

// ---------------------------------------------------------------------------
// Layer-1 aggregation: GROUP-SLICED + XCD-affine + one-pass online softmax.
// Wave = 8 degree-matched nodes (perm), same head h = (blockIdx&7)+8*phase.
// ---------------------------------------------------------------------------
__global__ __launch_bounds__(256) void gat_agg1_gs(
    const u16* __restrict__ xwh, const float* __restrict__ alsrc,
    const float* __restrict__ aldst, const int* __restrict__ row_ptr,
    const int* __restrict__ csr_src, const int* __restrict__ perm,
    const float* __restrict__ bias, const float* __restrict__ slope_p,
    u16* __restrict__ out, int N, int ALP, int NBH) {
  constexpr int U = 4;
  int b = blockIdx.x;
  int xcd = b & 7, seq = b >> 3;
  int phase = seq / NBH, nb = seq - phase * NBH;
  int h = xcd + (phase << 3);
  int lane = threadIdx.x & 63;
  int g = lane >> 3, l8 = lane & 7;
  int ti = nb * 32 + (threadIdx.x >> 6) * 8 + g;
  int n = perm[min(ti, N - 1)];
  const float* alh = alsrc + (size_t)h * ALP;
  float ad = aldst[(size_t)h * ALP + n];
  int start = row_ptr[n];
  int end = row_ptr[n + 1];
  int deg = (ti < N) ? end - start : 0;
  int endm1 = end - 1;

  float m = -1e30f, s = 0.f;
  float acc[8] = {};
  const u16* base = xwh + (size_t)h * 64 + (size_t)l8 * 8;

  auto fma8 = [&](const u32x4& v, float w) {
#pragma unroll
    for (int i = 0; i < 4; i++) {
      u32 u = v[i];
      acc[2 * i] = fmaf(w, bf2f(u & 0xffffu), acc[2 * i]);
      acc[2 * i + 1] = fmaf(w, bf2f(u >> 16), acc[2 * i + 1]);
    }
  };

  int c[U];
#pragma unroll
  for (int i = 0; i < U; i++) c[i] = csr_src[min(start + i, endm1)];
  int j = 0;
  for (; j + U <= deg; j += U) {
    u32x4 v[U];
    float e[U];
#pragma unroll
    for (int i = 0; i < U; i++) v[i] = *(const u32x4*)(base + (size_t)c[i] * 1024);
#pragma unroll
    for (int i = 0; i < U; i++) e[i] = lrelu(alh[c[i]] + ad);
#pragma unroll
    for (int i = 0; i < U; i++) c[i] = csr_src[min(start + j + U + i, endm1)];
    float mn = fmaxf(fmaxf(e[0], e[1]), fmaxf(e[2], e[3]));
    if (mn > m) {
      float sc = __expf(m - mn);
      s *= sc;
#pragma unroll
      for (int k = 0; k < 8; k++) acc[k] *= sc;
      m = mn;
    }
#pragma unroll
    for (int i = 0; i < U; i++) {
      float w = __expf(e[i] - m);
      s += w;
      fma8(v[i], w);
    }
  }
  for (int i = 0; j < deg; j++, i++) {
    u32x4 v = *(const u32x4*)(base + (size_t)c[i] * 1024);
    float e = lrelu(alh[c[i]] + ad);
    if (e > m) {
      float sc = __expf(m - e);
      s *= sc;
#pragma unroll
      for (int k = 0; k < 8; k++) acc[k] *= sc;
      m = e;
    }
    float w = __expf(e - m);
    s += w;
    fma8(v, w);
  }
  float rr = 1.f / (s + 1e-16f);

  if (ti < N) {
    float p = slope_p[0];
    u32 ow[4];
#pragma unroll
    for (int i = 0; i < 4; i++) {
      int cc = h * 64 + l8 * 8 + 2 * i;
      float v0 = acc[2 * i] * rr + bias[cc];
      float v1 = acc[2 * i + 1] * rr + bias[cc + 1];
      v0 = (v0 >= 0.f) ? v0 : p * v0;
      v1 = (v1 >= 0.f) ? v1 : p * v1;
      ow[i] = (u32)f2bf(v0) | ((u32)f2bf(v1) << 16);
    }
    *(u32x4*)(out + (size_t)n * 1024 + h * 64 + l8 * 8) = *(u32x4*)ow;
  }
}

// ---------------------------------------------------------------------------
// Layer-2 aggregation: wave = 8 degree-matched nodes, lane = 8 cols of one
// node (head = lane&7 since C=8), dwordx4 row loads, one-pass online softmax.
// ---------------------------------------------------------------------------
__global__ __launch_bounds__(256) void gat_agg2_gs(
    const u16* __restrict__ xwh, const float* __restrict__ alsrc,
    const float* __restrict__ aldst, const int* __restrict__ row_ptr,
    const int* __restrict__ csr_src, const int* __restrict__ perm,
    const float* __restrict__ bias, const float* __restrict__ slope_p,
    u16* __restrict__ out, int N, int ALP) {
  constexpr int U = 4;
  int lane = threadIdx.x & 63;
  int g = lane >> 3, l8 = lane & 7;  // l8 = col-block = head
  int ti = blockIdx.x * 32 + (threadIdx.x >> 6) * 8 + g;
  int n = perm[min(ti, N - 1)];
  const float* alh = alsrc + (size_t)l8 * ALP;
  float ad = aldst[(size_t)l8 * ALP + n];
  int start = row_ptr[n];
  int end = row_ptr[n + 1];
  int deg = (ti < N) ? end - start : 0;
  int endm1 = end - 1;

  float m = -1e30f, s = 0.f;
  float acc[8] = {};
  const u16* base = xwh + (size_t)l8 * 8;

  auto fma8 = [&](const u32x4& v, float w) {
#pragma unroll
    for (int i = 0; i < 4; i++) {
      u32 u = v[i];
      acc[2 * i] = fmaf(w, bf2f(u & 0xffffu), acc[2 * i]);
      acc[2 * i + 1] = fmaf(w, bf2f(u >> 16), acc[2 * i + 1]);
    }
  };

  int c[U];
#pragma unroll
  for (int i = 0; i < U; i++) c[i] = csr_src[min(start + i, endm1)];
  int j = 0;
  for (; j + U <= deg; j += U) {
    u32x4 v[U];
    float e[U];
#pragma unroll
    for (int i = 0; i < U; i++) v[i] = *(const u32x4*)(base + (size_t)c[i] * 64);
#pragma unroll
    for (int i = 0; i < U; i++) e[i] = lrelu(alh[c[i]] + ad);
#pragma unroll
    for (int i = 0; i < U; i++) c[i] = csr_src[min(start + j + U + i, endm1)];
    float mn = fmaxf(fmaxf(e[0], e[1]), fmaxf(e[2], e[3]));
    if (mn > m) {
      float sc = __expf(m - mn);
      s *= sc;
#pragma unroll
      for (int k = 0; k < 8; k++) acc[k] *= sc;
      m = mn;
    }
#pragma unroll
    for (int i = 0; i < U; i++) {
      float w = __expf(e[i] - m);
      s += w;
      fma8(v[i], w);
    }
  }
  for (int i = 0; j < deg; j++, i++) {
    u32x4 v = *(const u32x4*)(base + (size_t)c[i] * 64);
    float e = lrelu(alh[c[i]] + ad);
    if (e > m) {
      float sc = __expf(m - e);
      s *= sc;
#pragma unroll
      for (int k = 0; k < 8; k++) acc[k] *= sc;
      m = e;
    }
    float w = __expf(e - m);
    s += w;
    fma8(v, w);
  }
  float rr = 1.f / (s + 1e-16f);

  if (ti < N) {
    float p = slope_p[0];
    u32 ow[4];
#pragma unroll
    for (int i = 0; i < 4; i++) {
      int cc = l8 * 8 + 2 * i;
      float v0 = acc[2 * i] * rr + bias[cc];
      float v1 = acc[2 * i + 1] * rr + bias[cc + 1];
      v0 = (v0 >= 0.f) ? v0 : p * v0;
      v1 = (v1 >= 0.f) ? v1 : p * v1;
      ow[i] = (u32)f2bf(v0) | ((u32)f2bf(v1) << 16);
    }
    *(u32x4*)(out + (size_t)n * 64 + l8 * 8) = *(u32x4*)ow;
  }
}

// ---------------------------------------------------------------------------
// Layer-3 aggregation: wave = 4 degree-matched nodes x 16 lanes, lane = 8
// cols (head = (lane&15)>>1 since C=16), one-pass online softmax, head-mean
// via shfl_xor {2,4,8}, pairwise log_softmax, lanes {0,1} of group write.
// ---------------------------------------------------------------------------
__global__ __launch_bounds__(256) void gat_agg3_gs(
    const u16* __restrict__ xwh, const float* __restrict__ alsrc,
    const float* __restrict__ aldst, const int* __restrict__ row_ptr,
    const int* __restrict__ csr_src, const int* __restrict__ perm,
    const float* __restrict__ bias, float* __restrict__ out, int N, int ALP) {
  constexpr int U = 4;
  int lane = threadIdx.x & 63;
  int g = lane >> 4, l16 = lane & 15;
  int head = l16 >> 1;
  int ti = blockIdx.x * 16 + (threadIdx.x >> 6) * 4 + g;
  int n = perm[min(ti, N - 1)];
  const float* alh = alsrc + (size_t)head * ALP;
  float ad = aldst[(size_t)head * ALP + n];
  int start = row_ptr[n];
  int end = row_ptr[n + 1];
  int deg = (ti < N) ? end - start : 0;
  int endm1 = end - 1;

  float m = -1e30f, s = 0.f;
  float acc[8] = {};
  const u16* base = xwh + (size_t)l16 * 8;

  auto fma8 = [&](const u32x4& v, float w) {
#pragma unroll
    for (int i = 0; i < 4; i++) {
      u32 u = v[i];
      acc[2 * i] = fmaf(w, bf2f(u & 0xffffu), acc[2 * i]);
      acc[2 * i + 1] = fmaf(w, bf2f(u >> 16), acc[2 * i + 1]);
    }
  };

  int c[U];
#pragma unroll
  for (int i = 0; i < U; i++) c[i] = csr_src[min(start + i, endm1)];
  int j = 0;
  for (; j + U <= deg; j += U) {
    u32x4 v[U];
    float e[U];
#pragma unroll
    for (int i = 0; i < U; i++) v[i] = *(const u32x4*)(base + (size_t)c[i] * 128);
#pragma unroll
    for (int i = 0; i < U; i++) e[i] = lrelu(alh[c[i]] + ad);
#pragma unroll
    for (int i = 0; i < U; i++) c[i] = csr_src[min(start + j + U + i, endm1)];
    float mn = fmaxf(fmaxf(e[0], e[1]), fmaxf(e[2], e[3]));
    if (mn > m) {
      float sc = __expf(m - mn);
      s *= sc;
#pragma unroll
      for (int k = 0; k < 8; k++) acc[k] *= sc;
      m = mn;
    }
#pragma unroll
    for (int i = 0; i < U; i++) {
      float w = __expf(e[i] - m);
      s += w;
      fma8(v[i], w);
    }
  }
  for (int i = 0; j < deg; j++, i++) {
    u32x4 v = *(const u32x4*)(base + (size_t)c[i] * 128);
    float e = lrelu(alh[c[i]] + ad);
    if (e > m) {
      float sc = __expf(m - e);
      s *= sc;
#pragma unroll
      for (int k = 0; k < 8; k++) acc[k] *= sc;
      m = e;
    }
    float w = __expf(e - m);
    s += w;
    fma8(v, w);
  }
  float rr = 1.f / (s + 1e-16f);
#pragma unroll
  for (int k = 0; k < 8; k++) acc[k] *= rr;

  // sum over heads: lanes differing in bits 1..3 of l16 hold other heads
#pragma unroll
  for (int st = 2; st <= 8; st <<= 1)
#pragma unroll
    for (int k = 0; k < 8; k++) acc[k] += __shfl_xor(acc[k], st);

  int half = l16 & 1;  // which 8 of the 16 output cols this lane holds
  float v8[8];
  float mx = -1e30f;
#pragma unroll
  for (int k = 0; k < 8; k++) {
    v8[k] = acc[k] * 0.125f + bias[half * 8 + k];
    mx = fmaxf(mx, v8[k]);
  }
  mx = fmaxf(mx, __shfl_xor(mx, 1));
  float se = 0.f;
#pragma unroll
  for (int k = 0; k < 8; k++) se += __expf(v8[k] - mx);
  se += __shfl_xor(se, 1);
  float lse = mx + logf(se);
  if (ti < N && l16 < 2) {
    float4 o0 = make_float4(v8[0] - lse, v8[1] - lse, v8[2] - lse, v8[3] - lse);
    float4 o1 = make_float4(v8[4] - lse, v8[5] - lse, v8[6] - lse, v8[7] - lse);
    float* op = out + (size_t)n * 16 + half * 8;
    *(float4*)op = o0;
    *(float4*)(op + 4) = o1;
  }
}

// ---------------------------------------------------------------------------
extern "C" void kernel_launch(void* const* d_in, const int* in_sizes, int n_in,
                              void* d_out, int out_size, void* d_ws, size_t ws_size,
                              hipStream_t stream) {
  const float* x        = (const float*)d_in[0];
  const int*   ei       = (const int*)d_in[1];
  const float* bn_gamma = (const float*)d_in[2];
  const float* bn_beta  = (const float*)d_in[3];
  const float* W1       = (const float*)d_in[4];
  const float* a1s      = (const float*)d_in[5];
  const float* a1d      = (const float*)d_in[6];
  const float* b1       = (const float*)d_in[7];
  const float* p1       = (const float*)d_in[8];
  const float* W2       = (const float*)d_in[9];
  const float* a2s      = (const float*)d_in[10];
  const float* a2d      = (const float*)d_in[11];
  const float* b2       = (const float*)d_in[12];
  const float* p2       = (const float*)d_in[13];
  const float* W3       = (const float*)d_in[14];
  const float* a3s      = (const float*)d_in[15];
  const float* a3d      = (const float*)d_in[16];
  const float* b3       = (const float*)d_in[17];
  float* out = (float*)d_out;

  const int F  = in_sizes[2];       // 256
  const int N  = in_sizes[0] / F;   // 20000
  const int E  = in_sizes[1] / 2;   // 320000
  const int ET = E + N;
  const int MP = ((N + 127) / 128) * 128;  // MFMA row padding (also al stride)

  size_t off = 0;
  auto alloc = [&](size_t bytes) -> char* {
    char* r = (char*)d_ws + off;
    off += (bytes + 255) & ~(size_t)255;
    return r;
  };
  float* musum   = (float*)alloc(F * 4);
  float* sqsum   = (float*)alloc(F * 4);
  float* scale   = (float*)alloc(F * 4);
  float* shift   = (float*)alloc(F * 4);
  int*   row_ptr = (int*)alloc((size_t)(N + 1) * 4);
  int*   cursor  = (int*)alloc((size_t)N * 4);
  int*   csr_src = (int*)alloc((size_t)ET * 4);
  int*   perm    = (int*)alloc((size_t)N * 4);
  float* al_s    = (float*)alloc((size_t)16 * MP * 4);
  float* al_d    = (float*)alloc((size_t)16 * MP * 4);
  u16*   Wt1     = (u16*)alloc((size_t)1152 * 256 * 2);
  u16*   Wt2     = (u16*)alloc((size_t)96 * 1280 * 2);
  u16*   Wt3     = (u16*)alloc((size_t)160 * 64 * 2);
  u16*   x_in_h  = (u16*)alloc((size_t)MP * 256 * 2);
  u16*   xw1h    = (u16*)alloc((size_t)MP * 1024 * 2);
  u16*   h1      = (u16*)alloc((size_t)MP * 1024 * 2);
  u16*   xw2h    = (u16*)alloc((size_t)MP * 64 * 2);
  u16*   h2h     = (u16*)alloc((size_t)MP * 64 * 2);
  u16*   xw3h    = (u16*)alloc((size_t)MP * 128 * 2);

  // ---- BatchNorm ----
  hipMemsetAsync(musum, 0, (size_t)2 * F * 4, stream);
  bn_stats_kernel<<<256, 256, 0, stream>>>(x, musum, sqsum, N, F);
  bn_finalize_kernel<<<1, F, 0, stream>>>(musum, sqsum, bn_gamma, bn_beta, scale, shift, N);
  int totalXF = N * F;
  bn_apply_bf16_kernel<<<(totalXF + 255) / 256, 256, 0, stream>>>(x, scale, shift, x_in_h,
                                                                  totalXF, F - 1);

  // ---- CSR by dst ----
  hipMemsetAsync(cursor, 0, (size_t)N * 4, stream);
  csr_count_kernel<<<(ET + 255) / 256, 256, 0, stream>>>(ei, E, N, cursor);
  csr_scan_kernel<<<1, 1024, 0, stream>>>(cursor, row_ptr, cursor, N);
  csr_fill_kernel<<<(ET + 255) / 256, 256, 0, stream>>>(ei, E, N, cursor, csr_src);

  // ---- degree-sorted node permutation ----
  perm_build_kernel<<<1, 1024, 0, stream>>>(row_ptr, perm, N);

  // ---- weight prep ----
  {
    int total = 1024 * 256 + 64 * 1280 + 128 * 64 + 96 * 256 + 32 * 1280 + 32 * 64;
    wt_build_all<<<(total + 255) / 256, 256, 0, stream>>>(W1, W2, W3, Wt1, Wt2, Wt3);
    int tot2 = 32 * 256 + 16 * 1280 + 16 * 64;
    alfold_build<<<(tot2 + 255) / 256, 256, 0, stream>>>(W1, a1s, a1d, W2, a2s, a2d, W3, a3s, a3d,
                                                         Wt1, Wt2, Wt3);
  }

  // ---- Layer 1: [N,256]@[256,1024(+32al)] MFMA, H=16, C=64 ----
  {
    dim3 grid(MP / 128, 9);  // 9th tile covers al cols 1024..1151
    mfma_gemm_al<128, 128, 4, 4><<<grid, 256, 0, stream>>>(
        x_in_h, x_in_h, 256, 256, Wt1, xw1h, 1024, al_s, al_d, 32, MP, N);
    int NBH = (N + 31) / 32;  // node-32-blocks per head
    gat_agg1_gs<<<8 * NBH * 2, 256, 0, stream>>>(xw1h, al_s, al_d, row_ptr, csr_src, perm, b1, p1,
                                                 h1, N, MP, NBH);
  }

  // ---- Layer 2: concat([x_in,h1]) [N,1280]@[1280,64+16al] MFMA, H=8, C=8 ----
  {
    dim3 grid((N + 63) / 64, 1);
    mfma_gemm_al<64, 96, 2, 3><<<grid, 256, 0, stream>>>(
        x_in_h, h1, 256, 1280, Wt2, xw2h, 64, al_s, al_d, 16, MP, N);
    gat_agg2_gs<<<(N + 31) / 32, 256, 0, stream>>>(xw2h, al_s, al_d, row_ptr, csr_src, perm, b2,
                                                   p2, h2h, N, MP);
  }

  // ---- Layer 3: [N,64]@[64,128+16al] MFMA, H=8, C=16, mean + log_softmax ----
  {
    dim3 grid((N + 63) / 64, 1);
    mfma_gemm_al<64, 160, 2, 5><<<grid, 256, 0, stream>>>(
        h2h, h2h, 64, 64, Wt3, xw3h, 128, al_s, al_d, 16, MP, N);
    gat_agg3_gs<<<(N + 15) / 16, 256, 0, stream>>>(xw3h, al_s, al_d, row_ptr, csr_src, perm, b3,
                                                   out, N, MP);
  }
}

// Round 11
// 313.105 us; speedup vs baseline: 1.5468x; 1.0103x over previous
//
#include <hip/hip_runtime.h>
#include <math.h>

typedef unsigned int u32;
typedef unsigned short u16;
typedef u32 u32x4 __attribute__((ext_vector_type(4)));
typedef float f32x4 __attribute__((ext_vector_type(4)));

__device__ __forceinline__ u16 f2bf(float f) {
  u32 u = __builtin_bit_cast(u32, f);
  return (u16)((u + 0x7FFFu + ((u >> 16) & 1u)) >> 16);
}
__device__ __forceinline__ float bf2f(u32 lo16) {
  return __builtin_bit_cast(float, lo16 << 16);
}
__device__ __forceinline__ void mfma16(f32x4& c, const u32x4& a, const u32x4& b) {
  asm volatile("v_mfma_f32_16x16x32_bf16 %0, %1, %2, %0" : "+v"(c) : "v"(a), "v"(b));
}
__device__ __forceinline__ float lrelu(float e) { return fmaxf(e, 0.2f * e); }

// ---------------------------------------------------------------------------
// BatchNorm stats (musum/sqsum must be pre-zeroed)
// ---------------------------------------------------------------------------
__global__ void bn_stats_kernel(const float* __restrict__ x, float* __restrict__ musum,
                                float* __restrict__ sqsum, int N, int F) {
  int t = threadIdx.x;  // F == 256
  float s = 0.f, s2 = 0.f;
  for (int r = blockIdx.x; r < N; r += gridDim.x) {
    float v = x[(size_t)r * F + t];
    s += v;
    s2 += v * v;
  }
  atomicAdd(&musum[t], s);
  atomicAdd(&sqsum[t], s2);
}

// BN finalize folded in: each thread owns one column, computes scale/shift
// once, then grid-strides rows.
__global__ void bn_apply_bf16_kernel(const float* __restrict__ x, const float* __restrict__ musum,
                                     const float* __restrict__ sqsum,
                                     const float* __restrict__ gamma,
                                     const float* __restrict__ beta, u16* __restrict__ xin,
                                     int N, float invN) {
  int t = threadIdx.x;  // column, F == 256
  float mu = musum[t] * invN;
  float var = sqsum[t] * invN - mu * mu;
  float sc = gamma[t] * rsqrtf(var + 1e-5f);
  float sh = beta[t] - mu * sc;
  for (int r = blockIdx.x; r < N; r += gridDim.x) {
    size_t idx = (size_t)r * 256 + t;
    xin[idx] = f2bf(x[idx] * sc + sh);
  }
}

// ---------------------------------------------------------------------------
// CSR build (dst-indexed)
// ---------------------------------------------------------------------------
__global__ void csr_count_kernel(const int* __restrict__ ei, int E, int N, int* __restrict__ cnt) {
  int e = blockIdx.x * blockDim.x + threadIdx.x;
  int ET = E + N;
  if (e < ET) {
    int d = (e < E) ? ei[E + e] : (e - E);
    atomicAdd(&cnt[d], 1);
  }
}

// Merged: row_ptr scan + cursor init + degree-sorted permutation (counting
// sort, 256 bins) — all from cnt[] in one single-block kernel. cnt is
// overwritten with cursor values in the FINAL pass only.
__global__ __launch_bounds__(1024) void csr_scan_perm_kernel(int* __restrict__ cnt,
                                                             int* __restrict__ row_ptr,
                                                             int* __restrict__ perm, int N) {
  __shared__ int part[1024];
  __shared__ int bins[256];
  __shared__ int bs[256];
  int t = threadIdx.x;
  int chunk = (N + 1023) / 1024;
  int lo = min(t * chunk, N);
  int hi = min(lo + chunk, N);
  if (t < 256) bins[t] = 0;
  __syncthreads();
  // pass A: partial sums + degree histogram
  int s = 0;
  for (int i = lo; i < hi; i++) {
    int d = cnt[i];
    s += d;
    atomicAdd(&bins[min(d, 255)], 1);
  }
  part[t] = s;
  __syncthreads();
  // inclusive scan of part[1024]
  for (int off = 1; off < 1024; off <<= 1) {
    int v = (t >= off) ? part[t - off] : 0;
    __syncthreads();
    part[t] += v;
    __syncthreads();
  }
  // bins scan -> exclusive bases (cursor)
  if (t < 256) bs[t] = bins[t];
  __syncthreads();
  for (int off = 1; off < 256; off <<= 1) {
    int v = (t < 256 && t >= off) ? bs[t - off] : 0;
    __syncthreads();
    if (t < 256) bs[t] += v;
    __syncthreads();
  }
  if (t < 256) bins[t] = (t == 0) ? 0 : bs[t - 1];
  __syncthreads();
  // pass B: scatter perm (reads cnt, still counts)
  for (int i = lo; i < hi; i++) {
    int d = min(cnt[i], 255);
    int pos = atomicAdd(&bins[d], 1);
    perm[pos] = i;
  }
  __syncthreads();  // all reads of cnt done before overwrite
  // pass C: write row_ptr + cursor (cnt becomes cursor)
  int run = (t == 0) ? 0 : part[t - 1];
  for (int i = lo; i < hi; i++) {
    int d = cnt[i];
    row_ptr[i] = run;
    cnt[i] = run;
    run += d;
  }
  if (t == 1023) row_ptr[N] = part[1023];
}

__global__ void csr_fill_kernel(const int* __restrict__ ei, int E, int N,
                                int* __restrict__ cursor, int* __restrict__ csr_src) {
  int e = blockIdx.x * blockDim.x + threadIdx.x;
  int ET = E + N;
  if (e < ET) {
    int s, d;
    if (e < E) { s = ei[e]; d = ei[E + e]; }
    else       { s = e - E; d = s; }
    int pos = atomicAdd(&cursor[d], 1);
    csr_src[pos] = s;
  }
}

// ---------------------------------------------------------------------------
// Merged weight prep: Wt transposes + zero-pads + al-folds, disjoint ranges.
//   Wt1ext [1152][256]: 0..1023 = W1^T, 1024..1055 = alfold, 1056..1151 = 0
//   Wt2ext [  96][1280]: 0..63 = W2^T, 64..79 = alfold, 80..95 = 0
//   Wt3ext [ 160][  64]: 0..127 = W3^T, 128..143 = alfold, 144..159 = 0
// ---------------------------------------------------------------------------
__global__ void wt_alfold_build(const float* __restrict__ W1, const float* __restrict__ a1s,
                                const float* __restrict__ a1d, const float* __restrict__ W2,
                                const float* __restrict__ a2s, const float* __restrict__ a2d,
                                const float* __restrict__ W3, const float* __restrict__ a3s,
                                const float* __restrict__ a3d, u16* __restrict__ Wt1,
                                u16* __restrict__ Wt2, u16* __restrict__ Wt3) {
  const int S1 = 1024 * 256, S2 = 64 * 1280, S3 = 128 * 64;
  const int A1 = 32 * 256, A2 = 16 * 1280, A3 = 16 * 64;
  const int Z1 = 96 * 256, Z2 = 16 * 1280, Z3 = 16 * 64;
  int idx = blockIdx.x * blockDim.x + threadIdx.x;
  int o = idx;
  if (o < S1) {
    int n = o / 256, k = o % 256;
    Wt1[o] = f2bf(W1[(size_t)k * 1024 + n]);
    return;
  }
  o -= S1;
  if (o < S2) {
    int n = o / 1280, k = o % 1280;
    Wt2[o] = f2bf(W2[(size_t)k * 64 + n]);
    return;
  }
  o -= S2;
  if (o < S3) {
    int n = o / 64, k = o % 64;
    Wt3[o] = f2bf(W3[(size_t)k * 128 + n]);
    return;
  }
  o -= S3;
  if (o < A1) {  // H=16, C=64
    int jj = o / 256, k = o % 256, h = jj >> 1;
    const float* av = (jj & 1) ? a1d : a1s;
    float s = 0.f;
    for (int c = 0; c < 64; c++) s += W1[(size_t)k * 1024 + h * 64 + c] * av[h * 64 + c];
    Wt1[(size_t)(1024 + jj) * 256 + k] = f2bf(s);
    return;
  }
  o -= A1;
  if (o < A2) {  // H=8, C=8
    int jj = o / 1280, k = o % 1280, h = jj >> 1;
    const float* av = (jj & 1) ? a2d : a2s;
    float s = 0.f;
    for (int c = 0; c < 8; c++) s += W2[(size_t)k * 64 + h * 8 + c] * av[h * 8 + c];
    Wt2[(size_t)(64 + jj) * 1280 + k] = f2bf(s);
    return;
  }
  o -= A2;
  if (o < A3) {  // H=8, C=16
    int jj = o / 64, k = o % 64, h = jj >> 1;
    const float* av = (jj & 1) ? a3d : a3s;
    float s = 0.f;
    for (int c = 0; c < 16; c++) s += W3[(size_t)k * 128 + h * 16 + c] * av[h * 16 + c];
    Wt3[(size_t)(128 + jj) * 64 + k] = f2bf(s);
    return;
  }
  o -= A3;
  if (o < Z1) { Wt1[1056 * 256 + o] = 0; return; }
  o -= Z1;
  if (o < Z2) { Wt2[80 * 1280 + o] = 0; return; }
  o -= Z2;
  if (o < Z3) { Wt3[144 * 64 + o] = 0; return; }
}

// ---------------------------------------------------------------------------
// bf16 MFMA GEMM, double-buffered LDS via global_load_lds (width 16), one
// barrier per K-step. Fused al epilogue: cols < NcH -> bf16 Ch; cols NcH+j ->
// al_{s,d}[j>>1][m] (transposed [H][ALP]).
// ---------------------------------------------------------------------------
template <int BM, int BN, int FM, int FN>
__global__ __launch_bounds__(256) void mfma_gemm_al(
    const u16* __restrict__ A1, const u16* __restrict__ A2, int K1, int K,
    const u16* __restrict__ Wt, u16* __restrict__ Ch, int NcH,
    float* __restrict__ als, float* __restrict__ ald, int ALN, int ALP, int M) {
  constexpr int BK = 32;
  constexpr int ACH = (BM * BK) / 8;  // 16B chunks in A tile
  constexpr int BCH = (BN * BK) / 8;
  static_assert(BM == 2 * FM * 16 && BN == 2 * FN * 16, "wave grid 2x2");
  __shared__ u16 As[2][BM * BK];
  __shared__ u16 Bs[2][BN * BK];
  int t = threadIdx.x;
  int m0 = blockIdx.x * BM, n0 = blockIdx.y * BN;
  int r = t & 15;
  int g = (t >> 4) & 3;
  int wid = t >> 6;
  int wm0 = (wid >> 1) * (FM * 16);
  int wn0 = (wid & 1) * (FN * 16);
  int K8 = K >> 3;
  int K2 = K - K1;

  auto stage = [&](int buf, int k0) {
    const u16* Aseg;
    int sA, kl;
    if (k0 < K1) { Aseg = A1; sA = K1; kl = k0; }
    else         { Aseg = A2; sA = K2; kl = k0 - K1; }
#pragma unroll
    for (int i = 0; i < (ACH + 255) / 256; i++) {
      int c = i * 256 + t;
      if (ACH % 256 == 0 || c < ACH) {
        int m = c >> 2, kb = c & 3;
        __builtin_amdgcn_global_load_lds(
            (const __attribute__((address_space(1))) void*)(Aseg + (size_t)(m0 + m) * sA + kl + kb * 8),
            (__attribute__((address_space(3))) void*)(&As[buf][c * 8]), 16, 0, 0);
      }
    }
#pragma unroll
    for (int i = 0; i < (BCH + 255) / 256; i++) {
      int c = i * 256 + t;
      if (BCH % 256 == 0 || c < BCH) {
        int nn = c >> 2, kb = c & 3;
        __builtin_amdgcn_global_load_lds(
            (const __attribute__((address_space(1))) void*)(Wt + ((size_t)(n0 + nn) * K8 + (k0 >> 3) + kb) * 8),
            (__attribute__((address_space(3))) void*)(&Bs[buf][c * 8]), 16, 0, 0);
      }
    }
  };

  f32x4 acc[FM][FN] = {};
  asm volatile("s_nop 7\n\ts_nop 7" :::);  // VALU acc-init -> MFMA SrcC hazard guard

  stage(0, 0);
  __syncthreads();  // vmcnt(0) drain + barrier: tile 0 resident
  int nt = K / BK;
  for (int ts = 0; ts < nt; ts++) {
    if (ts + 1 < nt) stage((ts + 1) & 1, (ts + 1) * BK);  // overlap with compute
    int cur = ts & 1;
    u32x4 af[FM], bfr[FN];
#pragma unroll
    for (int fi = 0; fi < FM; fi++)
      af[fi] = *(const u32x4*)(&As[cur][((wm0 + fi * 16 + r) * 4 + g) * 8]);
#pragma unroll
    for (int fj = 0; fj < FN; fj++)
      bfr[fj] = *(const u32x4*)(&Bs[cur][((wn0 + fj * 16 + r) * 4 + g) * 8]);
#pragma unroll
    for (int fi = 0; fi < FM; fi++)
#pragma unroll
      for (int fj = 0; fj < FN; fj++) mfma16(acc[fi][fj], af[fi], bfr[fj]);
    __syncthreads();  // drains vmcnt (next tile ready) + ds_reads of cur done
  }
  asm volatile("s_nop 7\n\ts_nop 7" :::);  // MFMA -> VALU read hazard guard

#pragma unroll
  for (int fi = 0; fi < FM; fi++) {
#pragma unroll
    for (int fj = 0; fj < FN; fj++) {
#pragma unroll
      for (int v = 0; v < 4; v++) {
        int m = m0 + wm0 + fi * 16 + g * 4 + v;
        int nn = n0 + wn0 + fj * 16 + r;
        if (m < M) {
          float val = acc[fi][fj][v];
          if (nn < NcH) {
            Ch[(size_t)m * NcH + nn] = f2bf(val);
          } else {
            int j = nn - NcH;
            if (j < ALN) ((j & 1) ? ald : als)[(size_t)(j >> 1) * ALP + m] = val;
          }
        }
      }
    }
  }
}

// ---------------------------------------------------------------------------
// Layer-1 aggregation: GROUP-SLICED + XCD-affine + one-pass online softmax.
// Wave = 8 degree-matched nodes (perm), same head h = (blockIdx&7)+8*phase.
// U=6 deep pipelined gather (96B in flight per lane).
// ---------------------------------------------------------------------------
__global__ __launch_bounds__(256) void gat_agg1_gs(
    const u16* __restrict__ xwh, const float* __restrict__ alsrc,
    const float* __restrict__ aldst, const int* __restrict__ row_ptr,
    const int* __restrict__ csr_src, const int* __restrict__ perm,
    const float* __restrict__ bias, const float* __restrict__ slope_p,
    u16* __restrict__ out, int N, int ALP, int NBH) {
  constexpr int U = 6;
  int b = blockIdx.x;
  int xcd = b & 7, seq = b >> 3;
  int phase = seq / NBH, nb = seq - phase * NBH;
  int h = xcd + (phase << 3);
  int lane = threadIdx.x & 63;
  int g = lane >> 3, l8 = lane & 7;
  int ti = nb * 32 + (threadIdx.x >> 6) * 8 + g;
  int n = perm[min(ti, N - 1)];
  const float* alh = alsrc + (size_t)h * ALP;
  float ad = aldst[(size_t)h * ALP + n];
  int start = row_ptr[n];
  int end = row_ptr[n + 1];
  int deg = (ti < N) ? end - start : 0;
  int endm1 = end - 1;

  float m = -1e30f, s = 0.f;
  float acc[8] = {};
  const u16* base = xwh + (size_t)h * 64 + (size_t)l8 * 8;

  auto fma8 = [&](const u32x4& v, float w) {
#pragma unroll
    for (int i = 0; i < 4; i++) {
      u32 u = v[i];
      acc[2 * i] = fmaf(w, bf2f(u & 0xffffu), acc[2 * i]);
      acc[2 * i + 1] = fmaf(w, bf2f(u >> 16), acc[2 * i + 1]);
    }
  };

  int c[U];
#pragma unroll
  for (int i = 0; i < U; i++) c[i] = csr_src[min(start + i, endm1)];
  int j = 0;
  for (; j + U <= deg; j += U) {
    u32x4 v[U];
    float e[U];
#pragma unroll
    for (int i = 0; i < U; i++) v[i] = *(const u32x4*)(base + (size_t)c[i] * 1024);
#pragma unroll
    for (int i = 0; i < U; i++) e[i] = lrelu(alh[c[i]] + ad);
#pragma unroll
    for (int i = 0; i < U; i++) c[i] = csr_src[min(start + j + U + i, endm1)];
    float mn = fmaxf(fmaxf(fmaxf(e[0], e[1]), fmaxf(e[2], e[3])), fmaxf(e[4], e[5]));
    if (mn > m) {
      float sc = __expf(m - mn);
      s *= sc;
#pragma unroll
      for (int k = 0; k < 8; k++) acc[k] *= sc;
      m = mn;
    }
#pragma unroll
    for (int i = 0; i < U; i++) {
      float w = __expf(e[i] - m);
      s += w;
      fma8(v[i], w);
    }
  }
  for (int i = 0; j < deg; j++, i++) {
    u32x4 v = *(const u32x4*)(base + (size_t)c[i] * 1024);
    float e = lrelu(alh[c[i]] + ad);
    if (e > m) {
      float sc = __expf(m - e);
      s *= sc;
#pragma unroll
      for (int k = 0; k < 8; k++) acc[k] *= sc;
      m = e;
    }
    float w = __expf(e - m);
    s += w;
    fma8(v, w);
  }
  float rr = 1.f / (s + 1e-16f);

  if (ti < N) {
    float p = slope_p[0];
    u32 ow[4];
#pragma unroll
    for (int i = 0; i < 4; i++) {
      int cc = h * 64 + l8 * 8 + 2 * i;
      float v0 = acc[2 * i] * rr + bias[cc];
      float v1 = acc[2 * i + 1] * rr + bias[cc + 1];
      v0 = (v0 >= 0.f) ? v0 : p * v0;
      v1 = (v1 >= 0.f) ? v1 : p * v1;
      ow[i] = (u32)f2bf(v0) | ((u32)f2bf(v1) << 16);
    }
    *(u32x4*)(out + (size_t)n * 1024 + h * 64 + l8 * 8) = *(u32x4*)ow;
  }
}

// ---------------------------------------------------------------------------
// Layer-2 aggregation: wave = 8 degree-matched nodes, lane = 8 cols of one
// node (head = lane&7 since C=8), dwordx4 row loads, one-pass online softmax.
// ---------------------------------------------------------------------------
__global__ __launch_bounds__(256) void gat_agg2_gs(
    const u16* __restrict__ xwh, const float* __restrict__ alsrc,
    const float* __restrict__ aldst, const int* __restrict__ row_ptr,
    const int* __restrict__ csr_src, const int* __restrict__ perm,
    const float* __restrict__ bias, const float* __restrict__ slope_p,
    u16* __restrict__ out, int N, int ALP) {
  constexpr int U = 4;
  int lane = threadIdx.x & 63;
  int g = lane >> 3, l8 = lane & 7;  // l8 = col-block = head
  int ti = blockIdx.x * 32 + (threadIdx.x >> 6) * 8 + g;
  int n = perm[min(ti, N - 1)];
  const float* alh = alsrc + (size_t)l8 * ALP;
  float ad = aldst[(size_t)l8 * ALP + n];
  int start = row_ptr[n];
  int end = row_ptr[n + 1];
  int deg = (ti < N) ? end - start : 0;
  int endm1 = end - 1;

  float m = -1e30f, s = 0.f;
  float acc[8] = {};
  const u16* base = xwh + (size_t)l8 * 8;

  auto fma8 = [&](const u32x4& v, float w) {
#pragma unroll
    for (int i = 0; i < 4; i++) {
      u32 u = v[i];
      acc[2 * i] = fmaf(w, bf2f(u & 0xffffu), acc[2 * i]);
      acc[2 * i + 1] = fmaf(w, bf2f(u >> 16), acc[2 * i + 1]);
    }
  };

  int c[U];
#pragma unroll
  for (int i = 0; i < U; i++) c[i] = csr_src[min(start + i, endm1)];
  int j = 0;
  for (; j + U <= deg; j += U) {
    u32x4 v[U];
    float e[U];
#pragma unroll
    for (int i = 0; i < U; i++) v[i] = *(const u32x4*)(base + (size_t)c[i] * 64);
#pragma unroll
    for (int i = 0; i < U; i++) e[i] = lrelu(alh[c[i]] + ad);
#pragma unroll
    for (int i = 0; i < U; i++) c[i] = csr_src[min(start + j + U + i, endm1)];
    float mn = fmaxf(fmaxf(e[0], e[1]), fmaxf(e[2], e[3]));
    if (mn > m) {
      float sc = __expf(m - mn);
      s *= sc;
#pragma unroll
      for (int k = 0; k < 8; k++) acc[k] *= sc;
      m = mn;
    }
#pragma unroll
    for (int i = 0; i < U; i++) {
      float w = __expf(e[i] - m);
      s += w;
      fma8(v[i], w);
    }
  }
  for (int i = 0; j < deg; j++, i++) {
    u32x4 v = *(const u32x4*)(base + (size_t)c[i] * 64);
    float e = lrelu(alh[c[i]] + ad);
    if (e > m) {
      float sc = __expf(m - e);
      s *= sc;
#pragma unroll
      for (int k = 0; k < 8; k++) acc[k] *= sc;
      m = e;
    }
    float w = __expf(e - m);
    s += w;
    fma8(v, w);
  }
  float rr = 1.f / (s + 1e-16f);

  if (ti < N) {
    float p = slope_p[0];
    u32 ow[4];
#pragma unroll
    for (int i = 0; i < 4; i++) {
      int cc = l8 * 8 + 2 * i;
      float v0 = acc[2 * i] * rr + bias[cc];
      float v1 = acc[2 * i + 1] * rr + bias[cc + 1];
      v0 = (v0 >= 0.f) ? v0 : p * v0;
      v1 = (v1 >= 0.f) ? v1 : p * v1;
      ow[i] = (u32)f2bf(v0) | ((u32)f2bf(v1) << 16);
    }
    *(u32x4*)(out + (size_t)n * 64 + l8 * 8) = *(u32x4*)ow;
  }
}

// ---------------------------------------------------------------------------
// Layer-3 aggregation: wave = 4 degree-matched nodes x 16 lanes, lane = 8
// cols (head = (lane&15)>>1), one-pass online softmax, head-mean via
// shfl_xor {2,4,8}, pairwise log_softmax, lanes {0,1} of group write.
// ---------------------------------------------------------------------------
__global__ __launch_bounds__(256) void gat_agg3_gs(
    const u16* __restrict__ xwh, const float* __restrict__ alsrc,
    const float* __restrict__ aldst, const int* __restrict__ row_ptr,
    const int* __restrict__ csr_src, const int* __restrict__ perm,
    const float* __restrict__ bias, float* __restrict__ out, int N, int ALP) {
  constexpr int U = 4;
  int lane = threadIdx.x & 63;
  int g = lane >> 4, l16 = lane & 15;
  int head = l16 >> 1;
  int ti = blockIdx.x * 16 + (threadIdx.x >> 6) * 4 + g;
  int n = perm[min(ti, N - 1)];
  const float* alh = alsrc + (size_t)head * ALP;
  float ad = aldst[(size_t)head * ALP + n];
  int start = row_ptr[n];
  int end = row_ptr[n + 1];
  int deg = (ti < N) ? end - start : 0;
  int endm1 = end - 1;

  float m = -1e30f, s = 0.f;
  float acc[8] = {};
  const u16* base = xwh + (size_t)l16 * 8;

  auto fma8 = [&](const u32x4& v, float w) {
#pragma unroll
    for (int i = 0; i < 4; i++) {
      u32 u = v[i];
      acc[2 * i] = fmaf(w, bf2f(u & 0xffffu), acc[2 * i]);
      acc[2 * i + 1] = fmaf(w, bf2f(u >> 16), acc[2 * i + 1]);
    }
  };

  int c[U];
#pragma unroll
  for (int i = 0; i < U; i++) c[i] = csr_src[min(start + i, endm1)];
  int j = 0;
  for (; j + U <= deg; j += U) {
    u32x4 v[U];
    float e[U];
#pragma unroll
    for (int i = 0; i < U; i++) v[i] = *(const u32x4*)(base + (size_t)c[i] * 128);
#pragma unroll
    for (int i = 0; i < U; i++) e[i] = lrelu(alh[c[i]] + ad);
#pragma unroll
    for (int i = 0; i < U; i++) c[i] = csr_src[min(start + j + U + i, endm1)];
    float mn = fmaxf(fmaxf(e[0], e[1]), fmaxf(e[2], e[3]));
    if (mn > m) {
      float sc = __expf(m - mn);
      s *= sc;
#pragma unroll
      for (int k = 0; k < 8; k++) acc[k] *= sc;
      m = mn;
    }
#pragma unroll
    for (int i = 0; i < U; i++) {
      float w = __expf(e[i] - m);
      s += w;
      fma8(v[i], w);
    }
  }
  for (int i = 0; j < deg; j++, i++) {
    u32x4 v = *(const u32x4*)(base + (size_t)c[i] * 128);
    float e = lrelu(alh[c[i]] + ad);
    if (e > m) {
      float sc = __expf(m - e);
      s *= sc;
#pragma unroll
      for (int k = 0; k < 8; k++) acc[k] *= sc;
      m = e;
    }
    float w = __expf(e - m);
    s += w;
    fma8(v, w);
  }
  float rr = 1.f / (s + 1e-16f);
#pragma unroll
  for (int k = 0; k < 8; k++) acc[k] *= rr;

  // sum over heads: lanes differing in bits 1..3 of l16 hold other heads
#pragma unroll
  for (int st = 2; st <= 8; st <<= 1)
#pragma unroll
    for (int k = 0; k < 8; k++) acc[k] += __shfl_xor(acc[k], st);

  int half = l16 & 1;  // which 8 of the 16 output cols this lane holds
  float v8[8];
  float mx = -1e30f;
#pragma unroll
  for (int k = 0; k < 8; k++) {
    v8[k] = acc[k] * 0.125f + bias[half * 8 + k];
    mx = fmaxf(mx, v8[k]);
  }
  mx = fmaxf(mx, __shfl_xor(mx, 1));
  float se = 0.f;
#pragma unroll
  for (int k = 0; k < 8; k++) se += __expf(v8[k] - mx);
  se += __shfl_xor(se, 1);
  float lse = mx + logf(se);
  if (ti < N && l16 < 2) {
    float4 o0 = make_float4(v8[0] - lse, v8[1] - lse, v8[2] - lse, v8[3] - lse);
    float4 o1 = make_float4(v8[4] - lse, v8[5] - lse, v8[6] - lse, v8[7] - lse);
    float* op = out + (size_t)n * 16 + half * 8;
    *(float4*)op = o0;
    *(float4*)(op + 4) = o1;
  }
}

// ---------------------------------------------------------------------------
extern "C" void kernel_launch(void* const* d_in, const int* in_sizes, int n_in,
                              void* d_out, int out_size, void* d_ws, size_t ws_size,
                              hipStream_t stream) {
  const float* x        = (const float*)d_in[0];
  const int*   ei       = (const int*)d_in[1];
  const float* bn_gamma = (const float*)d_in[2];
  const float* bn_beta  = (const float*)d_in[3];
  const float* W1       = (const float*)d_in[4];
  const float* a1s      = (const float*)d_in[5];
  const float* a1d      = (const float*)d_in[6];
  const float* b1       = (const float*)d_in[7];
  const float* p1       = (const float*)d_in[8];
  const float* W2       = (const float*)d_in[9];
  const float* a2s      = (const float*)d_in[10];
  const float* a2d      = (const float*)d_in[11];
  const float* b2       = (const float*)d_in[12];
  const float* p2       = (const float*)d_in[13];
  const float* W3       = (const float*)d_in[14];
  const float* a3s      = (const float*)d_in[15];
  const float* a3d      = (const float*)d_in[16];
  const float* b3       = (const float*)d_in[17];
  float* out = (float*)d_out;

  const int F  = in_sizes[2];       // 256
  const int N  = in_sizes[0] / F;   // 20000
  const int E  = in_sizes[1] / 2;   // 320000
  const int ET = E + N;
  const int MP = ((N + 127) / 128) * 128;  // MFMA row padding (also al stride)

  size_t off = 0;
  auto alloc = [&](size_t bytes) -> char* {
    char* r = (char*)d_ws + off;
    off += (bytes + 255) & ~(size_t)255;
    return r;
  };
  // musum|sqsum|cursor adjacent -> single memset covers all three
  float* musum   = (float*)alloc(F * 4);
  float* sqsum   = (float*)alloc(F * 4);
  int*   cursor  = (int*)alloc((size_t)N * 4);
  int*   row_ptr = (int*)alloc((size_t)(N + 1) * 4);
  int*   csr_src = (int*)alloc((size_t)ET * 4);
  int*   perm    = (int*)alloc((size_t)N * 4);
  float* al_s    = (float*)alloc((size_t)16 * MP * 4);
  float* al_d    = (float*)alloc((size_t)16 * MP * 4);
  u16*   Wt1     = (u16*)alloc((size_t)1152 * 256 * 2);
  u16*   Wt2     = (u16*)alloc((size_t)96 * 1280 * 2);
  u16*   Wt3     = (u16*)alloc((size_t)160 * 64 * 2);
  u16*   x_in_h  = (u16*)alloc((size_t)MP * 256 * 2);
  u16*   xw1h    = (u16*)alloc((size_t)MP * 1024 * 2);
  u16*   h1      = (u16*)alloc((size_t)MP * 1024 * 2);
  u16*   xw2h    = (u16*)alloc((size_t)MP * 64 * 2);
  u16*   h2h     = (u16*)alloc((size_t)MP * 64 * 2);
  u16*   xw3h    = (u16*)alloc((size_t)MP * 128 * 2);

  // ---- single memset: musum (1KB) + sqsum (1KB) + cursor (N*4) ----
  hipMemsetAsync(musum, 0, (size_t)2 * F * 4 + (size_t)N * 4, stream);

  // ---- BatchNorm ----
  bn_stats_kernel<<<256, 256, 0, stream>>>(x, musum, sqsum, N, F);
  bn_apply_bf16_kernel<<<1024, 256, 0, stream>>>(x, musum, sqsum, bn_gamma, bn_beta, x_in_h, N,
                                                 1.0f / (float)N);

  // ---- CSR by dst + degree-sorted perm ----
  csr_count_kernel<<<(ET + 255) / 256, 256, 0, stream>>>(ei, E, N, cursor);
  csr_scan_perm_kernel<<<1, 1024, 0, stream>>>(cursor, row_ptr, perm, N);
  csr_fill_kernel<<<(ET + 255) / 256, 256, 0, stream>>>(ei, E, N, cursor, csr_src);

  // ---- weight prep (merged transpose + al-fold + zero-pad) ----
  {
    int total = 1024 * 256 + 64 * 1280 + 128 * 64      // data
              + 32 * 256 + 16 * 1280 + 16 * 64         // al-fold
              + 96 * 256 + 16 * 1280 + 16 * 64;        // zero-pad
    wt_alfold_build<<<(total + 255) / 256, 256, 0, stream>>>(W1, a1s, a1d, W2, a2s, a2d, W3, a3s,
                                                             a3d, Wt1, Wt2, Wt3);
  }

  // ---- Layer 1: [N,256]@[256,1024(+32al)] MFMA, H=16, C=64 ----
  {
    dim3 grid(MP / 128, 9);  // 9th tile covers al cols 1024..1151
    mfma_gemm_al<128, 128, 4, 4><<<grid, 256, 0, stream>>>(
        x_in_h, x_in_h, 256, 256, Wt1, xw1h, 1024, al_s, al_d, 32, MP, N);
    int NBH = (N + 31) / 32;  // node-32-blocks per head
    gat_agg1_gs<<<8 * NBH * 2, 256, 0, stream>>>(xw1h, al_s, al_d, row_ptr, csr_src, perm, b1, p1,
                                                 h1, N, MP, NBH);
  }

  // ---- Layer 2: concat([x_in,h1]) [N,1280]@[1280,64+16al] MFMA, H=8, C=8 ----
  {
    dim3 grid((N + 63) / 64, 1);
    mfma_gemm_al<64, 96, 2, 3><<<grid, 256, 0, stream>>>(
        x_in_h, h1, 256, 1280, Wt2, xw2h, 64, al_s, al_d, 16, MP, N);
    gat_agg2_gs<<<(N + 31) / 32, 256, 0, stream>>>(xw2h, al_s, al_d, row_ptr, csr_src, perm, b2,
                                                   p2, h2h, N, MP);
  }

  // ---- Layer 3: [N,64]@[64,128+16al] MFMA, H=8, C=16, mean + log_softmax ----
  {
    dim3 grid((N + 63) / 64, 1);
    mfma_gemm_al<64, 160, 2, 5><<<grid, 256, 0, stream>>>(
        h2h, h2h, 64, 64, Wt3, xw3h, 128, al_s, al_d, 16, MP, N);
    gat_agg3_gs<<<(N + 15) / 16, 256, 0, stream>>>(xw3h, al_s, al_d, row_ptr, csr_src, perm, b3,
                                                   out, N, MP);
  }
}

// Round 12
// 307.796 us; speedup vs baseline: 1.5735x; 1.0172x over previous
//
#include <hip/hip_runtime.h>
#include <math.h>

typedef unsigned int u32;
typedef unsigned short u16;
typedef u32 u32x4 __attribute__((ext_vector_type(4)));
typedef float f32x4 __attribute__((ext_vector_type(4)));

__device__ __forceinline__ u16 f2bf(float f) {
  u32 u = __builtin_bit_cast(u32, f);
  return (u16)((u + 0x7FFFu + ((u >> 16) & 1u)) >> 16);
}
__device__ __forceinline__ float bf2f(u32 lo16) {
  return __builtin_bit_cast(float, lo16 << 16);
}
__device__ __forceinline__ void mfma16(f32x4& c, const u32x4& a, const u32x4& b) {
  asm volatile("v_mfma_f32_16x16x32_bf16 %0, %1, %2, %0" : "+v"(c) : "v"(a), "v"(b));
}
__device__ __forceinline__ float lrelu(float e) { return fmaxf(e, 0.2f * e); }

// ---------------------------------------------------------------------------
// PREP-1 (merged): blocks [0,256) = BN stats; blocks [256,..) = CSR count.
// musum/sqsum/cnt must be pre-zeroed.
// ---------------------------------------------------------------------------
__global__ void prep1_kernel(const float* __restrict__ x, float* __restrict__ musum,
                             float* __restrict__ sqsum, const int* __restrict__ ei, int E,
                             int N, int* __restrict__ cnt) {
  int b = blockIdx.x;
  int t = threadIdx.x;
  if (b < 256) {
    float s = 0.f, s2 = 0.f;
    for (int r = b; r < N; r += 256) {
      float v = x[(size_t)r * 256 + t];
      s += v;
      s2 += v * v;
    }
    atomicAdd(&musum[t], s);
    atomicAdd(&sqsum[t], s2);
  } else {
    int e = (b - 256) * 256 + t;
    int ET = E + N;
    if (e < ET) {
      int d = (e < E) ? ei[E + e] : (e - E);
      atomicAdd(&cnt[d], 1);
    }
  }
}

// ---------------------------------------------------------------------------
// PREP-2 (merged, 1024 threads): block 0 = row_ptr scan + cursor + degree-
// sorted perm (LDS counting sort); blocks [1,257) = BN apply (bf16 x_in).
// cnt is overwritten with cursor values in its final pass.
// ---------------------------------------------------------------------------
__global__ __launch_bounds__(1024) void prep2_kernel(
    int* __restrict__ cnt, int* __restrict__ row_ptr, int* __restrict__ perm,
    const float* __restrict__ x, const float* __restrict__ musum,
    const float* __restrict__ sqsum, const float* __restrict__ gamma,
    const float* __restrict__ beta, u16* __restrict__ xin, int N, float invN) {
  int t = threadIdx.x;
  if (blockIdx.x == 0) {
    __shared__ int part[1024];
    __shared__ int bins[256];
    __shared__ int bs[256];
    int chunk = (N + 1023) / 1024;
    int lo = min(t * chunk, N);
    int hi = min(lo + chunk, N);
    if (t < 256) bins[t] = 0;
    __syncthreads();
    int s = 0;
    for (int i = lo; i < hi; i++) {
      int d = cnt[i];
      s += d;
      atomicAdd(&bins[min(d, 255)], 1);
    }
    part[t] = s;
    __syncthreads();
    for (int off = 1; off < 1024; off <<= 1) {
      int v = (t >= off) ? part[t - off] : 0;
      __syncthreads();
      part[t] += v;
      __syncthreads();
    }
    if (t < 256) bs[t] = bins[t];
    __syncthreads();
    for (int off = 1; off < 256; off <<= 1) {
      int v = (t < 256 && t >= off) ? bs[t - off] : 0;
      __syncthreads();
      if (t < 256) bs[t] += v;
      __syncthreads();
    }
    if (t < 256) bins[t] = (t == 0) ? 0 : bs[t - 1];
    __syncthreads();
    for (int i = lo; i < hi; i++) {
      int d = min(cnt[i], 255);
      int pos = atomicAdd(&bins[d], 1);
      perm[pos] = i;
    }
    __syncthreads();  // all reads of cnt done before overwrite
    int run = (t == 0) ? 0 : part[t - 1];
    for (int i = lo; i < hi; i++) {
      int d = cnt[i];
      row_ptr[i] = run;
      cnt[i] = run;
      run += d;
    }
    if (t == 1023) row_ptr[N] = part[1023];
  } else {
    int col = t & 255, ro = t >> 8;
    float mu = musum[col] * invN;
    float var = sqsum[col] * invN - mu * mu;
    float sc = gamma[col] * rsqrtf(var + 1e-5f);
    float sh = beta[col] - mu * sc;
    for (int r = (blockIdx.x - 1) * 4 + ro; r < N; r += 256 * 4) {
      size_t idx = (size_t)r * 256 + col;
      xin[idx] = f2bf(x[idx] * sc + sh);
    }
  }
}

// ---------------------------------------------------------------------------
// PREP-3 (merged): blocks [0,FILLB) = CSR fill; rest = weight prep
// (Wt transposes + al-folds + zero-pads, disjoint ranges).
//   Wt1ext [1152][256]: 0..1023 = W1^T, 1024..1055 = alfold, 1056..1151 = 0
//   Wt2ext [  96][1280]: 0..63 = W2^T, 64..79 = alfold, 80..95 = 0
//   Wt3ext [ 160][  64]: 0..127 = W3^T, 128..143 = alfold, 144..159 = 0
// ---------------------------------------------------------------------------
__global__ void prep3_kernel(const int* __restrict__ ei, int E, int N, int FILLB,
                             int* __restrict__ cursor, int* __restrict__ csr_src,
                             const float* __restrict__ W1, const float* __restrict__ a1s,
                             const float* __restrict__ a1d, const float* __restrict__ W2,
                             const float* __restrict__ a2s, const float* __restrict__ a2d,
                             const float* __restrict__ W3, const float* __restrict__ a3s,
                             const float* __restrict__ a3d, u16* __restrict__ Wt1,
                             u16* __restrict__ Wt2, u16* __restrict__ Wt3) {
  int b = blockIdx.x;
  if (b < FILLB) {
    int e = b * 256 + threadIdx.x;
    int ET = E + N;
    if (e < ET) {
      int s, d;
      if (e < E) { s = ei[e]; d = ei[E + e]; }
      else       { s = e - E; d = s; }
      int pos = atomicAdd(&cursor[d], 1);
      csr_src[pos] = s;
    }
    return;
  }
  const int S1 = 1024 * 256, S2 = 64 * 1280, S3 = 128 * 64;
  const int A1 = 32 * 256, A2 = 16 * 1280, A3 = 16 * 64;
  const int Z1 = 96 * 256, Z2 = 16 * 1280, Z3 = 16 * 64;
  int o = (b - FILLB) * 256 + threadIdx.x;
  if (o < S1) {
    int n = o / 256, k = o % 256;
    Wt1[o] = f2bf(W1[(size_t)k * 1024 + n]);
    return;
  }
  o -= S1;
  if (o < S2) {
    int n = o / 1280, k = o % 1280;
    Wt2[o] = f2bf(W2[(size_t)k * 64 + n]);
    return;
  }
  o -= S2;
  if (o < S3) {
    int n = o / 64, k = o % 64;
    Wt3[o] = f2bf(W3[(size_t)k * 128 + n]);
    return;
  }
  o -= S3;
  if (o < A1) {  // H=16, C=64
    int jj = o / 256, k = o % 256, h = jj >> 1;
    const float* av = (jj & 1) ? a1d : a1s;
    float s = 0.f;
    for (int c = 0; c < 64; c++) s += W1[(size_t)k * 1024 + h * 64 + c] * av[h * 64 + c];
    Wt1[(size_t)(1024 + jj) * 256 + k] = f2bf(s);
    return;
  }
  o -= A1;
  if (o < A2) {  // H=8, C=8
    int jj = o / 1280, k = o % 1280, h = jj >> 1;
    const float* av = (jj & 1) ? a2d : a2s;
    float s = 0.f;
    for (int c = 0; c < 8; c++) s += W2[(size_t)k * 64 + h * 8 + c] * av[h * 8 + c];
    Wt2[(size_t)(64 + jj) * 1280 + k] = f2bf(s);
    return;
  }
  o -= A2;
  if (o < A3) {  // H=8, C=16
    int jj = o / 64, k = o % 64, h = jj >> 1;
    const float* av = (jj & 1) ? a3d : a3s;
    float s = 0.f;
    for (int c = 0; c < 16; c++) s += W3[(size_t)k * 128 + h * 16 + c] * av[h * 16 + c];
    Wt3[(size_t)(128 + jj) * 64 + k] = f2bf(s);
    return;
  }
  o -= A3;
  if (o < Z1) { Wt1[1056 * 256 + o] = 0; return; }
  o -= Z1;
  if (o < Z2) { Wt2[80 * 1280 + o] = 0; return; }
  o -= Z2;
  if (o < Z3) { Wt3[144 * 64 + o] = 0; return; }
}

// ---------------------------------------------------------------------------
// bf16 MFMA GEMM, double-buffered LDS via global_load_lds (width 16), one
// barrier per K-step. Fused al epilogue: cols < NcH -> bf16 Ch; cols NcH+j ->
// al_{s,d}[j>>1][m] (transposed [H][ALP]).
// ---------------------------------------------------------------------------
template <int BM, int BN, int FM, int FN>
__global__ __launch_bounds__(256) void mfma_gemm_al(
    const u16* __restrict__ A1, const u16* __restrict__ A2, int K1, int K,
    const u16* __restrict__ Wt, u16* __restrict__ Ch, int NcH,
    float* __restrict__ als, float* __restrict__ ald, int ALN, int ALP, int M) {
  constexpr int BK = 32;
  constexpr int ACH = (BM * BK) / 8;  // 16B chunks in A tile
  constexpr int BCH = (BN * BK) / 8;
  static_assert(BM == 2 * FM * 16 && BN == 2 * FN * 16, "wave grid 2x2");
  __shared__ u16 As[2][BM * BK];
  __shared__ u16 Bs[2][BN * BK];
  int t = threadIdx.x;
  int m0 = blockIdx.x * BM, n0 = blockIdx.y * BN;
  int r = t & 15;
  int g = (t >> 4) & 3;
  int wid = t >> 6;
  int wm0 = (wid >> 1) * (FM * 16);
  int wn0 = (wid & 1) * (FN * 16);
  int K8 = K >> 3;
  int K2 = K - K1;

  auto stage = [&](int buf, int k0) {
    const u16* Aseg;
    int sA, kl;
    if (k0 < K1) { Aseg = A1; sA = K1; kl = k0; }
    else         { Aseg = A2; sA = K2; kl = k0 - K1; }
#pragma unroll
    for (int i = 0; i < (ACH + 255) / 256; i++) {
      int c = i * 256 + t;
      if (ACH % 256 == 0 || c < ACH) {
        int m = c >> 2, kb = c & 3;
        __builtin_amdgcn_global_load_lds(
            (const __attribute__((address_space(1))) void*)(Aseg + (size_t)(m0 + m) * sA + kl + kb * 8),
            (__attribute__((address_space(3))) void*)(&As[buf][c * 8]), 16, 0, 0);
      }
    }
#pragma unroll
    for (int i = 0; i < (BCH + 255) / 256; i++) {
      int c = i * 256 + t;
      if (BCH % 256 == 0 || c < BCH) {
        int nn = c >> 2, kb = c & 3;
        __builtin_amdgcn_global_load_lds(
            (const __attribute__((address_space(1))) void*)(Wt + ((size_t)(n0 + nn) * K8 + (k0 >> 3) + kb) * 8),
            (__attribute__((address_space(3))) void*)(&Bs[buf][c * 8]), 16, 0, 0);
      }
    }
  };

  f32x4 acc[FM][FN] = {};
  asm volatile("s_nop 7\n\ts_nop 7" :::);  // VALU acc-init -> MFMA SrcC hazard guard

  stage(0, 0);
  __syncthreads();  // vmcnt(0) drain + barrier: tile 0 resident
  int nt = K / BK;
  for (int ts = 0; ts < nt; ts++) {
    if (ts + 1 < nt) stage((ts + 1) & 1, (ts + 1) * BK);  // overlap with compute
    int cur = ts & 1;
    u32x4 af[FM], bfr[FN];
#pragma unroll
    for (int fi = 0; fi < FM; fi++)
      af[fi] = *(const u32x4*)(&As[cur][((wm0 + fi * 16 + r) * 4 + g) * 8]);
#pragma unroll
    for (int fj = 0; fj < FN; fj++)
      bfr[fj] = *(const u32x4*)(&Bs[cur][((wn0 + fj * 16 + r) * 4 + g) * 8]);
#pragma unroll
    for (int fi = 0; fi < FM; fi++)
#pragma unroll
      for (int fj = 0; fj < FN; fj++) mfma16(acc[fi][fj], af[fi], bfr[fj]);
    __syncthreads();  // drains vmcnt (next tile ready) + ds_reads of cur done
  }
  asm volatile("s_nop 7\n\ts_nop 7" :::);  // MFMA -> VALU read hazard guard

#pragma unroll
  for (int fi = 0; fi < FM; fi++) {
#pragma unroll
    for (int fj = 0; fj < FN; fj++) {
#pragma unroll
      for (int v = 0; v < 4; v++) {
        int m = m0 + wm0 + fi * 16 + g * 4 + v;
        int nn = n0 + wn0 + fj * 16 + r;
        if (m < M) {
          float val = acc[fi][fj][v];
          if (nn < NcH) {
            Ch[(size_t)m * NcH + nn] = f2bf(val);
          } else {
            int j = nn - NcH;
            if (j < ALN) ((j & 1) ? ald : als)[(size_t)(j >> 1) * ALP + m] = val;
          }
        }
      }
    }
  }
}

// ---------------------------------------------------------------------------
// Layer-1 aggregation: GROUP-SLICED + XCD-affine + one-pass online softmax.
// Wave = 8 degree-matched nodes (perm), same head h = (blockIdx&7)+8*phase.
// U=4 (proven optimum: 36 VGPR, ~56% occupancy).
// ---------------------------------------------------------------------------
__global__ __launch_bounds__(256) void gat_agg1_gs(
    const u16* __restrict__ xwh, const float* __restrict__ alsrc,
    const float* __restrict__ aldst, const int* __restrict__ row_ptr,
    const int* __restrict__ csr_src, const int* __restrict__ perm,
    const float* __restrict__ bias, const float* __restrict__ slope_p,
    u16* __restrict__ out, int N, int ALP, int NBH) {
  constexpr int U = 4;
  int b = blockIdx.x;
  int xcd = b & 7, seq = b >> 3;
  int phase = seq / NBH, nb = seq - phase * NBH;
  int h = xcd + (phase << 3);
  int lane = threadIdx.x & 63;
  int g = lane >> 3, l8 = lane & 7;
  int ti = nb * 32 + (threadIdx.x >> 6) * 8 + g;
  int n = perm[min(ti, N - 1)];
  const float* alh = alsrc + (size_t)h * ALP;
  float ad = aldst[(size_t)h * ALP + n];
  int start = row_ptr[n];
  int end = row_ptr[n + 1];
  int deg = (ti < N) ? end - start : 0;
  int endm1 = end - 1;

  float m = -1e30f, s = 0.f;
  float acc[8] = {};
  const u16* base = xwh + (size_t)h * 64 + (size_t)l8 * 8;

  auto fma8 = [&](const u32x4& v, float w) {
#pragma unroll
    for (int i = 0; i < 4; i++) {
      u32 u = v[i];
      acc[2 * i] = fmaf(w, bf2f(u & 0xffffu), acc[2 * i]);
      acc[2 * i + 1] = fmaf(w, bf2f(u >> 16), acc[2 * i + 1]);
    }
  };

  int c[U];
#pragma unroll
  for (int i = 0; i < U; i++) c[i] = csr_src[min(start + i, endm1)];
  int j = 0;
  for (; j + U <= deg; j += U) {
    u32x4 v[U];
    float e[U];
#pragma unroll
    for (int i = 0; i < U; i++) v[i] = *(const u32x4*)(base + (size_t)c[i] * 1024);
#pragma unroll
    for (int i = 0; i < U; i++) e[i] = lrelu(alh[c[i]] + ad);
#pragma unroll
    for (int i = 0; i < U; i++) c[i] = csr_src[min(start + j + U + i, endm1)];
    float mn = fmaxf(fmaxf(e[0], e[1]), fmaxf(e[2], e[3]));
    if (mn > m) {
      float sc = __expf(m - mn);
      s *= sc;
#pragma unroll
      for (int k = 0; k < 8; k++) acc[k] *= sc;
      m = mn;
    }
#pragma unroll
    for (int i = 0; i < U; i++) {
      float w = __expf(e[i] - m);
      s += w;
      fma8(v[i], w);
    }
  }
  for (int i = 0; j < deg; j++, i++) {
    u32x4 v = *(const u32x4*)(base + (size_t)c[i] * 1024);
    float e = lrelu(alh[c[i]] + ad);
    if (e > m) {
      float sc = __expf(m - e);
      s *= sc;
#pragma unroll
      for (int k = 0; k < 8; k++) acc[k] *= sc;
      m = e;
    }
    float w = __expf(e - m);
    s += w;
    fma8(v, w);
  }
  float rr = 1.f / (s + 1e-16f);

  if (ti < N) {
    float p = slope_p[0];
    u32 ow[4];
#pragma unroll
    for (int i = 0; i < 4; i++) {
      int cc = h * 64 + l8 * 8 + 2 * i;
      float v0 = acc[2 * i] * rr + bias[cc];
      float v1 = acc[2 * i + 1] * rr + bias[cc + 1];
      v0 = (v0 >= 0.f) ? v0 : p * v0;
      v1 = (v1 >= 0.f) ? v1 : p * v1;
      ow[i] = (u32)f2bf(v0) | ((u32)f2bf(v1) << 16);
    }
    *(u32x4*)(out + (size_t)n * 1024 + h * 64 + l8 * 8) = *(u32x4*)ow;
  }
}

// ---------------------------------------------------------------------------
// Layer-2 aggregation: wave = 8 degree-matched nodes, lane = 8 cols of one
// node (head = lane&7 since C=8), dwordx4 row loads, one-pass online softmax.
// ---------------------------------------------------------------------------
__global__ __launch_bounds__(256) void gat_agg2_gs(
    const u16* __restrict__ xwh, const float* __restrict__ alsrc,
    const float* __restrict__ aldst, const int* __restrict__ row_ptr,
    const int* __restrict__ csr_src, const int* __restrict__ perm,
    const float* __restrict__ bias, const float* __restrict__ slope_p,
    u16* __restrict__ out, int N, int ALP) {
  constexpr int U = 4;
  int lane = threadIdx.x & 63;
  int g = lane >> 3, l8 = lane & 7;  // l8 = col-block = head
  int ti = blockIdx.x * 32 + (threadIdx.x >> 6) * 8 + g;
  int n = perm[min(ti, N - 1)];
  const float* alh = alsrc + (size_t)l8 * ALP;
  float ad = aldst[(size_t)l8 * ALP + n];
  int start = row_ptr[n];
  int end = row_ptr[n + 1];
  int deg = (ti < N) ? end - start : 0;
  int endm1 = end - 1;

  float m = -1e30f, s = 0.f;
  float acc[8] = {};
  const u16* base = xwh + (size_t)l8 * 8;

  auto fma8 = [&](const u32x4& v, float w) {
#pragma unroll
    for (int i = 0; i < 4; i++) {
      u32 u = v[i];
      acc[2 * i] = fmaf(w, bf2f(u & 0xffffu), acc[2 * i]);
      acc[2 * i + 1] = fmaf(w, bf2f(u >> 16), acc[2 * i + 1]);
    }
  };

  int c[U];
#pragma unroll
  for (int i = 0; i < U; i++) c[i] = csr_src[min(start + i, endm1)];
  int j = 0;
  for (; j + U <= deg; j += U) {
    u32x4 v[U];
    float e[U];
#pragma unroll
    for (int i = 0; i < U; i++) v[i] = *(const u32x4*)(base + (size_t)c[i] * 64);
#pragma unroll
    for (int i = 0; i < U; i++) e[i] = lrelu(alh[c[i]] + ad);
#pragma unroll
    for (int i = 0; i < U; i++) c[i] = csr_src[min(start + j + U + i, endm1)];
    float mn = fmaxf(fmaxf(e[0], e[1]), fmaxf(e[2], e[3]));
    if (mn > m) {
      float sc = __expf(m - mn);
      s *= sc;
#pragma unroll
      for (int k = 0; k < 8; k++) acc[k] *= sc;
      m = mn;
    }
#pragma unroll
    for (int i = 0; i < U; i++) {
      float w = __expf(e[i] - m);
      s += w;
      fma8(v[i], w);
    }
  }
  for (int i = 0; j < deg; j++, i++) {
    u32x4 v = *(const u32x4*)(base + (size_t)c[i] * 64);
    float e = lrelu(alh[c[i]] + ad);
    if (e > m) {
      float sc = __expf(m - e);
      s *= sc;
#pragma unroll
      for (int k = 0; k < 8; k++) acc[k] *= sc;
      m = e;
    }
    float w = __expf(e - m);
    s += w;
    fma8(v, w);
  }
  float rr = 1.f / (s + 1e-16f);

  if (ti < N) {
    float p = slope_p[0];
    u32 ow[4];
#pragma unroll
    for (int i = 0; i < 4; i++) {
      int cc = l8 * 8 + 2 * i;
      float v0 = acc[2 * i] * rr + bias[cc];
      float v1 = acc[2 * i + 1] * rr + bias[cc + 1];
      v0 = (v0 >= 0.f) ? v0 : p * v0;
      v1 = (v1 >= 0.f) ? v1 : p * v1;
      ow[i] = (u32)f2bf(v0) | ((u32)f2bf(v1) << 16);
    }
    *(u32x4*)(out + (size_t)n * 64 + l8 * 8) = *(u32x4*)ow;
  }
}

// ---------------------------------------------------------------------------
// Layer-3 aggregation: wave = 4 degree-matched nodes x 16 lanes, lane = 8
// cols (head = (lane&15)>>1), one-pass online softmax, head-mean via
// shfl_xor {2,4,8}, pairwise log_softmax, lanes {0,1} of group write.
// ---------------------------------------------------------------------------
__global__ __launch_bounds__(256) void gat_agg3_gs(
    const u16* __restrict__ xwh, const float* __restrict__ alsrc,
    const float* __restrict__ aldst, const int* __restrict__ row_ptr,
    const int* __restrict__ csr_src, const int* __restrict__ perm,
    const float* __restrict__ bias, float* __restrict__ out, int N, int ALP) {
  constexpr int U = 4;
  int lane = threadIdx.x & 63;
  int g = lane >> 4, l16 = lane & 15;
  int head = l16 >> 1;
  int ti = blockIdx.x * 16 + (threadIdx.x >> 6) * 4 + g;
  int n = perm[min(ti, N - 1)];
  const float* alh = alsrc + (size_t)head * ALP;
  float ad = aldst[(size_t)head * ALP + n];
  int start = row_ptr[n];
  int end = row_ptr[n + 1];
  int deg = (ti < N) ? end - start : 0;
  int endm1 = end - 1;

  float m = -1e30f, s = 0.f;
  float acc[8] = {};
  const u16* base = xwh + (size_t)l16 * 8;

  auto fma8 = [&](const u32x4& v, float w) {
#pragma unroll
    for (int i = 0; i < 4; i++) {
      u32 u = v[i];
      acc[2 * i] = fmaf(w, bf2f(u & 0xffffu), acc[2 * i]);
      acc[2 * i + 1] = fmaf(w, bf2f(u >> 16), acc[2 * i + 1]);
    }
  };

  int c[U];
#pragma unroll
  for (int i = 0; i < U; i++) c[i] = csr_src[min(start + i, endm1)];
  int j = 0;
  for (; j + U <= deg; j += U) {
    u32x4 v[U];
    float e[U];
#pragma unroll
    for (int i = 0; i < U; i++) v[i] = *(const u32x4*)(base + (size_t)c[i] * 128);
#pragma unroll
    for (int i = 0; i < U; i++) e[i] = lrelu(alh[c[i]] + ad);
#pragma unroll
    for (int i = 0; i < U; i++) c[i] = csr_src[min(start + j + U + i, endm1)];
    float mn = fmaxf(fmaxf(e[0], e[1]), fmaxf(e[2], e[3]));
    if (mn > m) {
      float sc = __expf(m - mn);
      s *= sc;
#pragma unroll
      for (int k = 0; k < 8; k++) acc[k] *= sc;
      m = mn;
    }
#pragma unroll
    for (int i = 0; i < U; i++) {
      float w = __expf(e[i] - m);
      s += w;
      fma8(v[i], w);
    }
  }
  for (int i = 0; j < deg; j++, i++) {
    u32x4 v = *(const u32x4*)(base + (size_t)c[i] * 128);
    float e = lrelu(alh[c[i]] + ad);
    if (e > m) {
      float sc = __expf(m - e);
      s *= sc;
#pragma unroll
      for (int k = 0; k < 8; k++) acc[k] *= sc;
      m = e;
    }
    float w = __expf(e - m);
    s += w;
    fma8(v, w);
  }
  float rr = 1.f / (s + 1e-16f);
#pragma unroll
  for (int k = 0; k < 8; k++) acc[k] *= rr;

  // sum over heads: lanes differing in bits 1..3 of l16 hold other heads
#pragma unroll
  for (int st = 2; st <= 8; st <<= 1)
#pragma unroll
    for (int k = 0; k < 8; k++) acc[k] += __shfl_xor(acc[k], st);

  int half = l16 & 1;  // which 8 of the 16 output cols this lane holds
  float v8[8];
  float mx = -1e30f;
#pragma unroll
  for (int k = 0; k < 8; k++) {
    v8[k] = acc[k] * 0.125f + bias[half * 8 + k];
    mx = fmaxf(mx, v8[k]);
  }
  mx = fmaxf(mx, __shfl_xor(mx, 1));
  float se = 0.f;
#pragma unroll
  for (int k = 0; k < 8; k++) se += __expf(v8[k] - mx);
  se += __shfl_xor(se, 1);
  float lse = mx + logf(se);
  if (ti < N && l16 < 2) {
    float4 o0 = make_float4(v8[0] - lse, v8[1] - lse, v8[2] - lse, v8[3] - lse);
    float4 o1 = make_float4(v8[4] - lse, v8[5] - lse, v8[6] - lse, v8[7] - lse);
    float* op = out + (size_t)n * 16 + half * 8;
    *(float4*)op = o0;
    *(float4*)(op + 4) = o1;
  }
}

// ---------------------------------------------------------------------------
extern "C" void kernel_launch(void* const* d_in, const int* in_sizes, int n_in,
                              void* d_out, int out_size, void* d_ws, size_t ws_size,
                              hipStream_t stream) {
  const float* x        = (const float*)d_in[0];
  const int*   ei       = (const int*)d_in[1];
  const float* bn_gamma = (const float*)d_in[2];
  const float* bn_beta  = (const float*)d_in[3];
  const float* W1       = (const float*)d_in[4];
  const float* a1s      = (const float*)d_in[5];
  const float* a1d      = (const float*)d_in[6];
  const float* b1       = (const float*)d_in[7];
  const float* p1       = (const float*)d_in[8];
  const float* W2       = (const float*)d_in[9];
  const float* a2s      = (const float*)d_in[10];
  const float* a2d      = (const float*)d_in[11];
  const float* b2       = (const float*)d_in[12];
  const float* p2       = (const float*)d_in[13];
  const float* W3       = (const float*)d_in[14];
  const float* a3s      = (const float*)d_in[15];
  const float* a3d      = (const float*)d_in[16];
  const float* b3       = (const float*)d_in[17];
  float* out = (float*)d_out;

  const int F  = in_sizes[2];       // 256
  const int N  = in_sizes[0] / F;   // 20000
  const int E  = in_sizes[1] / 2;   // 320000
  const int ET = E + N;
  const int MP = ((N + 127) / 128) * 128;  // MFMA row padding (also al stride)

  size_t off = 0;
  auto alloc = [&](size_t bytes) -> char* {
    char* r = (char*)d_ws + off;
    off += (bytes + 255) & ~(size_t)255;
    return r;
  };
  // musum|sqsum|cursor adjacent -> single memset covers all three
  float* musum   = (float*)alloc(F * 4);
  float* sqsum   = (float*)alloc(F * 4);
  int*   cursor  = (int*)alloc((size_t)N * 4);
  int*   row_ptr = (int*)alloc((size_t)(N + 1) * 4);
  int*   csr_src = (int*)alloc((size_t)ET * 4);
  int*   perm    = (int*)alloc((size_t)N * 4);
  float* al_s    = (float*)alloc((size_t)16 * MP * 4);
  float* al_d    = (float*)alloc((size_t)16 * MP * 4);
  u16*   Wt1     = (u16*)alloc((size_t)1152 * 256 * 2);
  u16*   Wt2     = (u16*)alloc((size_t)96 * 1280 * 2);
  u16*   Wt3     = (u16*)alloc((size_t)160 * 64 * 2);
  u16*   x_in_h  = (u16*)alloc((size_t)MP * 256 * 2);
  u16*   xw1h    = (u16*)alloc((size_t)MP * 1024 * 2);
  u16*   h1      = (u16*)alloc((size_t)MP * 1024 * 2);
  u16*   xw2h    = (u16*)alloc((size_t)MP * 64 * 2);
  u16*   h2h     = (u16*)alloc((size_t)MP * 64 * 2);
  u16*   xw3h    = (u16*)alloc((size_t)MP * 128 * 2);

  // ---- single memset: musum (1KB) + sqsum (1KB) + cursor (N*4) ----
  hipMemsetAsync(musum, 0, (size_t)2 * F * 4 + (size_t)N * 4, stream);

  // ---- PREP-1: BN stats || CSR count ----
  int CNTB = (ET + 255) / 256;
  prep1_kernel<<<256 + CNTB, 256, 0, stream>>>(x, musum, sqsum, ei, E, N, cursor);

  // ---- PREP-2: scan+perm (block 0) || BN apply (blocks 1..256) ----
  prep2_kernel<<<257, 1024, 0, stream>>>(cursor, row_ptr, perm, x, musum, sqsum, bn_gamma,
                                         bn_beta, x_in_h, N, 1.0f / (float)N);

  // ---- PREP-3: CSR fill || weight prep ----
  {
    int total_wt = 1024 * 256 + 64 * 1280 + 128 * 64      // data
                 + 32 * 256 + 16 * 1280 + 16 * 64         // al-fold
                 + 96 * 256 + 16 * 1280 + 16 * 64;        // zero-pad
    int WTB = (total_wt + 255) / 256;
    prep3_kernel<<<CNTB + WTB, 256, 0, stream>>>(ei, E, N, CNTB, cursor, csr_src, W1, a1s, a1d,
                                                 W2, a2s, a2d, W3, a3s, a3d, Wt1, Wt2, Wt3);
  }

  // ---- Layer 1: [N,256]@[256,1024(+32al)] MFMA, H=16, C=64 ----
  {
    dim3 grid(MP / 128, 9);  // 9th tile covers al cols 1024..1151
    mfma_gemm_al<128, 128, 4, 4><<<grid, 256, 0, stream>>>(
        x_in_h, x_in_h, 256, 256, Wt1, xw1h, 1024, al_s, al_d, 32, MP, N);
    int NBH = (N + 31) / 32;  // node-32-blocks per head
    gat_agg1_gs<<<8 * NBH * 2, 256, 0, stream>>>(xw1h, al_s, al_d, row_ptr, csr_src, perm, b1, p1,
                                                 h1, N, MP, NBH);
  }

  // ---- Layer 2: concat([x_in,h1]) [N,1280]@[1280,64+16al] MFMA, H=8, C=8 ----
  {
    dim3 grid((N + 63) / 64, 1);
    mfma_gemm_al<64, 96, 2, 3><<<grid, 256, 0, stream>>>(
        x_in_h, h1, 256, 1280, Wt2, xw2h, 64, al_s, al_d, 16, MP, N);
    gat_agg2_gs<<<(N + 31) / 32, 256, 0, stream>>>(xw2h, al_s, al_d, row_ptr, csr_src, perm, b2,
                                                   p2, h2h, N, MP);
  }

  // ---- Layer 3: [N,64]@[64,128+16al] MFMA, H=8, C=16, mean + log_softmax ----
  {
    dim3 grid((N + 63) / 64, 1);
    mfma_gemm_al<64, 160, 2, 5><<<grid, 256, 0, stream>>>(
        h2h, h2h, 64, 64, Wt3, xw3h, 128, al_s, al_d, 16, MP, N);
    gat_agg3_gs<<<(N + 15) / 16, 256, 0, stream>>>(xw3h, al_s, al_d, row_ptr, csr_src, perm, b3,
                                                   out, N, MP);
  }
}

// Round 13
// 302.862 us; speedup vs baseline: 1.5992x; 1.0163x over previous
//
#include <hip/hip_runtime.h>
#include <math.h>

typedef unsigned int u32;
typedef unsigned short u16;
typedef u32 u32x4 __attribute__((ext_vector_type(4)));
typedef float f32x4 __attribute__((ext_vector_type(4)));
typedef float f32x2 __attribute__((ext_vector_type(2)));

__device__ __forceinline__ u16 f2bf(float f) {
  u32 u = __builtin_bit_cast(u32, f);
  return (u16)((u + 0x7FFFu + ((u >> 16) & 1u)) >> 16);
}
__device__ __forceinline__ void mfma16(f32x4& c, const u32x4& a, const u32x4& b) {
  asm volatile("v_mfma_f32_16x16x32_bf16 %0, %1, %2, %0" : "+v"(c) : "v"(a), "v"(b));
}
// packed fp32 fma: acc = val*w + acc (2 lanes worth per instruction)
__device__ __forceinline__ void pkfma(f32x2& acc, f32x2 val, f32x2 w) {
  asm volatile("v_pk_fma_f32 %0, %1, %2, %0" : "+v"(acc) : "v"(val), "v"(w));
}
// unpack u32 of 2 bf16 -> float2 {lo, hi}
__device__ __forceinline__ f32x2 unpk(u32 u) {
  f32x2 v;
  v.x = __builtin_bit_cast(float, u << 16);
  v.y = __builtin_bit_cast(float, u & 0xffff0000u);
  return v;
}
__device__ __forceinline__ float lrelu(float e) { return fmaxf(e, 0.2f * e); }

// ---------------------------------------------------------------------------
// PREP-1 (merged): blocks [0,256) = BN stats; blocks [256,..) = CSR count.
// ---------------------------------------------------------------------------
__global__ void prep1_kernel(const float* __restrict__ x, float* __restrict__ musum,
                             float* __restrict__ sqsum, const int* __restrict__ ei, int E,
                             int N, int* __restrict__ cnt) {
  int b = blockIdx.x;
  int t = threadIdx.x;
  if (b < 256) {
    float s = 0.f, s2 = 0.f;
    for (int r = b; r < N; r += 256) {
      float v = x[(size_t)r * 256 + t];
      s += v;
      s2 += v * v;
    }
    atomicAdd(&musum[t], s);
    atomicAdd(&sqsum[t], s2);
  } else {
    int e = (b - 256) * 256 + t;
    int ET = E + N;
    if (e < ET) {
      int d = (e < E) ? ei[E + e] : (e - E);
      atomicAdd(&cnt[d], 1);
    }
  }
}

// ---------------------------------------------------------------------------
// PREP-2 (merged, 1024 threads): block 0 = scan + perm; blocks 1.. = BN apply
// ---------------------------------------------------------------------------
__global__ __launch_bounds__(1024) void prep2_kernel(
    int* __restrict__ cnt, int* __restrict__ row_ptr, int* __restrict__ perm,
    const float* __restrict__ x, const float* __restrict__ musum,
    const float* __restrict__ sqsum, const float* __restrict__ gamma,
    const float* __restrict__ beta, u16* __restrict__ xin, int N, float invN) {
  int t = threadIdx.x;
  if (blockIdx.x == 0) {
    __shared__ int part[1024];
    __shared__ int bins[256];
    __shared__ int bs[256];
    int chunk = (N + 1023) / 1024;
    int lo = min(t * chunk, N);
    int hi = min(lo + chunk, N);
    if (t < 256) bins[t] = 0;
    __syncthreads();
    int s = 0;
    for (int i = lo; i < hi; i++) {
      int d = cnt[i];
      s += d;
      atomicAdd(&bins[min(d, 255)], 1);
    }
    part[t] = s;
    __syncthreads();
    for (int off = 1; off < 1024; off <<= 1) {
      int v = (t >= off) ? part[t - off] : 0;
      __syncthreads();
      part[t] += v;
      __syncthreads();
    }
    if (t < 256) bs[t] = bins[t];
    __syncthreads();
    for (int off = 1; off < 256; off <<= 1) {
      int v = (t < 256 && t >= off) ? bs[t - off] : 0;
      __syncthreads();
      if (t < 256) bs[t] += v;
      __syncthreads();
    }
    if (t < 256) bins[t] = (t == 0) ? 0 : bs[t - 1];
    __syncthreads();
    for (int i = lo; i < hi; i++) {
      int d = min(cnt[i], 255);
      int pos = atomicAdd(&bins[d], 1);
      perm[pos] = i;
    }
    __syncthreads();
    int run = (t == 0) ? 0 : part[t - 1];
    for (int i = lo; i < hi; i++) {
      int d = cnt[i];
      row_ptr[i] = run;
      cnt[i] = run;
      run += d;
    }
    if (t == 1023) row_ptr[N] = part[1023];
  } else {
    int col = t & 255, ro = t >> 8;
    float mu = musum[col] * invN;
    float var = sqsum[col] * invN - mu * mu;
    float sc = gamma[col] * rsqrtf(var + 1e-5f);
    float sh = beta[col] - mu * sc;
    for (int r = (blockIdx.x - 1) * 4 + ro; r < N; r += 256 * 4) {
      size_t idx = (size_t)r * 256 + col;
      xin[idx] = f2bf(x[idx] * sc + sh);
    }
  }
}

// ---------------------------------------------------------------------------
// PREP-3 (merged): CSR fill || weight prep (transposes + al-folds + zero-pads)
// ---------------------------------------------------------------------------
__global__ void prep3_kernel(const int* __restrict__ ei, int E, int N, int FILLB,
                             int* __restrict__ cursor, int* __restrict__ csr_src,
                             const float* __restrict__ W1, const float* __restrict__ a1s,
                             const float* __restrict__ a1d, const float* __restrict__ W2,
                             const float* __restrict__ a2s, const float* __restrict__ a2d,
                             const float* __restrict__ W3, const float* __restrict__ a3s,
                             const float* __restrict__ a3d, u16* __restrict__ Wt1,
                             u16* __restrict__ Wt2, u16* __restrict__ Wt3) {
  int b = blockIdx.x;
  if (b < FILLB) {
    int e = b * 256 + threadIdx.x;
    int ET = E + N;
    if (e < ET) {
      int s, d;
      if (e < E) { s = ei[e]; d = ei[E + e]; }
      else       { s = e - E; d = s; }
      int pos = atomicAdd(&cursor[d], 1);
      csr_src[pos] = s;
    }
    return;
  }
  const int S1 = 1024 * 256, S2 = 64 * 1280, S3 = 128 * 64;
  const int A1 = 32 * 256, A2 = 16 * 1280, A3 = 16 * 64;
  const int Z1 = 96 * 256, Z2 = 16 * 1280, Z3 = 16 * 64;
  int o = (b - FILLB) * 256 + threadIdx.x;
  if (o < S1) {
    int n = o / 256, k = o % 256;
    Wt1[o] = f2bf(W1[(size_t)k * 1024 + n]);
    return;
  }
  o -= S1;
  if (o < S2) {
    int n = o / 1280, k = o % 1280;
    Wt2[o] = f2bf(W2[(size_t)k * 64 + n]);
    return;
  }
  o -= S2;
  if (o < S3) {
    int n = o / 64, k = o % 64;
    Wt3[o] = f2bf(W3[(size_t)k * 128 + n]);
    return;
  }
  o -= S3;
  if (o < A1) {
    int jj = o / 256, k = o % 256, h = jj >> 1;
    const float* av = (jj & 1) ? a1d : a1s;
    float s = 0.f;
    for (int c = 0; c < 64; c++) s += W1[(size_t)k * 1024 + h * 64 + c] * av[h * 64 + c];
    Wt1[(size_t)(1024 + jj) * 256 + k] = f2bf(s);
    return;
  }
  o -= A1;
  if (o < A2) {
    int jj = o / 1280, k = o % 1280, h = jj >> 1;
    const float* av = (jj & 1) ? a2d : a2s;
    float s = 0.f;
    for (int c = 0; c < 8; c++) s += W2[(size_t)k * 64 + h * 8 + c] * av[h * 8 + c];
    Wt2[(size_t)(64 + jj) * 1280 + k] = f2bf(s);
    return;
  }
  o -= A2;
  if (o < A3) {
    int jj = o / 64, k = o % 64, h = jj >> 1;
    const float* av = (jj & 1) ? a3d : a3s;
    float s = 0.f;
    for (int c = 0; c < 16; c++) s += W3[(size_t)k * 128 + h * 16 + c] * av[h * 16 + c];
    Wt3[(size_t)(128 + jj) * 64 + k] = f2bf(s);
    return;
  }
  o -= A3;
  if (o < Z1) { Wt1[1056 * 256 + o] = 0; return; }
  o -= Z1;
  if (o < Z2) { Wt2[80 * 1280 + o] = 0; return; }
  o -= Z2;
  if (o < Z3) { Wt3[144 * 64 + o] = 0; return; }
}

// ---------------------------------------------------------------------------
// bf16 MFMA GEMM, generalized BK, double-buffered LDS via global_load_lds.
// Fused al epilogue (transposed [H][ALP] al output).
// ---------------------------------------------------------------------------
template <int BM, int BN, int FM, int FN, int BK>
__global__ __launch_bounds__(256) void mfma_gemm_al(
    const u16* __restrict__ A1, const u16* __restrict__ A2, int K1, int K,
    const u16* __restrict__ Wt, u16* __restrict__ Ch, int NcH,
    float* __restrict__ als, float* __restrict__ ald, int ALN, int ALP, int M) {
  constexpr int KC8 = BK / 8;          // 16B chunks per row of a K-tile
  constexpr int ACH = (BM * BK) / 8;
  constexpr int BCH = (BN * BK) / 8;
  static_assert(BM == 2 * FM * 16 && BN == 2 * FN * 16, "wave grid 2x2");
  __shared__ u16 As[2][BM * BK];
  __shared__ u16 Bs[2][BN * BK];
  int t = threadIdx.x;
  int m0 = blockIdx.x * BM, n0 = blockIdx.y * BN;
  int r = t & 15;
  int g = (t >> 4) & 3;
  int wid = t >> 6;
  int wm0 = (wid >> 1) * (FM * 16);
  int wn0 = (wid & 1) * (FN * 16);
  int K8 = K >> 3;
  int K2 = K - K1;

  auto stage = [&](int buf, int k0) {
    const u16* Aseg;
    int sA, kl;
    if (k0 < K1) { Aseg = A1; sA = K1; kl = k0; }
    else         { Aseg = A2; sA = K2; kl = k0 - K1; }
#pragma unroll
    for (int i = 0; i < (ACH + 255) / 256; i++) {
      int c = i * 256 + t;
      if (ACH % 256 == 0 || c < ACH) {
        int m = c / KC8, kb = c % KC8;
        __builtin_amdgcn_global_load_lds(
            (const __attribute__((address_space(1))) void*)(Aseg + (size_t)(m0 + m) * sA + kl + kb * 8),
            (__attribute__((address_space(3))) void*)(&As[buf][c * 8]), 16, 0, 0);
      }
    }
#pragma unroll
    for (int i = 0; i < (BCH + 255) / 256; i++) {
      int c = i * 256 + t;
      if (BCH % 256 == 0 || c < BCH) {
        int nn = c / KC8, kb = c % KC8;
        __builtin_amdgcn_global_load_lds(
            (const __attribute__((address_space(1))) void*)(Wt + ((size_t)(n0 + nn) * K8 + (k0 >> 3) + kb) * 8),
            (__attribute__((address_space(3))) void*)(&Bs[buf][c * 8]), 16, 0, 0);
      }
    }
  };

  f32x4 acc[FM][FN] = {};
  asm volatile("s_nop 7\n\ts_nop 7" :::);  // VALU acc-init -> MFMA SrcC hazard guard

  stage(0, 0);
  __syncthreads();  // vmcnt(0) drain + barrier: tile 0 resident
  int nt = K / BK;
  for (int ts = 0; ts < nt; ts++) {
    if (ts + 1 < nt) stage((ts + 1) & 1, (ts + 1) * BK);  // overlap with compute
    int cur = ts & 1;
#pragma unroll
    for (int ks = 0; ks < BK / 32; ks++) {
      u32x4 af[FM], bfr[FN];
#pragma unroll
      for (int fi = 0; fi < FM; fi++)
        af[fi] = *(const u32x4*)(&As[cur][((wm0 + fi * 16 + r) * KC8 + ks * 4 + g) * 8]);
#pragma unroll
      for (int fj = 0; fj < FN; fj++)
        bfr[fj] = *(const u32x4*)(&Bs[cur][((wn0 + fj * 16 + r) * KC8 + ks * 4 + g) * 8]);
#pragma unroll
      for (int fi = 0; fi < FM; fi++)
#pragma unroll
        for (int fj = 0; fj < FN; fj++) mfma16(acc[fi][fj], af[fi], bfr[fj]);
    }
    __syncthreads();  // drains vmcnt (next tile ready) + ds_reads of cur done
  }
  asm volatile("s_nop 7\n\ts_nop 7" :::);  // MFMA -> VALU read hazard guard

#pragma unroll
  for (int fi = 0; fi < FM; fi++) {
#pragma unroll
    for (int fj = 0; fj < FN; fj++) {
#pragma unroll
      for (int v = 0; v < 4; v++) {
        int m = m0 + wm0 + fi * 16 + g * 4 + v;
        int nn = n0 + wn0 + fj * 16 + r;
        if (m < M) {
          float val = acc[fi][fj][v];
          if (nn < NcH) {
            Ch[(size_t)m * NcH + nn] = f2bf(val);
          } else {
            int j = nn - NcH;
            if (j < ALN) ((j & 1) ? ald : als)[(size_t)(j >> 1) * ALP + m] = val;
          }
        }
      }
    }
  }
}

// ---------------------------------------------------------------------------
// Layer-1 aggregation: GROUP-SLICED + XCD-affine + one-pass online softmax.
// pk_fma inner loop. Wave = 8 degree-matched nodes, same head.
// ---------------------------------------------------------------------------
__global__ __launch_bounds__(256) void gat_agg1_gs(
    const u16* __restrict__ xwh, const float* __restrict__ alsrc,
    const float* __restrict__ aldst, const int* __restrict__ row_ptr,
    const int* __restrict__ csr_src, const int* __restrict__ perm,
    const float* __restrict__ bias, const float* __restrict__ slope_p,
    u16* __restrict__ out, int N, int ALP, int NBH) {
  constexpr int U = 4;
  int b = blockIdx.x;
  int xcd = b & 7, seq = b >> 3;
  int phase = seq / NBH, nb = seq - phase * NBH;
  int h = xcd + (phase << 3);
  int lane = threadIdx.x & 63;
  int g = lane >> 3, l8 = lane & 7;
  int ti = nb * 32 + (threadIdx.x >> 6) * 8 + g;
  int n = perm[min(ti, N - 1)];
  const float* alh = alsrc + (size_t)h * ALP;
  float ad = aldst[(size_t)h * ALP + n];
  int start = row_ptr[n];
  int end = row_ptr[n + 1];
  int deg = (ti < N) ? end - start : 0;
  int endm1 = end - 1;

  float m = -1e30f, s = 0.f;
  f32x2 acc2[4] = {};
  const u16* base = xwh + (size_t)h * 64 + (size_t)l8 * 8;

  auto fma8 = [&](const u32x4& v, float w) {
    f32x2 w2;
    w2.x = w;
    w2.y = w;
#pragma unroll
    for (int i = 0; i < 4; i++) pkfma(acc2[i], unpk(v[i]), w2);
  };

  int c[U];
#pragma unroll
  for (int i = 0; i < U; i++) c[i] = csr_src[min(start + i, endm1)];
  int j = 0;
  for (; j + U <= deg; j += U) {
    u32x4 v[U];
    float e[U];
#pragma unroll
    for (int i = 0; i < U; i++) v[i] = *(const u32x4*)(base + (size_t)c[i] * 1024);
#pragma unroll
    for (int i = 0; i < U; i++) e[i] = lrelu(alh[c[i]] + ad);
#pragma unroll
    for (int i = 0; i < U; i++) c[i] = csr_src[min(start + j + U + i, endm1)];
    float mn = fmaxf(fmaxf(e[0], e[1]), fmaxf(e[2], e[3]));
    if (mn > m) {
      float sc = __expf(m - mn);
      s *= sc;
#pragma unroll
      for (int k = 0; k < 4; k++) acc2[k] *= sc;
      m = mn;
    }
#pragma unroll
    for (int i = 0; i < U; i++) {
      float w = __expf(e[i] - m);
      s += w;
      fma8(v[i], w);
    }
  }
  for (int i = 0; j < deg; j++, i++) {
    u32x4 v = *(const u32x4*)(base + (size_t)c[i] * 1024);
    float e = lrelu(alh[c[i]] + ad);
    if (e > m) {
      float sc = __expf(m - e);
      s *= sc;
#pragma unroll
      for (int k = 0; k < 4; k++) acc2[k] *= sc;
      m = e;
    }
    float w = __expf(e - m);
    s += w;
    fma8(v, w);
  }
  float rr = 1.f / (s + 1e-16f);

  if (ti < N) {
    float p = slope_p[0];
    u32 ow[4];
#pragma unroll
    for (int i = 0; i < 4; i++) {
      int cc = h * 64 + l8 * 8 + 2 * i;
      float v0 = acc2[i].x * rr + bias[cc];
      float v1 = acc2[i].y * rr + bias[cc + 1];
      v0 = (v0 >= 0.f) ? v0 : p * v0;
      v1 = (v1 >= 0.f) ? v1 : p * v1;
      ow[i] = (u32)f2bf(v0) | ((u32)f2bf(v1) << 16);
    }
    *(u32x4*)(out + (size_t)n * 1024 + h * 64 + l8 * 8) = *(u32x4*)ow;
  }
}

// ---------------------------------------------------------------------------
// Layer-2 aggregation: wave = 8 degree-matched nodes, lane = 8 cols (head =
// lane&7), pk_fma inner loop, one-pass online softmax.
// ---------------------------------------------------------------------------
__global__ __launch_bounds__(256) void gat_agg2_gs(
    const u16* __restrict__ xwh, const float* __restrict__ alsrc,
    const float* __restrict__ aldst, const int* __restrict__ row_ptr,
    const int* __restrict__ csr_src, const int* __restrict__ perm,
    const float* __restrict__ bias, const float* __restrict__ slope_p,
    u16* __restrict__ out, int N, int ALP) {
  constexpr int U = 4;
  int lane = threadIdx.x & 63;
  int g = lane >> 3, l8 = lane & 7;  // l8 = col-block = head
  int ti = blockIdx.x * 32 + (threadIdx.x >> 6) * 8 + g;
  int n = perm[min(ti, N - 1)];
  const float* alh = alsrc + (size_t)l8 * ALP;
  float ad = aldst[(size_t)l8 * ALP + n];
  int start = row_ptr[n];
  int end = row_ptr[n + 1];
  int deg = (ti < N) ? end - start : 0;
  int endm1 = end - 1;

  float m = -1e30f, s = 0.f;
  f32x2 acc2[4] = {};
  const u16* base = xwh + (size_t)l8 * 8;

  auto fma8 = [&](const u32x4& v, float w) {
    f32x2 w2;
    w2.x = w;
    w2.y = w;
#pragma unroll
    for (int i = 0; i < 4; i++) pkfma(acc2[i], unpk(v[i]), w2);
  };

  int c[U];
#pragma unroll
  for (int i = 0; i < U; i++) c[i] = csr_src[min(start + i, endm1)];
  int j = 0;
  for (; j + U <= deg; j += U) {
    u32x4 v[U];
    float e[U];
#pragma unroll
    for (int i = 0; i < U; i++) v[i] = *(const u32x4*)(base + (size_t)c[i] * 64);
#pragma unroll
    for (int i = 0; i < U; i++) e[i] = lrelu(alh[c[i]] + ad);
#pragma unroll
    for (int i = 0; i < U; i++) c[i] = csr_src[min(start + j + U + i, endm1)];
    float mn = fmaxf(fmaxf(e[0], e[1]), fmaxf(e[2], e[3]));
    if (mn > m) {
      float sc = __expf(m - mn);
      s *= sc;
#pragma unroll
      for (int k = 0; k < 4; k++) acc2[k] *= sc;
      m = mn;
    }
#pragma unroll
    for (int i = 0; i < U; i++) {
      float w = __expf(e[i] - m);
      s += w;
      fma8(v[i], w);
    }
  }
  for (int i = 0; j < deg; j++, i++) {
    u32x4 v = *(const u32x4*)(base + (size_t)c[i] * 64);
    float e = lrelu(alh[c[i]] + ad);
    if (e > m) {
      float sc = __expf(m - e);
      s *= sc;
#pragma unroll
      for (int k = 0; k < 4; k++) acc2[k] *= sc;
      m = e;
    }
    float w = __expf(e - m);
    s += w;
    fma8(v, w);
  }
  float rr = 1.f / (s + 1e-16f);

  if (ti < N) {
    float p = slope_p[0];
    u32 ow[4];
#pragma unroll
    for (int i = 0; i < 4; i++) {
      int cc = l8 * 8 + 2 * i;
      float v0 = acc2[i].x * rr + bias[cc];
      float v1 = acc2[i].y * rr + bias[cc + 1];
      v0 = (v0 >= 0.f) ? v0 : p * v0;
      v1 = (v1 >= 0.f) ? v1 : p * v1;
      ow[i] = (u32)f2bf(v0) | ((u32)f2bf(v1) << 16);
    }
    *(u32x4*)(out + (size_t)n * 64 + l8 * 8) = *(u32x4*)ow;
  }
}

// ---------------------------------------------------------------------------
// Layer-3 aggregation: wave = 4 degree-matched nodes x 16 lanes, pk_fma,
// one-pass online softmax, head-mean via shfl_xor, pairwise log_softmax.
// ---------------------------------------------------------------------------
__global__ __launch_bounds__(256) void gat_agg3_gs(
    const u16* __restrict__ xwh, const float* __restrict__ alsrc,
    const float* __restrict__ aldst, const int* __restrict__ row_ptr,
    const int* __restrict__ csr_src, const int* __restrict__ perm,
    const float* __restrict__ bias, float* __restrict__ out, int N, int ALP) {
  constexpr int U = 4;
  int lane = threadIdx.x & 63;
  int g = lane >> 4, l16 = lane & 15;
  int head = l16 >> 1;
  int ti = blockIdx.x * 16 + (threadIdx.x >> 6) * 4 + g;
  int n = perm[min(ti, N - 1)];
  const float* alh = alsrc + (size_t)head * ALP;
  float ad = aldst[(size_t)head * ALP + n];
  int start = row_ptr[n];
  int end = row_ptr[n + 1];
  int deg = (ti < N) ? end - start : 0;
  int endm1 = end - 1;

  float m = -1e30f, s = 0.f;
  f32x2 acc2[4] = {};
  const u16* base = xwh + (size_t)l16 * 8;

  auto fma8 = [&](const u32x4& v, float w) {
    f32x2 w2;
    w2.x = w;
    w2.y = w;
#pragma unroll
    for (int i = 0; i < 4; i++) pkfma(acc2[i], unpk(v[i]), w2);
  };

  int c[U];
#pragma unroll
  for (int i = 0; i < U; i++) c[i] = csr_src[min(start + i, endm1)];
  int j = 0;
  for (; j + U <= deg; j += U) {
    u32x4 v[U];
    float e[U];
#pragma unroll
    for (int i = 0; i < U; i++) v[i] = *(const u32x4*)(base + (size_t)c[i] * 128);
#pragma unroll
    for (int i = 0; i < U; i++) e[i] = lrelu(alh[c[i]] + ad);
#pragma unroll
    for (int i = 0; i < U; i++) c[i] = csr_src[min(start + j + U + i, endm1)];
    float mn = fmaxf(fmaxf(e[0], e[1]), fmaxf(e[2], e[3]));
    if (mn > m) {
      float sc = __expf(m - mn);
      s *= sc;
#pragma unroll
      for (int k = 0; k < 4; k++) acc2[k] *= sc;
      m = mn;
    }
#pragma unroll
    for (int i = 0; i < U; i++) {
      float w = __expf(e[i] - m);
      s += w;
      fma8(v[i], w);
    }
  }
  for (int i = 0; j < deg; j++, i++) {
    u32x4 v = *(const u32x4*)(base + (size_t)c[i] * 128);
    float e = lrelu(alh[c[i]] + ad);
    if (e > m) {
      float sc = __expf(m - e);
      s *= sc;
#pragma unroll
      for (int k = 0; k < 4; k++) acc2[k] *= sc;
      m = e;
    }
    float w = __expf(e - m);
    s += w;
    fma8(v, w);
  }
  float rr = 1.f / (s + 1e-16f);

  float a8[8];
#pragma unroll
  for (int k = 0; k < 4; k++) {
    a8[2 * k] = acc2[k].x * rr;
    a8[2 * k + 1] = acc2[k].y * rr;
  }

  // sum over heads: lanes differing in bits 1..3 of l16 hold other heads
#pragma unroll
  for (int st = 2; st <= 8; st <<= 1)
#pragma unroll
    for (int k = 0; k < 8; k++) a8[k] += __shfl_xor(a8[k], st);

  int half = l16 & 1;  // which 8 of the 16 output cols this lane holds
  float v8[8];
  float mx = -1e30f;
#pragma unroll
  for (int k = 0; k < 8; k++) {
    v8[k] = a8[k] * 0.125f + bias[half * 8 + k];
    mx = fmaxf(mx, v8[k]);
  }
  mx = fmaxf(mx, __shfl_xor(mx, 1));
  float se = 0.f;
#pragma unroll
  for (int k = 0; k < 8; k++) se += __expf(v8[k] - mx);
  se += __shfl_xor(se, 1);
  float lse = mx + logf(se);
  if (ti < N && l16 < 2) {
    float4 o0 = make_float4(v8[0] - lse, v8[1] - lse, v8[2] - lse, v8[3] - lse);
    float4 o1 = make_float4(v8[4] - lse, v8[5] - lse, v8[6] - lse, v8[7] - lse);
    float* op = out + (size_t)n * 16 + half * 8;
    *(float4*)op = o0;
    *(float4*)(op + 4) = o1;
  }
}

// ---------------------------------------------------------------------------
extern "C" void kernel_launch(void* const* d_in, const int* in_sizes, int n_in,
                              void* d_out, int out_size, void* d_ws, size_t ws_size,
                              hipStream_t stream) {
  const float* x        = (const float*)d_in[0];
  const int*   ei       = (const int*)d_in[1];
  const float* bn_gamma = (const float*)d_in[2];
  const float* bn_beta  = (const float*)d_in[3];
  const float* W1       = (const float*)d_in[4];
  const float* a1s      = (const float*)d_in[5];
  const float* a1d      = (const float*)d_in[6];
  const float* b1       = (const float*)d_in[7];
  const float* p1       = (const float*)d_in[8];
  const float* W2       = (const float*)d_in[9];
  const float* a2s      = (const float*)d_in[10];
  const float* a2d      = (const float*)d_in[11];
  const float* b2       = (const float*)d_in[12];
  const float* p2       = (const float*)d_in[13];
  const float* W3       = (const float*)d_in[14];
  const float* a3s      = (const float*)d_in[15];
  const float* a3d      = (const float*)d_in[16];
  const float* b3       = (const float*)d_in[17];
  float* out = (float*)d_out;

  const int F  = in_sizes[2];       // 256
  const int N  = in_sizes[0] / F;   // 20000
  const int E  = in_sizes[1] / 2;   // 320000
  const int ET = E + N;
  const int MP = ((N + 127) / 128) * 128;  // MFMA row padding (also al stride)

  size_t off = 0;
  auto alloc = [&](size_t bytes) -> char* {
    char* r = (char*)d_ws + off;
    off += (bytes + 255) & ~(size_t)255;
    return r;
  };
  float* musum   = (float*)alloc(F * 4);
  float* sqsum   = (float*)alloc(F * 4);
  int*   cursor  = (int*)alloc((size_t)N * 4);
  int*   row_ptr = (int*)alloc((size_t)(N + 1) * 4);
  int*   csr_src = (int*)alloc((size_t)ET * 4);
  int*   perm    = (int*)alloc((size_t)N * 4);
  float* al_s    = (float*)alloc((size_t)16 * MP * 4);
  float* al_d    = (float*)alloc((size_t)16 * MP * 4);
  u16*   Wt1     = (u16*)alloc((size_t)1152 * 256 * 2);
  u16*   Wt2     = (u16*)alloc((size_t)96 * 1280 * 2);
  u16*   Wt3     = (u16*)alloc((size_t)160 * 64 * 2);
  u16*   x_in_h  = (u16*)alloc((size_t)MP * 256 * 2);
  u16*   xw1h    = (u16*)alloc((size_t)MP * 1024 * 2);
  u16*   h1      = (u16*)alloc((size_t)MP * 1024 * 2);
  u16*   xw2h    = (u16*)alloc((size_t)MP * 64 * 2);
  u16*   h2h     = (u16*)alloc((size_t)MP * 64 * 2);
  u16*   xw3h    = (u16*)alloc((size_t)MP * 128 * 2);

  // ---- single memset: musum + sqsum + cursor ----
  hipMemsetAsync(musum, 0, (size_t)2 * F * 4 + (size_t)N * 4, stream);

  // ---- PREP-1: BN stats || CSR count ----
  int CNTB = (ET + 255) / 256;
  prep1_kernel<<<256 + CNTB, 256, 0, stream>>>(x, musum, sqsum, ei, E, N, cursor);

  // ---- PREP-2: scan+perm (block 0) || BN apply (blocks 1..256) ----
  prep2_kernel<<<257, 1024, 0, stream>>>(cursor, row_ptr, perm, x, musum, sqsum, bn_gamma,
                                         bn_beta, x_in_h, N, 1.0f / (float)N);

  // ---- PREP-3: CSR fill || weight prep ----
  {
    int total_wt = 1024 * 256 + 64 * 1280 + 128 * 64
                 + 32 * 256 + 16 * 1280 + 16 * 64
                 + 96 * 256 + 16 * 1280 + 16 * 64;
    int WTB = (total_wt + 255) / 256;
    prep3_kernel<<<CNTB + WTB, 256, 0, stream>>>(ei, E, N, CNTB, cursor, csr_src, W1, a1s, a1d,
                                                 W2, a2s, a2d, W3, a3s, a3d, Wt1, Wt2, Wt3);
  }

  // ---- Layer 1: [N,256]@[256,1024(+32al)] MFMA, H=16, C=64 ----
  {
    dim3 grid(MP / 128, 9);  // 9th tile covers al cols 1024..1151
    mfma_gemm_al<128, 128, 4, 4, 32><<<grid, 256, 0, stream>>>(
        x_in_h, x_in_h, 256, 256, Wt1, xw1h, 1024, al_s, al_d, 32, MP, N);
    int NBH = (N + 31) / 32;
    gat_agg1_gs<<<8 * NBH * 2, 256, 0, stream>>>(xw1h, al_s, al_d, row_ptr, csr_src, perm, b1, p1,
                                                 h1, N, MP, NBH);
  }

  // ---- Layer 2: concat([x_in,h1]) [N,1280]@[1280,64+16al] MFMA, H=8, C=8 ----
  // BM=32 (626 blocks, 2.4/CU) + BK=64 (20 K-steps) for parallelism.
  {
    dim3 grid((N + 31) / 32, 1);
    mfma_gemm_al<32, 96, 1, 3, 64><<<grid, 256, 0, stream>>>(
        x_in_h, h1, 256, 1280, Wt2, xw2h, 64, al_s, al_d, 16, MP, N);
    gat_agg2_gs<<<(N + 31) / 32, 256, 0, stream>>>(xw2h, al_s, al_d, row_ptr, csr_src, perm, b2,
                                                   p2, h2h, N, MP);
  }

  // ---- Layer 3: [N,64]@[64,128+16al] MFMA, H=8, C=16 (single K-step) ----
  {
    dim3 grid((N + 63) / 64, 1);
    mfma_gemm_al<64, 160, 2, 5, 64><<<grid, 256, 0, stream>>>(
        h2h, h2h, 64, 64, Wt3, xw3h, 128, al_s, al_d, 16, MP, N);
    gat_agg3_gs<<<(N + 15) / 16, 256, 0, stream>>>(xw3h, al_s, al_d, row_ptr, csr_src, perm, b3,
                                                   out, N, MP);
  }
}